// Round 14
// baseline (299.616 us; speedup 1.0000x reference)
//
#include <hip/hip_runtime.h>
#include <hip/hip_bf16.h>

#define H 96
#define DIN 256

typedef unsigned int uint32;
typedef __attribute__((ext_vector_type(8))) short bf16x8;
typedef __attribute__((ext_vector_type(4))) float f32x4;

__device__ __forceinline__ float bflo(uint32 u) { return __uint_as_float(u << 16); }
__device__ __forceinline__ float bfhi(uint32 u) { return __uint_as_float(u & 0xffff0000u); }
__device__ __forceinline__ uint32 packbf(float a, float b) {
    __hip_bfloat16 x = __float2bfloat16(a), y = __float2bfloat16(b);
    unsigned short lo = *reinterpret_cast<unsigned short*>(&x);
    unsigned short hi = *reinterpret_cast<unsigned short*>(&y);
    return (uint32)lo | ((uint32)hi << 16);
}
__device__ __forceinline__ float bfround(float a) {
    return __bfloat162float(__float2bfloat16(a));
}
// fast tanh: exact at saturation (exp overflow -> 1, underflow -> -1)
__device__ __forceinline__ float tanh_fast(float x) {
    float e = __expf(2.f * x);
    return 1.f - 2.f / (e + 1.f);
}

// ---------- CSR build ----------
__global__ void k_hist(const int* __restrict__ ei, int E, int N, int* __restrict__ deg) {
    int e = blockIdx.x * blockDim.x + threadIdx.x;
    int Et = E + N;
    if (e >= Et) return;
    int dst = (e < E) ? ei[E + e] : (e - E);
    atomicAdd(&deg[dst], 1);
}

__global__ __launch_bounds__(256) void k_scanA(const int* __restrict__ deg, int* __restrict__ rs,
                                               int* __restrict__ bsum, int n) {
    __shared__ int sh[256];
    int t = threadIdx.x;
    int base = blockIdx.x * 1024 + t * 4;
    int v[4];
    int s = 0;
#pragma unroll
    for (int j = 0; j < 4; j++) { v[j] = (base + j < n) ? deg[base + j] : 0; s += v[j]; }
    sh[t] = s;
    __syncthreads();
    for (int off = 1; off < 256; off <<= 1) {
        int tmp = (t >= off) ? sh[t - off] : 0;
        __syncthreads();
        sh[t] += tmp;
        __syncthreads();
    }
    int excl = sh[t] - s;
#pragma unroll
    for (int j = 0; j < 4; j++) {
        if (base + j < n) rs[base + j] = excl;
        excl += v[j];
    }
    if (t == 255) bsum[blockIdx.x] = sh[255];
}

__global__ void k_scanB(int* __restrict__ bsum, int nb) {
    int l = threadIdx.x;
    int orig = (l < nb) ? bsum[l] : 0;
    int v = orig;
#pragma unroll
    for (int off = 1; off < 64; off <<= 1) {
        int u = __shfl_up(v, off, 64);
        if (l >= off) v += u;
    }
    if (l < nb) bsum[l] = v - orig;
}

__global__ void k_scanC(int* __restrict__ rs, int* __restrict__ cur, const int* __restrict__ bsum,
                        int n, int total) {
    int i = blockIdx.x * blockDim.x + threadIdx.x;
    if (i < n) {
        int r = rs[i] + bsum[i >> 10];
        rs[i] = r;
        cur[i] = r;
    }
    if (i == 0) rs[n] = total;
}

__global__ void k_scatter(const int* __restrict__ ei, int E, int N,
                          int* __restrict__ cur, int* __restrict__ csr_src) {
    int e = blockIdx.x * blockDim.x + threadIdx.x;
    int Et = E + N;
    if (e >= Et) return;
    int src, dst;
    if (e < E) { src = ei[e]; dst = ei[E + e]; }
    else       { src = e - E; dst = e - E; }
    int pos = atomicAdd(&cur[dst], 1);
    csr_src[pos] = src;
}

// ---------- MFMA GEMM: xt half of ftb + inv2.x ----------
__global__ __launch_bounds__(256) void k_gemm_in_mfma(const float* __restrict__ x, const float* __restrict__ W,
                                                      const float* __restrict__ b, uint32* __restrict__ ftb,
                                                      float* __restrict__ inv2, int N) {
    __shared__ uint32 As[64 * 68];
    __shared__ uint32 Ws[96 * 68];
    int tid = threadIdx.x;
    int lane = tid & 63;
    int w = tid >> 6;
    int row0 = blockIdx.x * 64;
    int n = lane & 15, g = lane >> 4;

    f32x4 acc[6];
#pragma unroll
    for (int t = 0; t < 6; t++) acc[t] = (f32x4){0.f, 0.f, 0.f, 0.f};

    for (int kc = 0; kc < DIN; kc += 128) {
        for (int i = tid; i < 64 * 32; i += 256) {
            int r = i >> 5, seg = i & 31;
            int grow = row0 + r;
            float4 v = (grow < N) ? *(const float4*)(x + (size_t)grow * DIN + kc + seg * 4)
                                  : make_float4(0.f, 0.f, 0.f, 0.f);
            As[r * 68 + seg * 2]     = packbf(v.x, v.y);
            As[r * 68 + seg * 2 + 1] = packbf(v.z, v.w);
        }
        for (int i = tid; i < 96 * 32; i += 256) {
            int r = i >> 5, seg = i & 31;
            float4 v = *(const float4*)(W + (size_t)r * DIN + kc + seg * 4);
            Ws[r * 68 + seg * 2]     = packbf(v.x, v.y);
            Ws[r * 68 + seg * 2 + 1] = packbf(v.z, v.w);
        }
        __syncthreads();
#pragma unroll
        for (int s = 0; s < 4; s++) {
            int kb = s * 16 + g * 4;
            bf16x8 a = *(const bf16x8*)&As[(16 * w + n) * 68 + kb];
#pragma unroll
            for (int t = 0; t < 6; t++) {
                bf16x8 bb = *(const bf16x8*)&Ws[(16 * t + n) * 68 + kb];
                acc[t] = __builtin_amdgcn_mfma_f32_16x16x32_bf16(a, bb, acc[t], 0, 0, 0);
            }
        }
        __syncthreads();
    }
    float ss[4] = {0.f, 0.f, 0.f, 0.f};
#pragma unroll
    for (int t = 0; t < 6; t++) {
        int col = 16 * t + n;
        float bv = b[col];
#pragma unroll
        for (int r = 0; r < 4; r++) {
            int grow = row0 + 16 * w + g * 4 + r;
            float v = acc[t][r] + bv;
            float vb = bfround(v);
            ss[r] += vb * vb;
            float p = __shfl_xor(v, 1, 64);
            if ((n & 1) == 0 && grow < N)
                ftb[(size_t)grow * 96 + 8 * t + (n >> 1)] = packbf(v, p);
        }
    }
#pragma unroll
    for (int r = 0; r < 4; r++) {
#pragma unroll
        for (int off = 1; off < 16; off <<= 1) ss[r] += __shfl_xor(ss[r], off, 64);
        int grow = row0 + 16 * w + g * 4 + r;
        if (n == 0 && grow < N) inv2[2 * grow] = 1.f / fmaxf(sqrtf(ss[r]), 1e-12f);
    }
}

// ---------- MFMA GEMM: h_N = h + tanh([h|A]@[Wb1|Wb2]^T + b) -> hN half of ftb + inv2.y ----------
__global__ __launch_bounds__(256) void k_gemm_gate_mfma(const uint32* __restrict__ hb, const uint32* __restrict__ hN0b,
                                                        const float* __restrict__ h,
                                                        const float* __restrict__ W1, const float* __restrict__ W2,
                                                        const float* __restrict__ b1, const float* __restrict__ b2,
                                                        uint32* __restrict__ ftb, float* __restrict__ inv2, int N) {
    __shared__ uint32 As[64 * 52];
    __shared__ uint32 Ws[96 * 52];
    int tid = threadIdx.x;
    int lane = tid & 63;
    int w = tid >> 6;
    int row0 = blockIdx.x * 64;
    int n = lane & 15, g = lane >> 4;

    f32x4 acc[6];
#pragma unroll
    for (int t = 0; t < 6; t++) acc[t] = (f32x4){0.f, 0.f, 0.f, 0.f};

    for (int chunk = 0; chunk < 2; chunk++) {
        {
            const uint32* src = chunk ? hN0b : hb;
            int r = tid >> 2, j = tid & 3;
            int grow = row0 + r;
            if (grow < N) {
#pragma unroll
                for (int m = 0; m < 3; m++) {
                    uint4 u = *(const uint4*)(src + (size_t)grow * 48 + j * 12 + m * 4);
                    *(uint4*)&As[r * 52 + j * 12 + m * 4] = u;
                }
            } else {
#pragma unroll
                for (int m = 0; m < 12; m++) As[r * 52 + j * 12 + m] = 0u;
            }
        }
        {
            const float* Wsrc = chunk ? W2 : W1;
            for (int i = tid; i < 96 * 24; i += 256) {
                int r = i / 24, seg = i % 24;
                float4 v = *(const float4*)(Wsrc + (size_t)r * H + seg * 4);
                Ws[r * 52 + seg * 2]     = packbf(v.x, v.y);
                Ws[r * 52 + seg * 2 + 1] = packbf(v.z, v.w);
            }
        }
        __syncthreads();
#pragma unroll
        for (int s = 0; s < 3; s++) {
            int kb = s * 16 + g * 4;
            bf16x8 a = *(const bf16x8*)&As[(16 * w + n) * 52 + kb];
#pragma unroll
            for (int t = 0; t < 6; t++) {
                bf16x8 bb = *(const bf16x8*)&Ws[(16 * t + n) * 52 + kb];
                acc[t] = __builtin_amdgcn_mfma_f32_16x16x32_bf16(a, bb, acc[t], 0, 0, 0);
            }
        }
        __syncthreads();
    }
    float ss[4] = {0.f, 0.f, 0.f, 0.f};
#pragma unroll
    for (int t = 0; t < 6; t++) {
        int col = 16 * t + n;
        float bsum = b1[col] + b2[col];
#pragma unroll
        for (int r = 0; r < 4; r++) {
            int grow = row0 + 16 * w + g * 4 + r;
            float hval = (grow < N) ? h[(size_t)grow * H + col] : 0.f;
            float v = hval + tanh_fast(acc[t][r] + bsum);
            float vb = bfround(v);
            ss[r] += vb * vb;
            float p = __shfl_xor(v, 1, 64);
            if ((n & 1) == 0 && grow < N)
                ftb[(size_t)grow * 96 + 48 + 8 * t + (n >> 1)] = packbf(v, p);
        }
    }
#pragma unroll
    for (int r = 0; r < 4; r++) {
#pragma unroll
        for (int off = 1; off < 16; off <<= 1) ss[r] += __shfl_xor(ss[r], off, 64);
        int grow = row0 + 16 * w + g * 4 + r;
        if (n == 0 && grow < N) inv2[2 * grow + 1] = 1.f / fmaxf(sqrtf(ss[r]), 1e-12f);
    }
}

// ---------- h (f32) -> bf16 table + inverse norm ----------
__global__ __launch_bounds__(256) void k_cvt_h(const float* __restrict__ h, uint32* __restrict__ hb,
                                               float* __restrict__ inv, int N) {
    int wid = (blockIdx.x * blockDim.x + threadIdx.x) >> 6;
    int lane = threadIdx.x & 63;
    if (wid >= N) return;
    const float2* row = (const float2*)(h + (size_t)wid * H);
    float ss = 0.f;
    if (lane < 48) {
        float2 v = row[lane];
        uint32 p = packbf(v.x, v.y);
        hb[(size_t)wid * 48 + lane] = p;
        float a = bflo(p), b = bfhi(p);
        ss = a * a + b * b;
    }
#pragma unroll
    for (int off = 32; off; off >>= 1) ss += __shfl_xor(ss, off, 64);
    if (lane == 0) inv[wid] = 1.f / fmaxf(sqrtf(ss), 1e-12f);
}

// ---------- fused AGNN on h: 8 lanes/edge x 8 edges/iter, 3-stage pipeline ----------
__global__ __launch_bounds__(256, 8) void k_fused_h(const uint32* __restrict__ hb, const float* __restrict__ invn,
                                                    const int* __restrict__ rs, const int* __restrict__ csr_src,
                                                    const float* __restrict__ betas, uint32* __restrict__ outb, int N) {
    int wid = (blockIdx.x * blockDim.x + threadIdx.x) >> 6;
    int lane = threadIdx.x & 63;
    if (wid >= N) return;
    int d8 = lane & 7;
    int e8 = lane >> 3;
    float beta = betas[1];
    float shift = fabsf(beta);
    const uint32* dbase = hb + (size_t)wid * 48 + 6 * d8;
    float invd = invn[wid];
    uint2 dw0 = *(const uint2*)dbase, dw1 = *(const uint2*)(dbase + 2), dw2 = *(const uint2*)(dbase + 4);
    float dn[12] = {bflo(dw0.x) * invd, bfhi(dw0.x) * invd, bflo(dw0.y) * invd, bfhi(dw0.y) * invd,
                    bflo(dw1.x) * invd, bfhi(dw1.x) * invd, bflo(dw1.y) * invd, bfhi(dw1.y) * invd,
                    bflo(dw2.x) * invd, bfhi(dw2.x) * invd, bflo(dw2.y) * invd, bfhi(dw2.y) * invd};
    int s0 = rs[wid], s1 = rs[wid + 1];
    int nIter = (s1 - s0 + 7) >> 3;
    int idx0 = s0 + e8;

    // stage A (iter 0)
    bool vA = idx0 < s1;
    int snA = csr_src[vA ? idx0 : s0];
    const uint32* rbA = hb + (size_t)snA * 48 + 6 * d8;
    uint2 A0 = *(const uint2*)rbA, A1 = *(const uint2*)(rbA + 2), A2 = *(const uint2*)(rbA + 4);
    float iA = invn[snA];
    // stage B (iter 1)
    int idx1 = idx0 + 8;
    bool vB = idx1 < s1;
    int snB = csr_src[vB ? idx1 : s0];
    const uint32* rbB = hb + (size_t)snB * 48 + 6 * d8;
    uint2 B0 = *(const uint2*)rbB, B1 = *(const uint2*)(rbB + 2), B2 = *(const uint2*)(rbB + 4);
    float iB = invn[snB];

    float den = 0.f;
    float acc[12] = {0, 0, 0, 0, 0, 0, 0, 0, 0, 0, 0, 0};
    for (int it = 0; it < nIter; ++it) {
        // prefetch stage C (iter it+2)
        int idxC = idx0 + 8 * (it + 2);
        bool vCn = idxC < s1;
        int snC = csr_src[vCn ? idxC : s0];
        const uint32* rbC = hb + (size_t)snC * 48 + 6 * d8;
        uint2 C0 = *(const uint2*)rbC, C1 = *(const uint2*)(rbC + 2), C2 = *(const uint2*)(rbC + 4);
        float iC = invn[snC];
        // compute stage A
        float v[12] = {bflo(A0.x), bfhi(A0.x), bflo(A0.y), bfhi(A0.y),
                       bflo(A1.x), bfhi(A1.x), bflo(A1.y), bfhi(A1.y),
                       bflo(A2.x), bfhi(A2.x), bflo(A2.y), bfhi(A2.y)};
        float d = 0.f;
#pragma unroll
        for (int j = 0; j < 12; j++) d += v[j] * dn[j];
        d += __shfl_xor(d, 1, 64);
        d += __shfl_xor(d, 2, 64);
        d += __shfl_xor(d, 4, 64);
        float w = __expf(beta * (d * iA) - shift);
        if (!vA) w = 0.f;
        den += w;
#pragma unroll
        for (int j = 0; j < 12; j++) acc[j] += w * v[j];
        // shift stages
        A0 = B0; A1 = B1; A2 = B2; iA = iB; vA = vB;
        B0 = C0; B1 = C1; B2 = C2; iB = iC; vB = vCn;
    }
    den += __shfl_xor(den, 8, 64);
    den += __shfl_xor(den, 16, 64);
    den += __shfl_xor(den, 32, 64);
#pragma unroll
    for (int j = 0; j < 12; j++) {
        acc[j] += __shfl_xor(acc[j], 8, 64);
        acc[j] += __shfl_xor(acc[j], 16, 64);
        acc[j] += __shfl_xor(acc[j], 32, 64);
    }
    if (e8 == 0) {
        float r = 1.f / den;
        uint32* op = outb + (size_t)wid * 48 + 6 * d8;
        uint2 o0, o1, o2;
        o0.x = packbf(acc[0] * r, acc[1] * r);  o0.y = packbf(acc[2] * r, acc[3] * r);
        o1.x = packbf(acc[4] * r, acc[5] * r);  o1.y = packbf(acc[6] * r, acc[7] * r);
        o2.x = packbf(acc[8] * r, acc[9] * r);  o2.y = packbf(acc[10] * r, acc[11] * r);
        *(uint2*)op = o0; *(uint2*)(op + 2) = o1; *(uint2*)(op + 4) = o2;
    }
}

// ---------- fused gate kernel: merged table, role-split, fast tanh, 3-stage pipeline ----------
__global__ __launch_bounds__(256, 8) void k_fused_gates(const uint32* __restrict__ ftb, const float* __restrict__ inv2,
                                                        const int* __restrict__ rs, const int* __restrict__ csr_src,
                                                        const float* __restrict__ betas, const float* __restrict__ cold,
                                                        float* __restrict__ hout, float* __restrict__ cout_, int N) {
    int wid = (blockIdx.x * blockDim.x + threadIdx.x) >> 6;
    int lane = threadIdx.x & 63;
    if (wid >= N) return;
    float bx0 = betas[2], bh0 = betas[3];
    float bx1 = betas[4], bh1 = betas[5];
    float bx2 = betas[6], bh2 = betas[7];
    float bx3 = betas[8], bh3 = betas[9];
    bool uni = (bx0 == bx1) && (bx0 == bx2) && (bx0 == bx3) &&
               (bh0 == bh1) && (bh0 == bh2) && (bh0 == bh3);
    int s0 = rs[wid], s1 = rs[wid + 1];
    size_t rowbase = (size_t)wid * H;

    if (uni) {
        int l16 = lane & 15, q = lane >> 4;
        int sub = l16 >> 3;      // 0 = xt, 1 = hN
        int d8  = l16 & 7;       // dims [12*d8, 12*d8+12) of its feature
        float bsel = sub ? bh0 : bx0;
        float ssel = fabsf(bsel);
        const uint32* dbase = ftb + (size_t)wid * 96 + sub * 48 + 6 * d8;
        float invd = inv2[2 * wid + sub];
        uint2 dw0 = *(const uint2*)dbase, dw1 = *(const uint2*)(dbase + 2), dw2 = *(const uint2*)(dbase + 4);
        float dn[12] = {bflo(dw0.x) * invd, bfhi(dw0.x) * invd, bflo(dw0.y) * invd, bfhi(dw0.y) * invd,
                        bflo(dw1.x) * invd, bfhi(dw1.x) * invd, bflo(dw1.y) * invd, bfhi(dw1.y) * invd,
                        bflo(dw2.x) * invd, bfhi(dw2.x) * invd, bflo(dw2.y) * invd, bfhi(dw2.y) * invd};
        int nIter = (s1 - s0 + 3) >> 2;
        int idx0 = s0 + q;

        // stage A (iter 0)
        bool vA = idx0 < s1;
        int snA = csr_src[vA ? idx0 : s0];
        const uint32* rbA = ftb + (size_t)snA * 96 + sub * 48 + 6 * d8;
        uint2 A0 = *(const uint2*)rbA, A1 = *(const uint2*)(rbA + 2), A2 = *(const uint2*)(rbA + 4);
        float iA = inv2[2 * snA + sub];
        // stage B (iter 1)
        int idx1 = idx0 + 4;
        bool vB = idx1 < s1;
        int snB = csr_src[vB ? idx1 : s0];
        const uint32* rbB = ftb + (size_t)snB * 96 + sub * 48 + 6 * d8;
        uint2 B0 = *(const uint2*)rbB, B1 = *(const uint2*)(rbB + 2), B2 = *(const uint2*)(rbB + 4);
        float iB = inv2[2 * snB + sub];

        float den = 0.f;
        float acc[12] = {0, 0, 0, 0, 0, 0, 0, 0, 0, 0, 0, 0};
        for (int it = 0; it < nIter; ++it) {
            // prefetch stage C (iter it+2)
            int idxC = idx0 + 4 * (it + 2);
            bool vCn = idxC < s1;
            int snC = csr_src[vCn ? idxC : s0];
            const uint32* rbC = ftb + (size_t)snC * 96 + sub * 48 + 6 * d8;
            uint2 C0 = *(const uint2*)rbC, C1 = *(const uint2*)(rbC + 2), C2 = *(const uint2*)(rbC + 4);
            float iC = inv2[2 * snC + sub];
            // compute stage A
            float v[12] = {bflo(A0.x), bfhi(A0.x), bflo(A0.y), bfhi(A0.y),
                           bflo(A1.x), bfhi(A1.x), bflo(A1.y), bfhi(A1.y),
                           bflo(A2.x), bfhi(A2.x), bflo(A2.y), bfhi(A2.y)};
            float d = 0.f;
#pragma unroll
            for (int j = 0; j < 12; j++) d += v[j] * dn[j];
            d += __shfl_xor(d, 1, 64);
            d += __shfl_xor(d, 2, 64);
            d += __shfl_xor(d, 4, 64);
            float w = __expf(bsel * (d * iA) - ssel);
            if (!vA) w = 0.f;
            den += w;
#pragma unroll
            for (int j = 0; j < 12; j++) acc[j] += w * v[j];
            // shift stages
            A0 = B0; A1 = B1; A2 = B2; iA = iB; vA = vB;
            B0 = C0; B1 = C1; B2 = C2; iB = iC; vB = vCn;
        }
        den += __shfl_xor(den, 16, 64);
        den += __shfl_xor(den, 32, 64);
#pragma unroll
        for (int j = 0; j < 12; j++) {
            acc[j] += __shfl_xor(acc[j], 16, 64);
            acc[j] += __shfl_xor(acc[j], 32, 64);
        }
        float oden = __shfl_xor(den, 8, 64);
        float oacc[12];
#pragma unroll
        for (int j = 0; j < 12; j++) oacc[j] = __shfl_xor(acc[j], 8, 64);
        if (q == 0 && sub == 0) {
            float rX = 1.f / den, rH = 1.f / oden;
            size_t ob = rowbase + 12 * d8;
            float4 cv0 = *(const float4*)(cold + ob);
            float4 cv1 = *(const float4*)(cold + ob + 4);
            float4 cv2 = *(const float4*)(cold + ob + 8);
            float cvv[12] = {cv0.x, cv0.y, cv0.z, cv0.w, cv1.x, cv1.y, cv1.z, cv1.w,
                             cv2.x, cv2.y, cv2.z, cv2.w};
            float ho[12], co[12];
#pragma unroll
            for (int j = 0; j < 12; j++) {
                float a   = acc[j] * rX + oacc[j] * rH;
                float sig = 1.f / (1.f + __expf(-a));   // f = i = o
                float ct  = tanh_fast(a);
                float cn  = sig * cvv[j] + sig * ct;
                ho[j] = sig * tanh_fast(cn);
                co[j] = cn;
            }
            *(float4*)(hout + ob)     = make_float4(ho[0], ho[1], ho[2], ho[3]);
            *(float4*)(hout + ob + 4) = make_float4(ho[4], ho[5], ho[6], ho[7]);
            *(float4*)(hout + ob + 8) = make_float4(ho[8], ho[9], ho[10], ho[11]);
            *(float4*)(cout_ + ob)     = make_float4(co[0], co[1], co[2], co[3]);
            *(float4*)(cout_ + ob + 4) = make_float4(co[4], co[5], co[6], co[7]);
            *(float4*)(cout_ + ob + 8) = make_float4(co[8], co[9], co[10], co[11]);
        }
    } else {
        // general 4-gate path (correctness fallback; arbitrary betas)
        int fi = lane & 15;
        int q  = lane >> 4;
        float ixd = inv2[2 * wid], ihd = inv2[2 * wid + 1];
        const uint32* xdp = ftb + (size_t)wid * 96 + 3 * fi;
        const uint32* hdp = ftb + (size_t)wid * 96 + 48 + 3 * fi;
        uint32 xu0 = xdp[0], xu1 = xdp[1], xu2 = xdp[2];
        uint32 hu0 = hdp[0], hu1 = hdp[1], hu2 = hdp[2];
        float xn[6] = {bflo(xu0) * ixd, bfhi(xu0) * ixd, bflo(xu1) * ixd,
                       bfhi(xu1) * ixd, bflo(xu2) * ixd, bfhi(xu2) * ixd};
        float hn[6] = {bflo(hu0) * ihd, bfhi(hu0) * ihd, bflo(hu1) * ihd,
                       bfhi(hu1) * ihd, bflo(hu2) * ihd, bfhi(hu2) * ihd};
        float sx[4] = {fabsf(bx0), fabsf(bx1), fabsf(bx2), fabsf(bx3)};
        float sh_[4] = {fabsf(bh0), fabsf(bh1), fabsf(bh2), fabsf(bh3)};
        float bxv[4] = {bx0, bx1, bx2, bx3};
        float bhv[4] = {bh0, bh1, bh2, bh3};
        float denX[4] = {0, 0, 0, 0}, denH[4] = {0, 0, 0, 0};
        float aX[4][6], aH[4][6];
#pragma unroll
        for (int g = 0; g < 4; g++)
#pragma unroll
            for (int j = 0; j < 6; j++) { aX[g][j] = 0.f; aH[g][j] = 0.f; }
        for (int s = s0; s < s1; s += 4) {
            int idx = s + q;
            bool valid = idx < s1;
            int sidx = valid ? idx : s0;
            int sn = csr_src[sidx];
            float isx = inv2[2 * sn], ish = inv2[2 * sn + 1];
            const uint32* xrp = ftb + (size_t)sn * 96 + 3 * fi;
            const uint32* hrp = ftb + (size_t)sn * 96 + 48 + 3 * fi;
            uint32 a0 = xrp[0], a1 = xrp[1], a2 = xrp[2];
            uint32 b0 = hrp[0], b1 = hrp[1], b2 = hrp[2];
            float xv[6] = {bflo(a0), bfhi(a0), bflo(a1), bfhi(a1), bflo(a2), bfhi(a2)};
            float hv[6] = {bflo(b0), bfhi(b0), bflo(b1), bfhi(b1), bflo(b2), bfhi(b2)};
            float dx = 0.f, dh = 0.f;
#pragma unroll
            for (int j = 0; j < 6; j++) { dx += xv[j] * xn[j]; dh += hv[j] * hn[j]; }
#pragma unroll
            for (int off = 8; off; off >>= 1) {
                dx += __shfl_xor(dx, off, 64);
                dh += __shfl_xor(dh, off, 64);
            }
            float cx = dx * isx, ch = dh * ish;
#pragma unroll
            for (int g = 0; g < 4; g++) {
                float wx = __expf(bxv[g] * cx - sx[g]);
                float wh = __expf(bhv[g] * ch - sh_[g]);
                if (!valid) { wx = 0.f; wh = 0.f; }
                denX[g] += wx; denH[g] += wh;
#pragma unroll
                for (int j = 0; j < 6; j++) { aX[g][j] += wx * xv[j]; aH[g][j] += wh * hv[j]; }
            }
        }
#pragma unroll
        for (int g = 0; g < 4; g++) {
            denX[g] += __shfl_xor(denX[g], 16, 64); denX[g] += __shfl_xor(denX[g], 32, 64);
            denH[g] += __shfl_xor(denH[g], 16, 64); denH[g] += __shfl_xor(denH[g], 32, 64);
#pragma unroll
            for (int j = 0; j < 6; j++) {
                aX[g][j] += __shfl_xor(aX[g][j], 16, 64); aX[g][j] += __shfl_xor(aX[g][j], 32, 64);
                aH[g][j] += __shfl_xor(aH[g][j], 16, 64); aH[g][j] += __shfl_xor(aH[g][j], 32, 64);
            }
        }
        if (q == 0) {
#pragma unroll
            for (int j = 0; j < 6; j++) {
                int d = 6 * fi + j;
                float a0 = aX[0][j] / denX[0] + aH[0][j] / denH[0];
                float a1 = aX[1][j] / denX[1] + aH[1][j] / denH[1];
                float a2 = aX[2][j] / denX[2] + aH[2][j] / denH[2];
                float a3 = aX[3][j] / denX[3] + aH[3][j] / denH[3];
                float f  = 1.f / (1.f + __expf(-a0));
                float i_ = 1.f / (1.f + __expf(-a1));
                float ct = tanh_fast(a2);
                float o  = 1.f / (1.f + __expf(-a3));
                float cv = cold[rowbase + d];
                float cn = f * cv + i_ * ct;
                hout[rowbase + d]  = o * tanh_fast(cn);
                cout_[rowbase + d] = cn;
            }
        }
    }
}

extern "C" void kernel_launch(void* const* d_in, const int* in_sizes, int n_in,
                              void* d_out, int out_size, void* d_ws, size_t ws_size,
                              hipStream_t stream) {
    const float* x        = (const float*)d_in[0];
    const int*   ei       = (const int*)d_in[1];
    const float* h        = (const float*)d_in[2];
    const float* c        = (const float*)d_in[3];
    const float* W_in     = (const float*)d_in[4];
    const float* b_in     = (const float*)d_in[5];
    const float* Wb1      = (const float*)d_in[10];
    const float* bb1      = (const float*)d_in[11];
    const float* Wb2      = (const float*)d_in[12];
    const float* bb2      = (const float*)d_in[13];
    const float* betas    = (const float*)d_in[14];

    int N  = in_sizes[0] / DIN;
    int E  = in_sizes[1] / 2;
    int Et = E + N;
    int NH = N * H;

    char* ws = (char*)d_ws;
    size_t off = 0;
    auto alloc = [&](size_t bytes) -> void* {
        void* p = ws + off;
        off = (off + bytes + 255) & ~(size_t)255;
        return p;
    };
    uint32* ftb  = (uint32*)alloc((size_t)N * 96 * 4);   // merged bf16 rows: [xt(48 u32) | hN(48 u32)]
    uint32* hb   = (uint32*)alloc((size_t)N * 48 * 4);   // h bf16 rows
    uint32* hN0b = (uint32*)alloc((size_t)N * 48 * 4);   // AGNN(h) bf16 rows
    float* inv2  = (float*)alloc((size_t)N * 2 * 4);     // (inv_xt, inv_hN) pairs
    int* csr_src = (int*)alloc((size_t)Et * 4);
    int* deg     = (int*)alloc((size_t)N * 4);
    int* rs      = (int*)alloc((size_t)(N + 1) * 4);
    int* cur     = (int*)alloc((size_t)N * 4);
    int* bsum    = (int*)alloc(64 * 4);
    float* inv_h = (float*)alloc((size_t)N * 4);

    int nb = (N + 1023) / 1024;
    int gblk = (N + 63) / 64;

    hipMemsetAsync(deg, 0, (size_t)N * 4, stream);
    k_hist<<<(Et + 255) / 256, 256, 0, stream>>>(ei, E, N, deg);
    k_scanA<<<nb, 256, 0, stream>>>(deg, rs, bsum, N);
    k_scanB<<<1, 64, 0, stream>>>(bsum, nb);
    k_scanC<<<(N + 255) / 256, 256, 0, stream>>>(rs, cur, bsum, N, Et);
    k_scatter<<<(Et + 255) / 256, 256, 0, stream>>>(ei, E, N, cur, csr_src);

    k_gemm_in_mfma<<<gblk, 256, 0, stream>>>(x, W_in, b_in, ftb, inv2, N);
    k_cvt_h<<<(N + 3) / 4, 256, 0, stream>>>(h, hb, inv_h, N);
    k_fused_h<<<(N + 3) / 4, 256, 0, stream>>>(hb, inv_h, rs, csr_src, betas, hN0b, N);

    k_gemm_gate_mfma<<<gblk, 256, 0, stream>>>(hb, hN0b, h, Wb1, Wb2, bb1, bb2, ftb, inv2, N);

    float* hout = (float*)d_out;
    float* cout_ = (float*)d_out + NH;
    k_fused_gates<<<(N + 3) / 4, 256, 0, stream>>>(ftb, inv2, rs, csr_src, betas, c, hout, cout_, N);
}

// Round 15
// 287.472 us; speedup vs baseline: 1.0422x; 1.0422x over previous
//
#include <hip/hip_runtime.h>
#include <hip/hip_bf16.h>

#define H 96
#define DIN 256

typedef unsigned int uint32;
typedef __attribute__((ext_vector_type(8))) short bf16x8;
typedef __attribute__((ext_vector_type(4))) float f32x4;
typedef __attribute__((ext_vector_type(2))) float f32x2;

__device__ __forceinline__ float bflo(uint32 u) { return __uint_as_float(u << 16); }
__device__ __forceinline__ float bfhi(uint32 u) { return __uint_as_float(u & 0xffff0000u); }
__device__ __forceinline__ uint32 packbf(float a, float b) {
    __hip_bfloat16 x = __float2bfloat16(a), y = __float2bfloat16(b);
    unsigned short lo = *reinterpret_cast<unsigned short*>(&x);
    unsigned short hi = *reinterpret_cast<unsigned short*>(&y);
    return (uint32)lo | ((uint32)hi << 16);
}
__device__ __forceinline__ float bfround(float a) {
    return __bfloat162float(__float2bfloat16(a));
}
// fast tanh: exact at saturation (exp overflow -> 1, underflow -> -1)
__device__ __forceinline__ float tanh_fast(float x) {
    float e = __expf(2.f * x);
    return 1.f - 2.f / (e + 1.f);
}
__device__ __forceinline__ f32x2 unpk(uint32 u) {
    return (f32x2){__uint_as_float(u << 16), __uint_as_float(u & 0xffff0000u)};
}

// ---------- CSR build ----------
__global__ void k_hist(const int* __restrict__ ei, int E, int N, int* __restrict__ deg) {
    int e = blockIdx.x * blockDim.x + threadIdx.x;
    int Et = E + N;
    if (e >= Et) return;
    int dst = (e < E) ? ei[E + e] : (e - E);
    atomicAdd(&deg[dst], 1);
}

__global__ __launch_bounds__(256) void k_scanA(const int* __restrict__ deg, int* __restrict__ rs,
                                               int* __restrict__ bsum, int n) {
    __shared__ int sh[256];
    int t = threadIdx.x;
    int base = blockIdx.x * 1024 + t * 4;
    int v[4];
    int s = 0;
#pragma unroll
    for (int j = 0; j < 4; j++) { v[j] = (base + j < n) ? deg[base + j] : 0; s += v[j]; }
    sh[t] = s;
    __syncthreads();
    for (int off = 1; off < 256; off <<= 1) {
        int tmp = (t >= off) ? sh[t - off] : 0;
        __syncthreads();
        sh[t] += tmp;
        __syncthreads();
    }
    int excl = sh[t] - s;
#pragma unroll
    for (int j = 0; j < 4; j++) {
        if (base + j < n) rs[base + j] = excl;
        excl += v[j];
    }
    if (t == 255) bsum[blockIdx.x] = sh[255];
}

__global__ void k_scanB(int* __restrict__ bsum, int nb) {
    int l = threadIdx.x;
    int orig = (l < nb) ? bsum[l] : 0;
    int v = orig;
#pragma unroll
    for (int off = 1; off < 64; off <<= 1) {
        int u = __shfl_up(v, off, 64);
        if (l >= off) v += u;
    }
    if (l < nb) bsum[l] = v - orig;
}

__global__ void k_scanC(int* __restrict__ rs, int* __restrict__ cur, const int* __restrict__ bsum,
                        int n, int total) {
    int i = blockIdx.x * blockDim.x + threadIdx.x;
    if (i < n) {
        int r = rs[i] + bsum[i >> 10];
        rs[i] = r;
        cur[i] = r;
    }
    if (i == 0) rs[n] = total;
}

__global__ void k_scatter(const int* __restrict__ ei, int E, int N,
                          int* __restrict__ cur, int* __restrict__ csr_src) {
    int e = blockIdx.x * blockDim.x + threadIdx.x;
    int Et = E + N;
    if (e >= Et) return;
    int src, dst;
    if (e < E) { src = ei[e]; dst = ei[E + e]; }
    else       { src = e - E; dst = e - E; }
    int pos = atomicAdd(&cur[dst], 1);
    csr_src[pos] = src;
}

// ---------- MFMA GEMM: xt half of ftb + inv2.x ----------
__global__ __launch_bounds__(256) void k_gemm_in_mfma(const float* __restrict__ x, const float* __restrict__ W,
                                                      const float* __restrict__ b, uint32* __restrict__ ftb,
                                                      float* __restrict__ inv2, int N) {
    __shared__ uint32 As[64 * 68];
    __shared__ uint32 Ws[96 * 68];
    int tid = threadIdx.x;
    int lane = tid & 63;
    int w = tid >> 6;
    int row0 = blockIdx.x * 64;
    int n = lane & 15, g = lane >> 4;

    f32x4 acc[6];
#pragma unroll
    for (int t = 0; t < 6; t++) acc[t] = (f32x4){0.f, 0.f, 0.f, 0.f};

    for (int kc = 0; kc < DIN; kc += 128) {
        for (int i = tid; i < 64 * 32; i += 256) {
            int r = i >> 5, seg = i & 31;
            int grow = row0 + r;
            float4 v = (grow < N) ? *(const float4*)(x + (size_t)grow * DIN + kc + seg * 4)
                                  : make_float4(0.f, 0.f, 0.f, 0.f);
            As[r * 68 + seg * 2]     = packbf(v.x, v.y);
            As[r * 68 + seg * 2 + 1] = packbf(v.z, v.w);
        }
        for (int i = tid; i < 96 * 32; i += 256) {
            int r = i >> 5, seg = i & 31;
            float4 v = *(const float4*)(W + (size_t)r * DIN + kc + seg * 4);
            Ws[r * 68 + seg * 2]     = packbf(v.x, v.y);
            Ws[r * 68 + seg * 2 + 1] = packbf(v.z, v.w);
        }
        __syncthreads();
#pragma unroll
        for (int s = 0; s < 4; s++) {
            int kb = s * 16 + g * 4;
            bf16x8 a = *(const bf16x8*)&As[(16 * w + n) * 68 + kb];
#pragma unroll
            for (int t = 0; t < 6; t++) {
                bf16x8 bb = *(const bf16x8*)&Ws[(16 * t + n) * 68 + kb];
                acc[t] = __builtin_amdgcn_mfma_f32_16x16x32_bf16(a, bb, acc[t], 0, 0, 0);
            }
        }
        __syncthreads();
    }
    float ss[4] = {0.f, 0.f, 0.f, 0.f};
#pragma unroll
    for (int t = 0; t < 6; t++) {
        int col = 16 * t + n;
        float bv = b[col];
#pragma unroll
        for (int r = 0; r < 4; r++) {
            int grow = row0 + 16 * w + g * 4 + r;
            float v = acc[t][r] + bv;
            float vb = bfround(v);
            ss[r] += vb * vb;
            float p = __shfl_xor(v, 1, 64);
            if ((n & 1) == 0 && grow < N)
                ftb[(size_t)grow * 96 + 8 * t + (n >> 1)] = packbf(v, p);
        }
    }
#pragma unroll
    for (int r = 0; r < 4; r++) {
#pragma unroll
        for (int off = 1; off < 16; off <<= 1) ss[r] += __shfl_xor(ss[r], off, 64);
        int grow = row0 + 16 * w + g * 4 + r;
        if (n == 0 && grow < N) inv2[2 * grow] = 1.f / fmaxf(sqrtf(ss[r]), 1e-12f);
    }
}

// ---------- MFMA GEMM: h_N = h + tanh([h|A]@[Wb1|Wb2]^T + b) -> hN half of ftb + inv2.y ----------
__global__ __launch_bounds__(256) void k_gemm_gate_mfma(const uint32* __restrict__ hb, const uint32* __restrict__ hN0b,
                                                        const float* __restrict__ h,
                                                        const float* __restrict__ W1, const float* __restrict__ W2,
                                                        const float* __restrict__ b1, const float* __restrict__ b2,
                                                        uint32* __restrict__ ftb, float* __restrict__ inv2, int N) {
    __shared__ uint32 As[64 * 52];
    __shared__ uint32 Ws[96 * 52];
    int tid = threadIdx.x;
    int lane = tid & 63;
    int w = tid >> 6;
    int row0 = blockIdx.x * 64;
    int n = lane & 15, g = lane >> 4;

    f32x4 acc[6];
#pragma unroll
    for (int t = 0; t < 6; t++) acc[t] = (f32x4){0.f, 0.f, 0.f, 0.f};

    for (int chunk = 0; chunk < 2; chunk++) {
        {
            const uint32* src = chunk ? hN0b : hb;
            int r = tid >> 2, j = tid & 3;
            int grow = row0 + r;
            if (grow < N) {
#pragma unroll
                for (int m = 0; m < 3; m++) {
                    uint4 u = *(const uint4*)(src + (size_t)grow * 48 + j * 12 + m * 4);
                    *(uint4*)&As[r * 52 + j * 12 + m * 4] = u;
                }
            } else {
#pragma unroll
                for (int m = 0; m < 12; m++) As[r * 52 + j * 12 + m] = 0u;
            }
        }
        {
            const float* Wsrc = chunk ? W2 : W1;
            for (int i = tid; i < 96 * 24; i += 256) {
                int r = i / 24, seg = i % 24;
                float4 v = *(const float4*)(Wsrc + (size_t)r * H + seg * 4);
                Ws[r * 52 + seg * 2]     = packbf(v.x, v.y);
                Ws[r * 52 + seg * 2 + 1] = packbf(v.z, v.w);
            }
        }
        __syncthreads();
#pragma unroll
        for (int s = 0; s < 3; s++) {
            int kb = s * 16 + g * 4;
            bf16x8 a = *(const bf16x8*)&As[(16 * w + n) * 52 + kb];
#pragma unroll
            for (int t = 0; t < 6; t++) {
                bf16x8 bb = *(const bf16x8*)&Ws[(16 * t + n) * 52 + kb];
                acc[t] = __builtin_amdgcn_mfma_f32_16x16x32_bf16(a, bb, acc[t], 0, 0, 0);
            }
        }
        __syncthreads();
    }
    float ss[4] = {0.f, 0.f, 0.f, 0.f};
#pragma unroll
    for (int t = 0; t < 6; t++) {
        int col = 16 * t + n;
        float bsum = b1[col] + b2[col];
#pragma unroll
        for (int r = 0; r < 4; r++) {
            int grow = row0 + 16 * w + g * 4 + r;
            float hval = (grow < N) ? h[(size_t)grow * H + col] : 0.f;
            float v = hval + tanh_fast(acc[t][r] + bsum);
            float vb = bfround(v);
            ss[r] += vb * vb;
            float p = __shfl_xor(v, 1, 64);
            if ((n & 1) == 0 && grow < N)
                ftb[(size_t)grow * 96 + 48 + 8 * t + (n >> 1)] = packbf(v, p);
        }
    }
#pragma unroll
    for (int r = 0; r < 4; r++) {
#pragma unroll
        for (int off = 1; off < 16; off <<= 1) ss[r] += __shfl_xor(ss[r], off, 64);
        int grow = row0 + 16 * w + g * 4 + r;
        if (n == 0 && grow < N) inv2[2 * grow + 1] = 1.f / fmaxf(sqrtf(ss[r]), 1e-12f);
    }
}

// ---------- h (f32) -> bf16 table + inverse norm ----------
__global__ __launch_bounds__(256) void k_cvt_h(const float* __restrict__ h, uint32* __restrict__ hb,
                                               float* __restrict__ inv, int N) {
    int wid = (blockIdx.x * blockDim.x + threadIdx.x) >> 6;
    int lane = threadIdx.x & 63;
    if (wid >= N) return;
    const float2* row = (const float2*)(h + (size_t)wid * H);
    float ss = 0.f;
    if (lane < 48) {
        float2 v = row[lane];
        uint32 p = packbf(v.x, v.y);
        hb[(size_t)wid * 48 + lane] = p;
        float a = bflo(p), b = bfhi(p);
        ss = a * a + b * b;
    }
#pragma unroll
    for (int off = 32; off; off >>= 1) ss += __shfl_xor(ss, off, 64);
    if (lane == 0) inv[wid] = 1.f / fmaxf(sqrtf(ss), 1e-12f);
}

// ---------- fused AGNN on h: 8 lanes/edge x 8 edges/iter, packed f32 math ----------
__global__ __launch_bounds__(256, 8) void k_fused_h(const uint32* __restrict__ hb, const float* __restrict__ invn,
                                                    const int* __restrict__ rs, const int* __restrict__ csr_src,
                                                    const float* __restrict__ betas, uint32* __restrict__ outb, int N) {
    int wid = (blockIdx.x * blockDim.x + threadIdx.x) >> 6;
    int lane = threadIdx.x & 63;
    if (wid >= N) return;
    int d8 = lane & 7;
    int e8 = lane >> 3;
    float beta = betas[1];
    float shift = fabsf(beta);
    const uint32* dbase = hb + (size_t)wid * 48 + 6 * d8;
    float invd = invn[wid];
    uint2 dw0 = *(const uint2*)dbase, dw1 = *(const uint2*)(dbase + 2), dw2 = *(const uint2*)(dbase + 4);
    f32x2 dn2[6];
    dn2[0] = unpk(dw0.x) * invd; dn2[1] = unpk(dw0.y) * invd;
    dn2[2] = unpk(dw1.x) * invd; dn2[3] = unpk(dw1.y) * invd;
    dn2[4] = unpk(dw2.x) * invd; dn2[5] = unpk(dw2.y) * invd;
    int s0 = rs[wid], s1 = rs[wid + 1];
    int nIter = (s1 - s0 + 7) >> 3;
    int idx0 = s0 + e8;
    bool vC = idx0 < s1;
    int snC = csr_src[vC ? idx0 : s0];
    const uint32* rb = hb + (size_t)snC * 48 + 6 * d8;
    uint2 c0 = *(const uint2*)rb, c1 = *(const uint2*)(rb + 2), c2 = *(const uint2*)(rb + 4);
    float invC = invn[snC];

    float den = 0.f;
    f32x2 acc2[6];
#pragma unroll
    for (int j = 0; j < 6; j++) acc2[j] = (f32x2){0.f, 0.f};
    for (int it = 0; it < nIter; ++it) {
        int idxN = idx0 + 8 * (it + 1);
        bool vN = idxN < s1;
        int snN = csr_src[vN ? idxN : s0];
        const uint32* rbn = hb + (size_t)snN * 48 + 6 * d8;
        uint2 n0 = *(const uint2*)rbn, n1 = *(const uint2*)(rbn + 2), n2 = *(const uint2*)(rbn + 4);
        float invN = invn[snN];
        f32x2 v2[6];
        v2[0] = unpk(c0.x); v2[1] = unpk(c0.y);
        v2[2] = unpk(c1.x); v2[3] = unpk(c1.y);
        v2[4] = unpk(c2.x); v2[5] = unpk(c2.y);
        f32x2 d2 = v2[0] * dn2[0];
#pragma unroll
        for (int j = 1; j < 6; j++) d2 += v2[j] * dn2[j];
        float d = d2.x + d2.y;
        d += __shfl_xor(d, 1, 64);
        d += __shfl_xor(d, 2, 64);
        d += __shfl_xor(d, 4, 64);
        float w = __expf(beta * (d * invC) - shift);
        if (!vC) w = 0.f;
        den += w;
#pragma unroll
        for (int j = 0; j < 6; j++) acc2[j] += w * v2[j];
        c0 = n0; c1 = n1; c2 = n2; invC = invN; vC = vN;
    }
    den += __shfl_xor(den, 8, 64);
    den += __shfl_xor(den, 16, 64);
    den += __shfl_xor(den, 32, 64);
#pragma unroll
    for (int j = 0; j < 6; j++) {
        acc2[j].x += __shfl_xor(acc2[j].x, 8, 64);
        acc2[j].y += __shfl_xor(acc2[j].y, 8, 64);
        acc2[j].x += __shfl_xor(acc2[j].x, 16, 64);
        acc2[j].y += __shfl_xor(acc2[j].y, 16, 64);
        acc2[j].x += __shfl_xor(acc2[j].x, 32, 64);
        acc2[j].y += __shfl_xor(acc2[j].y, 32, 64);
    }
    if (e8 == 0) {
        float r = 1.f / den;
        uint32* op = outb + (size_t)wid * 48 + 6 * d8;
        uint2 o0, o1, o2;
        o0.x = packbf(acc2[0].x * r, acc2[0].y * r);  o0.y = packbf(acc2[1].x * r, acc2[1].y * r);
        o1.x = packbf(acc2[2].x * r, acc2[2].y * r);  o1.y = packbf(acc2[3].x * r, acc2[3].y * r);
        o2.x = packbf(acc2[4].x * r, acc2[4].y * r);  o2.y = packbf(acc2[5].x * r, acc2[5].y * r);
        *(uint2*)op = o0; *(uint2*)(op + 2) = o1; *(uint2*)(op + 4) = o2;
    }
}

// ---------- fused gate kernel: merged table, role-split, fast tanh, packed f32 math ----------
__global__ __launch_bounds__(256, 8) void k_fused_gates(const uint32* __restrict__ ftb, const float* __restrict__ inv2,
                                                        const int* __restrict__ rs, const int* __restrict__ csr_src,
                                                        const float* __restrict__ betas, const float* __restrict__ cold,
                                                        float* __restrict__ hout, float* __restrict__ cout_, int N) {
    int wid = (blockIdx.x * blockDim.x + threadIdx.x) >> 6;
    int lane = threadIdx.x & 63;
    if (wid >= N) return;
    float bx0 = betas[2], bh0 = betas[3];
    float bx1 = betas[4], bh1 = betas[5];
    float bx2 = betas[6], bh2 = betas[7];
    float bx3 = betas[8], bh3 = betas[9];
    bool uni = (bx0 == bx1) && (bx0 == bx2) && (bx0 == bx3) &&
               (bh0 == bh1) && (bh0 == bh2) && (bh0 == bh3);
    int s0 = rs[wid], s1 = rs[wid + 1];
    size_t rowbase = (size_t)wid * H;

    if (uni) {
        int l16 = lane & 15, q = lane >> 4;
        int sub = l16 >> 3;      // 0 = xt, 1 = hN
        int d8  = l16 & 7;       // dims [12*d8, 12*d8+12) of its feature
        float bsel = sub ? bh0 : bx0;
        float ssel = fabsf(bsel);
        const uint32* dbase = ftb + (size_t)wid * 96 + sub * 48 + 6 * d8;
        float invd = inv2[2 * wid + sub];
        uint2 dw0 = *(const uint2*)dbase, dw1 = *(const uint2*)(dbase + 2), dw2 = *(const uint2*)(dbase + 4);
        f32x2 dn2[6];
        dn2[0] = unpk(dw0.x) * invd; dn2[1] = unpk(dw0.y) * invd;
        dn2[2] = unpk(dw1.x) * invd; dn2[3] = unpk(dw1.y) * invd;
        dn2[4] = unpk(dw2.x) * invd; dn2[5] = unpk(dw2.y) * invd;
        int nIter = (s1 - s0 + 3) >> 2;
        int idx0 = s0 + q;
        bool vC = idx0 < s1;
        int snC = csr_src[vC ? idx0 : s0];
        const uint32* rb = ftb + (size_t)snC * 96 + sub * 48 + 6 * d8;
        uint2 c0 = *(const uint2*)rb, c1 = *(const uint2*)(rb + 2), c2 = *(const uint2*)(rb + 4);
        float isC = inv2[2 * snC + sub];

        float den = 0.f;
        f32x2 acc2[6];
#pragma unroll
        for (int j = 0; j < 6; j++) acc2[j] = (f32x2){0.f, 0.f};
        for (int it = 0; it < nIter; ++it) {
            int idxN = idx0 + 4 * (it + 1);
            bool vN = idxN < s1;
            int snN = csr_src[vN ? idxN : s0];
            const uint32* rbn = ftb + (size_t)snN * 96 + sub * 48 + 6 * d8;
            uint2 n0 = *(const uint2*)rbn, n1 = *(const uint2*)(rbn + 2), n2 = *(const uint2*)(rbn + 4);
            float isN = inv2[2 * snN + sub];
            f32x2 v2[6];
            v2[0] = unpk(c0.x); v2[1] = unpk(c0.y);
            v2[2] = unpk(c1.x); v2[3] = unpk(c1.y);
            v2[4] = unpk(c2.x); v2[5] = unpk(c2.y);
            f32x2 d2 = v2[0] * dn2[0];
#pragma unroll
            for (int j = 1; j < 6; j++) d2 += v2[j] * dn2[j];
            float d = d2.x + d2.y;
            d += __shfl_xor(d, 1, 64);
            d += __shfl_xor(d, 2, 64);
            d += __shfl_xor(d, 4, 64);
            float w = __expf(bsel * (d * isC) - ssel);
            if (!vC) w = 0.f;
            den += w;
#pragma unroll
            for (int j = 0; j < 6; j++) acc2[j] += w * v2[j];
            c0 = n0; c1 = n1; c2 = n2; isC = isN; vC = vN;
        }
        den += __shfl_xor(den, 16, 64);
        den += __shfl_xor(den, 32, 64);
#pragma unroll
        for (int j = 0; j < 6; j++) {
            acc2[j].x += __shfl_xor(acc2[j].x, 16, 64);
            acc2[j].y += __shfl_xor(acc2[j].y, 16, 64);
            acc2[j].x += __shfl_xor(acc2[j].x, 32, 64);
            acc2[j].y += __shfl_xor(acc2[j].y, 32, 64);
        }
        float oden = __shfl_xor(den, 8, 64);
        float oacc[12];
#pragma unroll
        for (int j = 0; j < 6; j++) {
            oacc[2 * j]     = __shfl_xor(acc2[j].x, 8, 64);
            oacc[2 * j + 1] = __shfl_xor(acc2[j].y, 8, 64);
        }
        if (q == 0 && sub == 0) {
            float rX = 1.f / den, rH = 1.f / oden;
            size_t ob = rowbase + 12 * d8;
            float4 cv0 = *(const float4*)(cold + ob);
            float4 cv1 = *(const float4*)(cold + ob + 4);
            float4 cv2 = *(const float4*)(cold + ob + 8);
            float cvv[12] = {cv0.x, cv0.y, cv0.z, cv0.w, cv1.x, cv1.y, cv1.z, cv1.w,
                             cv2.x, cv2.y, cv2.z, cv2.w};
            float aj[12] = {acc2[0].x, acc2[0].y, acc2[1].x, acc2[1].y, acc2[2].x, acc2[2].y,
                            acc2[3].x, acc2[3].y, acc2[4].x, acc2[4].y, acc2[5].x, acc2[5].y};
            float ho[12], co[12];
#pragma unroll
            for (int j = 0; j < 12; j++) {
                float a   = aj[j] * rX + oacc[j] * rH;
                float sig = 1.f / (1.f + __expf(-a));   // f = i = o
                float ct  = tanh_fast(a);
                float cn  = sig * cvv[j] + sig * ct;
                ho[j] = sig * tanh_fast(cn);
                co[j] = cn;
            }
            *(float4*)(hout + ob)     = make_float4(ho[0], ho[1], ho[2], ho[3]);
            *(float4*)(hout + ob + 4) = make_float4(ho[4], ho[5], ho[6], ho[7]);
            *(float4*)(hout + ob + 8) = make_float4(ho[8], ho[9], ho[10], ho[11]);
            *(float4*)(cout_ + ob)     = make_float4(co[0], co[1], co[2], co[3]);
            *(float4*)(cout_ + ob + 4) = make_float4(co[4], co[5], co[6], co[7]);
            *(float4*)(cout_ + ob + 8) = make_float4(co[8], co[9], co[10], co[11]);
        }
    } else {
        // general 4-gate path (correctness fallback; arbitrary betas)
        int fi = lane & 15;
        int q  = lane >> 4;
        float ixd = inv2[2 * wid], ihd = inv2[2 * wid + 1];
        const uint32* xdp = ftb + (size_t)wid * 96 + 3 * fi;
        const uint32* hdp = ftb + (size_t)wid * 96 + 48 + 3 * fi;
        uint32 xu0 = xdp[0], xu1 = xdp[1], xu2 = xdp[2];
        uint32 hu0 = hdp[0], hu1 = hdp[1], hu2 = hdp[2];
        float xn[6] = {bflo(xu0) * ixd, bfhi(xu0) * ixd, bflo(xu1) * ixd,
                       bfhi(xu1) * ixd, bflo(xu2) * ixd, bfhi(xu2) * ixd};
        float hn[6] = {bflo(hu0) * ihd, bfhi(hu0) * ihd, bflo(hu1) * ihd,
                       bfhi(hu1) * ihd, bflo(hu2) * ihd, bfhi(hu2) * ihd};
        float sx[4] = {fabsf(bx0), fabsf(bx1), fabsf(bx2), fabsf(bx3)};
        float sh_[4] = {fabsf(bh0), fabsf(bh1), fabsf(bh2), fabsf(bh3)};
        float bxv[4] = {bx0, bx1, bx2, bx3};
        float bhv[4] = {bh0, bh1, bh2, bh3};
        float denX[4] = {0, 0, 0, 0}, denH[4] = {0, 0, 0, 0};
        float aX[4][6], aH[4][6];
#pragma unroll
        for (int g = 0; g < 4; g++)
#pragma unroll
            for (int j = 0; j < 6; j++) { aX[g][j] = 0.f; aH[g][j] = 0.f; }
        for (int s = s0; s < s1; s += 4) {
            int idx = s + q;
            bool valid = idx < s1;
            int sidx = valid ? idx : s0;
            int sn = csr_src[sidx];
            float isx = inv2[2 * sn], ish = inv2[2 * sn + 1];
            const uint32* xrp = ftb + (size_t)sn * 96 + 3 * fi;
            const uint32* hrp = ftb + (size_t)sn * 96 + 48 + 3 * fi;
            uint32 a0 = xrp[0], a1 = xrp[1], a2 = xrp[2];
            uint32 b0 = hrp[0], b1 = hrp[1], b2 = hrp[2];
            float xv[6] = {bflo(a0), bfhi(a0), bflo(a1), bfhi(a1), bflo(a2), bfhi(a2)};
            float hv[6] = {bflo(b0), bfhi(b0), bflo(b1), bfhi(b1), bflo(b2), bfhi(b2)};
            float dx = 0.f, dh = 0.f;
#pragma unroll
            for (int j = 0; j < 6; j++) { dx += xv[j] * xn[j]; dh += hv[j] * hn[j]; }
#pragma unroll
            for (int off = 8; off; off >>= 1) {
                dx += __shfl_xor(dx, off, 64);
                dh += __shfl_xor(dh, off, 64);
            }
            float cx = dx * isx, ch = dh * ish;
#pragma unroll
            for (int g = 0; g < 4; g++) {
                float wx = __expf(bxv[g] * cx - sx[g]);
                float wh = __expf(bhv[g] * ch - sh_[g]);
                if (!valid) { wx = 0.f; wh = 0.f; }
                denX[g] += wx; denH[g] += wh;
#pragma unroll
                for (int j = 0; j < 6; j++) { aX[g][j] += wx * xv[j]; aH[g][j] += wh * hv[j]; }
            }
        }
#pragma unroll
        for (int g = 0; g < 4; g++) {
            denX[g] += __shfl_xor(denX[g], 16, 64); denX[g] += __shfl_xor(denX[g], 32, 64);
            denH[g] += __shfl_xor(denH[g], 16, 64); denH[g] += __shfl_xor(denH[g], 32, 64);
#pragma unroll
            for (int j = 0; j < 6; j++) {
                aX[g][j] += __shfl_xor(aX[g][j], 16, 64); aX[g][j] += __shfl_xor(aX[g][j], 32, 64);
                aH[g][j] += __shfl_xor(aH[g][j], 16, 64); aH[g][j] += __shfl_xor(aH[g][j], 32, 64);
            }
        }
        if (q == 0) {
#pragma unroll
            for (int j = 0; j < 6; j++) {
                int d = 6 * fi + j;
                float a0 = aX[0][j] / denX[0] + aH[0][j] / denH[0];
                float a1 = aX[1][j] / denX[1] + aH[1][j] / denH[1];
                float a2 = aX[2][j] / denX[2] + aH[2][j] / denH[2];
                float a3 = aX[3][j] / denX[3] + aH[3][j] / denH[3];
                float f  = 1.f / (1.f + __expf(-a0));
                float i_ = 1.f / (1.f + __expf(-a1));
                float ct = tanh_fast(a2);
                float o  = 1.f / (1.f + __expf(-a3));
                float cv = cold[rowbase + d];
                float cn = f * cv + i_ * ct;
                hout[rowbase + d]  = o * tanh_fast(cn);
                cout_[rowbase + d] = cn;
            }
        }
    }
}

extern "C" void kernel_launch(void* const* d_in, const int* in_sizes, int n_in,
                              void* d_out, int out_size, void* d_ws, size_t ws_size,
                              hipStream_t stream) {
    const float* x        = (const float*)d_in[0];
    const int*   ei       = (const int*)d_in[1];
    const float* h        = (const float*)d_in[2];
    const float* c        = (const float*)d_in[3];
    const float* W_in     = (const float*)d_in[4];
    const float* b_in     = (const float*)d_in[5];
    const float* Wb1      = (const float*)d_in[10];
    const float* bb1      = (const float*)d_in[11];
    const float* Wb2      = (const float*)d_in[12];
    const float* bb2      = (const float*)d_in[13];
    const float* betas    = (const float*)d_in[14];

    int N  = in_sizes[0] / DIN;
    int E  = in_sizes[1] / 2;
    int Et = E + N;
    int NH = N * H;

    char* ws = (char*)d_ws;
    size_t off = 0;
    auto alloc = [&](size_t bytes) -> void* {
        void* p = ws + off;
        off = (off + bytes + 255) & ~(size_t)255;
        return p;
    };
    uint32* ftb  = (uint32*)alloc((size_t)N * 96 * 4);   // merged bf16 rows: [xt(48 u32) | hN(48 u32)]
    uint32* hb   = (uint32*)alloc((size_t)N * 48 * 4);   // h bf16 rows
    uint32* hN0b = (uint32*)alloc((size_t)N * 48 * 4);   // AGNN(h) bf16 rows
    float* inv2  = (float*)alloc((size_t)N * 2 * 4);     // (inv_xt, inv_hN) pairs
    int* csr_src = (int*)alloc((size_t)Et * 4);
    int* deg     = (int*)alloc((size_t)N * 4);
    int* rs      = (int*)alloc((size_t)(N + 1) * 4);
    int* cur     = (int*)alloc((size_t)N * 4);
    int* bsum    = (int*)alloc(64 * 4);
    float* inv_h = (float*)alloc((size_t)N * 4);

    int nb = (N + 1023) / 1024;
    int gblk = (N + 63) / 64;

    hipMemsetAsync(deg, 0, (size_t)N * 4, stream);
    k_hist<<<(Et + 255) / 256, 256, 0, stream>>>(ei, E, N, deg);
    k_scanA<<<nb, 256, 0, stream>>>(deg, rs, bsum, N);
    k_scanB<<<1, 64, 0, stream>>>(bsum, nb);
    k_scanC<<<(N + 255) / 256, 256, 0, stream>>>(rs, cur, bsum, N, Et);
    k_scatter<<<(Et + 255) / 256, 256, 0, stream>>>(ei, E, N, cur, csr_src);

    k_gemm_in_mfma<<<gblk, 256, 0, stream>>>(x, W_in, b_in, ftb, inv2, N);
    k_cvt_h<<<(N + 3) / 4, 256, 0, stream>>>(h, hb, inv_h, N);
    k_fused_h<<<(N + 3) / 4, 256, 0, stream>>>(hb, inv_h, rs, csr_src, betas, hN0b, N);

    k_gemm_gate_mfma<<<gblk, 256, 0, stream>>>(hb, hN0b, h, Wb1, Wb2, bb1, bb2, ftb, inv2, N);

    float* hout = (float*)d_out;
    float* cout_ = (float*)d_out + NH;
    k_fused_gates<<<(N + 3) / 4, 256, 0, stream>>>(ftb, inv2, rs, csr_src, betas, c, hout, cout_, N);
}

// Round 16
// 266.183 us; speedup vs baseline: 1.1256x; 1.0800x over previous
//
#include <hip/hip_runtime.h>
#include <hip/hip_bf16.h>

#define H 96
#define DIN 256

typedef unsigned int uint32;
typedef __attribute__((ext_vector_type(8))) short bf16x8;
typedef __attribute__((ext_vector_type(4))) float f32x4;
typedef __attribute__((ext_vector_type(2))) float f32x2;

__device__ __forceinline__ float bflo(uint32 u) { return __uint_as_float(u << 16); }
__device__ __forceinline__ float bfhi(uint32 u) { return __uint_as_float(u & 0xffff0000u); }
__device__ __forceinline__ uint32 packbf(float a, float b) {
    __hip_bfloat16 x = __float2bfloat16(a), y = __float2bfloat16(b);
    unsigned short lo = *reinterpret_cast<unsigned short*>(&x);
    unsigned short hi = *reinterpret_cast<unsigned short*>(&y);
    return (uint32)lo | ((uint32)hi << 16);
}
__device__ __forceinline__ float bfround(float a) {
    return __bfloat162float(__float2bfloat16(a));
}
// fast tanh: exact at saturation (exp overflow -> 1, underflow -> -1)
__device__ __forceinline__ float tanh_fast(float x) {
    float e = __expf(2.f * x);
    return 1.f - 2.f / (e + 1.f);
}
__device__ __forceinline__ f32x2 unpk(uint32 u) {
    return (f32x2){__uint_as_float(u << 16), __uint_as_float(u & 0xffff0000u)};
}

// ---------- CSR build ----------
__global__ void k_hist(const int* __restrict__ ei, int E, int N, int* __restrict__ deg) {
    int e = blockIdx.x * blockDim.x + threadIdx.x;
    int Et = E + N;
    if (e >= Et) return;
    int dst = (e < E) ? ei[E + e] : (e - E);
    atomicAdd(&deg[dst], 1);
}

__global__ __launch_bounds__(256) void k_scanA(const int* __restrict__ deg, int* __restrict__ rs,
                                               int* __restrict__ bsum, int n) {
    __shared__ int sh[256];
    int t = threadIdx.x;
    int base = blockIdx.x * 1024 + t * 4;
    int v[4];
    int s = 0;
#pragma unroll
    for (int j = 0; j < 4; j++) { v[j] = (base + j < n) ? deg[base + j] : 0; s += v[j]; }
    sh[t] = s;
    __syncthreads();
    for (int off = 1; off < 256; off <<= 1) {
        int tmp = (t >= off) ? sh[t - off] : 0;
        __syncthreads();
        sh[t] += tmp;
        __syncthreads();
    }
    int excl = sh[t] - s;
#pragma unroll
    for (int j = 0; j < 4; j++) {
        if (base + j < n) rs[base + j] = excl;
        excl += v[j];
    }
    if (t == 255) bsum[blockIdx.x] = sh[255];
}

__global__ void k_scanB(int* __restrict__ bsum, int nb) {
    int l = threadIdx.x;
    int orig = (l < nb) ? bsum[l] : 0;
    int v = orig;
#pragma unroll
    for (int off = 1; off < 64; off <<= 1) {
        int u = __shfl_up(v, off, 64);
        if (l >= off) v += u;
    }
    if (l < nb) bsum[l] = v - orig;
}

__global__ void k_scanC(int* __restrict__ rs, int* __restrict__ cur, const int* __restrict__ bsum,
                        int n, int total) {
    int i = blockIdx.x * blockDim.x + threadIdx.x;
    if (i < n) {
        int r = rs[i] + bsum[i >> 10];
        rs[i] = r;
        cur[i] = r;
    }
    if (i == 0) rs[n] = total;
}

__global__ void k_scatter(const int* __restrict__ ei, int E, int N,
                          int* __restrict__ cur, int* __restrict__ csr_src) {
    int e = blockIdx.x * blockDim.x + threadIdx.x;
    int Et = E + N;
    if (e >= Et) return;
    int src, dst;
    if (e < E) { src = ei[e]; dst = ei[E + e]; }
    else       { src = e - E; dst = e - E; }
    int pos = atomicAdd(&cur[dst], 1);
    csr_src[pos] = src;
}

// ---------- MFMA GEMM: xt half of ftb + inv2.x ----------
__global__ __launch_bounds__(256) void k_gemm_in_mfma(const float* __restrict__ x, const float* __restrict__ W,
                                                      const float* __restrict__ b, uint32* __restrict__ ftb,
                                                      float* __restrict__ inv2, int N) {
    __shared__ uint32 As[64 * 68];
    __shared__ uint32 Ws[96 * 68];
    int tid = threadIdx.x;
    int lane = tid & 63;
    int w = tid >> 6;
    int row0 = blockIdx.x * 64;
    int n = lane & 15, g = lane >> 4;

    f32x4 acc[6];
#pragma unroll
    for (int t = 0; t < 6; t++) acc[t] = (f32x4){0.f, 0.f, 0.f, 0.f};

    for (int kc = 0; kc < DIN; kc += 128) {
        for (int i = tid; i < 64 * 32; i += 256) {
            int r = i >> 5, seg = i & 31;
            int grow = row0 + r;
            float4 v = (grow < N) ? *(const float4*)(x + (size_t)grow * DIN + kc + seg * 4)
                                  : make_float4(0.f, 0.f, 0.f, 0.f);
            As[r * 68 + seg * 2]     = packbf(v.x, v.y);
            As[r * 68 + seg * 2 + 1] = packbf(v.z, v.w);
        }
        for (int i = tid; i < 96 * 32; i += 256) {
            int r = i >> 5, seg = i & 31;
            float4 v = *(const float4*)(W + (size_t)r * DIN + kc + seg * 4);
            Ws[r * 68 + seg * 2]     = packbf(v.x, v.y);
            Ws[r * 68 + seg * 2 + 1] = packbf(v.z, v.w);
        }
        __syncthreads();
#pragma unroll
        for (int s = 0; s < 4; s++) {
            int kb = s * 16 + g * 4;
            bf16x8 a = *(const bf16x8*)&As[(16 * w + n) * 68 + kb];
#pragma unroll
            for (int t = 0; t < 6; t++) {
                bf16x8 bb = *(const bf16x8*)&Ws[(16 * t + n) * 68 + kb];
                acc[t] = __builtin_amdgcn_mfma_f32_16x16x32_bf16(a, bb, acc[t], 0, 0, 0);
            }
        }
        __syncthreads();
    }
    float ss[4] = {0.f, 0.f, 0.f, 0.f};
#pragma unroll
    for (int t = 0; t < 6; t++) {
        int col = 16 * t + n;
        float bv = b[col];
#pragma unroll
        for (int r = 0; r < 4; r++) {
            int grow = row0 + 16 * w + g * 4 + r;
            float v = acc[t][r] + bv;
            float vb = bfround(v);
            ss[r] += vb * vb;
            float p = __shfl_xor(v, 1, 64);
            if ((n & 1) == 0 && grow < N)
                ftb[(size_t)grow * 96 + 8 * t + (n >> 1)] = packbf(v, p);
        }
    }
#pragma unroll
    for (int r = 0; r < 4; r++) {
#pragma unroll
        for (int off = 1; off < 16; off <<= 1) ss[r] += __shfl_xor(ss[r], off, 64);
        int grow = row0 + 16 * w + g * 4 + r;
        if (n == 0 && grow < N) inv2[2 * grow] = 1.f / fmaxf(sqrtf(ss[r]), 1e-12f);
    }
}

// ---------- MFMA GEMM: h_N = h + tanh([h|A]@[Wb1|Wb2]^T + b) -> hN half of ftb + inv2.y ----------
__global__ __launch_bounds__(256) void k_gemm_gate_mfma(const uint32* __restrict__ hb, const uint32* __restrict__ hN0b,
                                                        const float* __restrict__ h,
                                                        const float* __restrict__ W1, const float* __restrict__ W2,
                                                        const float* __restrict__ b1, const float* __restrict__ b2,
                                                        uint32* __restrict__ ftb, float* __restrict__ inv2, int N) {
    __shared__ uint32 As[64 * 52];
    __shared__ uint32 Ws[96 * 52];
    int tid = threadIdx.x;
    int lane = tid & 63;
    int w = tid >> 6;
    int row0 = blockIdx.x * 64;
    int n = lane & 15, g = lane >> 4;

    f32x4 acc[6];
#pragma unroll
    for (int t = 0; t < 6; t++) acc[t] = (f32x4){0.f, 0.f, 0.f, 0.f};

    for (int chunk = 0; chunk < 2; chunk++) {
        {
            const uint32* src = chunk ? hN0b : hb;
            int r = tid >> 2, j = tid & 3;
            int grow = row0 + r;
            if (grow < N) {
#pragma unroll
                for (int m = 0; m < 3; m++) {
                    uint4 u = *(const uint4*)(src + (size_t)grow * 48 + j * 12 + m * 4);
                    *(uint4*)&As[r * 52 + j * 12 + m * 4] = u;
                }
            } else {
#pragma unroll
                for (int m = 0; m < 12; m++) As[r * 52 + j * 12 + m] = 0u;
            }
        }
        {
            const float* Wsrc = chunk ? W2 : W1;
            for (int i = tid; i < 96 * 24; i += 256) {
                int r = i / 24, seg = i % 24;
                float4 v = *(const float4*)(Wsrc + (size_t)r * H + seg * 4);
                Ws[r * 52 + seg * 2]     = packbf(v.x, v.y);
                Ws[r * 52 + seg * 2 + 1] = packbf(v.z, v.w);
            }
        }
        __syncthreads();
#pragma unroll
        for (int s = 0; s < 3; s++) {
            int kb = s * 16 + g * 4;
            bf16x8 a = *(const bf16x8*)&As[(16 * w + n) * 52 + kb];
#pragma unroll
            for (int t = 0; t < 6; t++) {
                bf16x8 bb = *(const bf16x8*)&Ws[(16 * t + n) * 52 + kb];
                acc[t] = __builtin_amdgcn_mfma_f32_16x16x32_bf16(a, bb, acc[t], 0, 0, 0);
            }
        }
        __syncthreads();
    }
    float ss[4] = {0.f, 0.f, 0.f, 0.f};
#pragma unroll
    for (int t = 0; t < 6; t++) {
        int col = 16 * t + n;
        float bsum = b1[col] + b2[col];
#pragma unroll
        for (int r = 0; r < 4; r++) {
            int grow = row0 + 16 * w + g * 4 + r;
            float hval = (grow < N) ? h[(size_t)grow * H + col] : 0.f;
            float v = hval + tanh_fast(acc[t][r] + bsum);
            float vb = bfround(v);
            ss[r] += vb * vb;
            float p = __shfl_xor(v, 1, 64);
            if ((n & 1) == 0 && grow < N)
                ftb[(size_t)grow * 96 + 48 + 8 * t + (n >> 1)] = packbf(v, p);
        }
    }
#pragma unroll
    for (int r = 0; r < 4; r++) {
#pragma unroll
        for (int off = 1; off < 16; off <<= 1) ss[r] += __shfl_xor(ss[r], off, 64);
        int grow = row0 + 16 * w + g * 4 + r;
        if (n == 0 && grow < N) inv2[2 * grow + 1] = 1.f / fmaxf(sqrtf(ss[r]), 1e-12f);
    }
}

// ---------- h (f32) -> bf16 table + inverse norm ----------
__global__ __launch_bounds__(256) void k_cvt_h(const float* __restrict__ h, uint32* __restrict__ hb,
                                               float* __restrict__ inv, int N) {
    int wid = (blockIdx.x * blockDim.x + threadIdx.x) >> 6;
    int lane = threadIdx.x & 63;
    if (wid >= N) return;
    const float2* row = (const float2*)(h + (size_t)wid * H);
    float ss = 0.f;
    if (lane < 48) {
        float2 v = row[lane];
        uint32 p = packbf(v.x, v.y);
        hb[(size_t)wid * 48 + lane] = p;
        float a = bflo(p), b = bfhi(p);
        ss = a * a + b * b;
    }
#pragma unroll
    for (int off = 32; off; off >>= 1) ss += __shfl_xor(ss, off, 64);
    if (lane == 0) inv[wid] = 1.f / fmaxf(sqrtf(ss), 1e-12f);
}

// ---------- fused AGNN on h: 8 lanes/edge x 8 edges/iter, packed f32 math ----------
__global__ __launch_bounds__(256, 8) void k_fused_h(const uint32* __restrict__ hb, const float* __restrict__ invn,
                                                    const int* __restrict__ rs, const int* __restrict__ csr_src,
                                                    const float* __restrict__ betas, uint32* __restrict__ outb, int N) {
    int wid = (blockIdx.x * blockDim.x + threadIdx.x) >> 6;
    int lane = threadIdx.x & 63;
    if (wid >= N) return;
    int d8 = lane & 7;
    int e8 = lane >> 3;
    float beta = betas[1];
    float shift = fabsf(beta);
    const uint32* dbase = hb + (size_t)wid * 48 + 6 * d8;
    float invd = invn[wid];
    uint2 dw0 = *(const uint2*)dbase, dw1 = *(const uint2*)(dbase + 2), dw2 = *(const uint2*)(dbase + 4);
    f32x2 dn2[6];
    dn2[0] = unpk(dw0.x) * invd; dn2[1] = unpk(dw0.y) * invd;
    dn2[2] = unpk(dw1.x) * invd; dn2[3] = unpk(dw1.y) * invd;
    dn2[4] = unpk(dw2.x) * invd; dn2[5] = unpk(dw2.y) * invd;
    int s0 = rs[wid], s1 = rs[wid + 1];
    int nIter = (s1 - s0 + 7) >> 3;
    int idx0 = s0 + e8;
    bool vC = idx0 < s1;
    int snC = csr_src[vC ? idx0 : s0];
    const uint32* rb = hb + (size_t)snC * 48 + 6 * d8;
    uint2 c0 = *(const uint2*)rb, c1 = *(const uint2*)(rb + 2), c2 = *(const uint2*)(rb + 4);
    float invC = invn[snC];

    float den = 0.f;
    f32x2 acc2[6];
#pragma unroll
    for (int j = 0; j < 6; j++) acc2[j] = (f32x2){0.f, 0.f};
    for (int it = 0; it < nIter; ++it) {
        int idxN = idx0 + 8 * (it + 1);
        bool vN = idxN < s1;
        int snN = csr_src[vN ? idxN : s0];
        const uint32* rbn = hb + (size_t)snN * 48 + 6 * d8;
        uint2 n0 = *(const uint2*)rbn, n1 = *(const uint2*)(rbn + 2), n2 = *(const uint2*)(rbn + 4);
        float invN = invn[snN];
        f32x2 v2[6];
        v2[0] = unpk(c0.x); v2[1] = unpk(c0.y);
        v2[2] = unpk(c1.x); v2[3] = unpk(c1.y);
        v2[4] = unpk(c2.x); v2[5] = unpk(c2.y);
        f32x2 d2 = v2[0] * dn2[0];
#pragma unroll
        for (int j = 1; j < 6; j++) d2 += v2[j] * dn2[j];
        float d = d2.x + d2.y;
        d += __shfl_xor(d, 1, 64);
        d += __shfl_xor(d, 2, 64);
        d += __shfl_xor(d, 4, 64);
        float w = __expf(beta * (d * invC) - shift);
        if (!vC) w = 0.f;
        den += w;
#pragma unroll
        for (int j = 0; j < 6; j++) acc2[j] += w * v2[j];
        c0 = n0; c1 = n1; c2 = n2; invC = invN; vC = vN;
    }
    den += __shfl_xor(den, 8, 64);
    den += __shfl_xor(den, 16, 64);
    den += __shfl_xor(den, 32, 64);
#pragma unroll
    for (int j = 0; j < 6; j++) {
        acc2[j].x += __shfl_xor(acc2[j].x, 8, 64);
        acc2[j].y += __shfl_xor(acc2[j].y, 8, 64);
        acc2[j].x += __shfl_xor(acc2[j].x, 16, 64);
        acc2[j].y += __shfl_xor(acc2[j].y, 16, 64);
        acc2[j].x += __shfl_xor(acc2[j].x, 32, 64);
        acc2[j].y += __shfl_xor(acc2[j].y, 32, 64);
    }
    if (e8 == 0) {
        float r = 1.f / den;
        uint32* op = outb + (size_t)wid * 48 + 6 * d8;
        uint2 o0, o1, o2;
        o0.x = packbf(acc2[0].x * r, acc2[0].y * r);  o0.y = packbf(acc2[1].x * r, acc2[1].y * r);
        o1.x = packbf(acc2[2].x * r, acc2[2].y * r);  o1.y = packbf(acc2[3].x * r, acc2[3].y * r);
        o2.x = packbf(acc2[4].x * r, acc2[4].y * r);  o2.y = packbf(acc2[5].x * r, acc2[5].y * r);
        *(uint2*)op = o0; *(uint2*)(op + 2) = o1; *(uint2*)(op + 4) = o2;
    }
}

// ---------- fused gate kernel: merged table, role-split, 4-way-parallel LSTM epilogue ----------
__global__ __launch_bounds__(256, 8) void k_fused_gates(const uint32* __restrict__ ftb, const float* __restrict__ inv2,
                                                        const int* __restrict__ rs, const int* __restrict__ csr_src,
                                                        const float* __restrict__ betas, const float* __restrict__ cold,
                                                        float* __restrict__ hout, float* __restrict__ cout_, int N) {
    int wid = (blockIdx.x * blockDim.x + threadIdx.x) >> 6;
    int lane = threadIdx.x & 63;
    if (wid >= N) return;
    float bx0 = betas[2], bh0 = betas[3];
    float bx1 = betas[4], bh1 = betas[5];
    float bx2 = betas[6], bh2 = betas[7];
    float bx3 = betas[8], bh3 = betas[9];
    bool uni = (bx0 == bx1) && (bx0 == bx2) && (bx0 == bx3) &&
               (bh0 == bh1) && (bh0 == bh2) && (bh0 == bh3);
    int s0 = rs[wid], s1 = rs[wid + 1];
    size_t rowbase = (size_t)wid * H;

    if (uni) {
        int l16 = lane & 15, q = lane >> 4;
        int sub = l16 >> 3;      // 0 = xt, 1 = hN
        int d8  = l16 & 7;       // dims [12*d8, 12*d8+12) of its feature
        float bsel = sub ? bh0 : bx0;
        float ssel = fabsf(bsel);
        const uint32* dbase = ftb + (size_t)wid * 96 + sub * 48 + 6 * d8;
        float invd = inv2[2 * wid + sub];
        uint2 dw0 = *(const uint2*)dbase, dw1 = *(const uint2*)(dbase + 2), dw2 = *(const uint2*)(dbase + 4);
        f32x2 dn2[6];
        dn2[0] = unpk(dw0.x) * invd; dn2[1] = unpk(dw0.y) * invd;
        dn2[2] = unpk(dw1.x) * invd; dn2[3] = unpk(dw1.y) * invd;
        dn2[4] = unpk(dw2.x) * invd; dn2[5] = unpk(dw2.y) * invd;
        int nIter = (s1 - s0 + 3) >> 2;
        int idx0 = s0 + q;
        bool vC = idx0 < s1;
        int snC = csr_src[vC ? idx0 : s0];
        const uint32* rb = ftb + (size_t)snC * 96 + sub * 48 + 6 * d8;
        uint2 c0 = *(const uint2*)rb, c1 = *(const uint2*)(rb + 2), c2 = *(const uint2*)(rb + 4);
        float isC = inv2[2 * snC + sub];

        float den = 0.f;
        f32x2 acc2[6];
#pragma unroll
        for (int j = 0; j < 6; j++) acc2[j] = (f32x2){0.f, 0.f};
        for (int it = 0; it < nIter; ++it) {
            int idxN = idx0 + 4 * (it + 1);
            bool vN = idxN < s1;
            int snN = csr_src[vN ? idxN : s0];
            const uint32* rbn = ftb + (size_t)snN * 96 + sub * 48 + 6 * d8;
            uint2 n0 = *(const uint2*)rbn, n1 = *(const uint2*)(rbn + 2), n2 = *(const uint2*)(rbn + 4);
            float isN = inv2[2 * snN + sub];
            f32x2 v2[6];
            v2[0] = unpk(c0.x); v2[1] = unpk(c0.y);
            v2[2] = unpk(c1.x); v2[3] = unpk(c1.y);
            v2[4] = unpk(c2.x); v2[5] = unpk(c2.y);
            f32x2 d2 = v2[0] * dn2[0];
#pragma unroll
            for (int j = 1; j < 6; j++) d2 += v2[j] * dn2[j];
            float d = d2.x + d2.y;
            d += __shfl_xor(d, 1, 64);
            d += __shfl_xor(d, 2, 64);
            d += __shfl_xor(d, 4, 64);
            float w = __expf(bsel * (d * isC) - ssel);
            if (!vC) w = 0.f;
            den += w;
#pragma unroll
            for (int j = 0; j < 6; j++) acc2[j] += w * v2[j];
            c0 = n0; c1 = n1; c2 = n2; isC = isN; vC = vN;
        }
        den += __shfl_xor(den, 16, 64);
        den += __shfl_xor(den, 32, 64);
#pragma unroll
        for (int j = 0; j < 6; j++) {
            acc2[j].x += __shfl_xor(acc2[j].x, 16, 64);
            acc2[j].y += __shfl_xor(acc2[j].y, 16, 64);
            acc2[j].x += __shfl_xor(acc2[j].x, 32, 64);
            acc2[j].y += __shfl_xor(acc2[j].y, 32, 64);
        }
        // after the butterfly, all q-lanes hold full sums; exchange xt<->hN halves
        float oden = __shfl_xor(den, 8, 64);
        float oacc[12];
#pragma unroll
        for (int j = 0; j < 6; j++) {
            oacc[2 * j]     = __shfl_xor(acc2[j].x, 8, 64);
            oacc[2 * j + 1] = __shfl_xor(acc2[j].y, 8, 64);
        }
        // 4-way parallel epilogue: all sub==0 lanes active; lane q handles dims 12*d8 + 3q + {0,1,2}
        if (sub == 0) {
            float rX = 1.f / den, rH = 1.f / oden;   // sub=0: own acc = xt side, oacc = hN side
            float a0f = acc2[0].x, a1f = acc2[0].y, a2f = acc2[1].x, a3f = acc2[1].y;
            float a4f = acc2[2].x, a5f = acc2[2].y, a6f = acc2[3].x, a7f = acc2[3].y;
            float a8f = acc2[4].x, a9f = acc2[4].y, a10f = acc2[5].x, a11f = acc2[5].y;
            float aX0 = q == 0 ? a0f : q == 1 ? a3f : q == 2 ? a6f : a9f;
            float aX1 = q == 0 ? a1f : q == 1 ? a4f : q == 2 ? a7f : a10f;
            float aX2 = q == 0 ? a2f : q == 1 ? a5f : q == 2 ? a8f : a11f;
            float aH0 = q == 0 ? oacc[0] : q == 1 ? oacc[3] : q == 2 ? oacc[6] : oacc[9];
            float aH1 = q == 0 ? oacc[1] : q == 1 ? oacc[4] : q == 2 ? oacc[7] : oacc[10];
            float aH2 = q == 0 ? oacc[2] : q == 1 ? oacc[5] : q == 2 ? oacc[8] : oacc[11];
            size_t ob = rowbase + 12 * d8 + 3 * q;
            float aA[3] = {aX0 * rX + aH0 * rH, aX1 * rX + aH1 * rH, aX2 * rX + aH2 * rH};
            float cvs[3] = {cold[ob], cold[ob + 1], cold[ob + 2]};
            float ho[3], co[3];
#pragma unroll
            for (int t = 0; t < 3; t++) {
                float a   = aA[t];
                float sig = 1.f / (1.f + __expf(-a));   // f = i = o
                float ct  = tanh_fast(a);
                float cn  = sig * cvs[t] + sig * ct;
                ho[t] = sig * tanh_fast(cn);
                co[t] = cn;
            }
            hout[ob]     = ho[0]; hout[ob + 1]  = ho[1]; hout[ob + 2]  = ho[2];
            cout_[ob]    = co[0]; cout_[ob + 1] = co[1]; cout_[ob + 2] = co[2];
        }
    } else {
        // general 4-gate path (correctness fallback; arbitrary betas)
        int fi = lane & 15;
        int q  = lane >> 4;
        float ixd = inv2[2 * wid], ihd = inv2[2 * wid + 1];
        const uint32* xdp = ftb + (size_t)wid * 96 + 3 * fi;
        const uint32* hdp = ftb + (size_t)wid * 96 + 48 + 3 * fi;
        uint32 xu0 = xdp[0], xu1 = xdp[1], xu2 = xdp[2];
        uint32 hu0 = hdp[0], hu1 = hdp[1], hu2 = hdp[2];
        float xn[6] = {bflo(xu0) * ixd, bfhi(xu0) * ixd, bflo(xu1) * ixd,
                       bfhi(xu1) * ixd, bflo(xu2) * ixd, bfhi(xu2) * ixd};
        float hn[6] = {bflo(hu0) * ihd, bfhi(hu0) * ihd, bflo(hu1) * ihd,
                       bfhi(hu1) * ihd, bflo(hu2) * ihd, bfhi(hu2) * ihd};
        float sx[4] = {fabsf(bx0), fabsf(bx1), fabsf(bx2), fabsf(bx3)};
        float sh_[4] = {fabsf(bh0), fabsf(bh1), fabsf(bh2), fabsf(bh3)};
        float bxv[4] = {bx0, bx1, bx2, bx3};
        float bhv[4] = {bh0, bh1, bh2, bh3};
        float denX[4] = {0, 0, 0, 0}, denH[4] = {0, 0, 0, 0};
        float aX[4][6], aH[4][6];
#pragma unroll
        for (int g = 0; g < 4; g++)
#pragma unroll
            for (int j = 0; j < 6; j++) { aX[g][j] = 0.f; aH[g][j] = 0.f; }
        for (int s = s0; s < s1; s += 4) {
            int idx = s + q;
            bool valid = idx < s1;
            int sidx = valid ? idx : s0;
            int sn = csr_src[sidx];
            float isx = inv2[2 * sn], ish = inv2[2 * sn + 1];
            const uint32* xrp = ftb + (size_t)sn * 96 + 3 * fi;
            const uint32* hrp = ftb + (size_t)sn * 96 + 48 + 3 * fi;
            uint32 a0 = xrp[0], a1 = xrp[1], a2 = xrp[2];
            uint32 b0 = hrp[0], b1 = hrp[1], b2 = hrp[2];
            float xv[6] = {bflo(a0), bfhi(a0), bflo(a1), bfhi(a1), bflo(a2), bfhi(a2)};
            float hv[6] = {bflo(b0), bfhi(b0), bflo(b1), bfhi(b1), bflo(b2), bfhi(b2)};
            float dx = 0.f, dh = 0.f;
#pragma unroll
            for (int j = 0; j < 6; j++) { dx += xv[j] * xn[j]; dh += hv[j] * hn[j]; }
#pragma unroll
            for (int off = 8; off; off >>= 1) {
                dx += __shfl_xor(dx, off, 64);
                dh += __shfl_xor(dh, off, 64);
            }
            float cx = dx * isx, ch = dh * ish;
#pragma unroll
            for (int g = 0; g < 4; g++) {
                float wx = __expf(bxv[g] * cx - sx[g]);
                float wh = __expf(bhv[g] * ch - sh_[g]);
                if (!valid) { wx = 0.f; wh = 0.f; }
                denX[g] += wx; denH[g] += wh;
#pragma unroll
                for (int j = 0; j < 6; j++) { aX[g][j] += wx * xv[j]; aH[g][j] += wh * hv[j]; }
            }
        }
#pragma unroll
        for (int g = 0; g < 4; g++) {
            denX[g] += __shfl_xor(denX[g], 16, 64); denX[g] += __shfl_xor(denX[g], 32, 64);
            denH[g] += __shfl_xor(denH[g], 16, 64); denH[g] += __shfl_xor(denH[g], 32, 64);
#pragma unroll
            for (int j = 0; j < 6; j++) {
                aX[g][j] += __shfl_xor(aX[g][j], 16, 64); aX[g][j] += __shfl_xor(aX[g][j], 32, 64);
                aH[g][j] += __shfl_xor(aH[g][j], 16, 64); aH[g][j] += __shfl_xor(aH[g][j], 32, 64);
            }
        }
        if (q == 0) {
#pragma unroll
            for (int j = 0; j < 6; j++) {
                int d = 6 * fi + j;
                float a0 = aX[0][j] / denX[0] + aH[0][j] / denH[0];
                float a1 = aX[1][j] / denX[1] + aH[1][j] / denH[1];
                float a2 = aX[2][j] / denX[2] + aH[2][j] / denH[2];
                float a3 = aX[3][j] / denX[3] + aH[3][j] / denH[3];
                float f  = 1.f / (1.f + __expf(-a0));
                float i_ = 1.f / (1.f + __expf(-a1));
                float ct = tanh_fast(a2);
                float o  = 1.f / (1.f + __expf(-a3));
                float cv = cold[rowbase + d];
                float cn = f * cv + i_ * ct;
                hout[rowbase + d]  = o * tanh_fast(cn);
                cout_[rowbase + d] = cn;
            }
        }
    }
}

extern "C" void kernel_launch(void* const* d_in, const int* in_sizes, int n_in,
                              void* d_out, int out_size, void* d_ws, size_t ws_size,
                              hipStream_t stream) {
    const float* x        = (const float*)d_in[0];
    const int*   ei       = (const int*)d_in[1];
    const float* h        = (const float*)d_in[2];
    const float* c        = (const float*)d_in[3];
    const float* W_in     = (const float*)d_in[4];
    const float* b_in     = (const float*)d_in[5];
    const float* Wb1      = (const float*)d_in[10];
    const float* bb1      = (const float*)d_in[11];
    const float* Wb2      = (const float*)d_in[12];
    const float* bb2      = (const float*)d_in[13];
    const float* betas    = (const float*)d_in[14];

    int N  = in_sizes[0] / DIN;
    int E  = in_sizes[1] / 2;
    int Et = E + N;
    int NH = N * H;

    char* ws = (char*)d_ws;
    size_t off = 0;
    auto alloc = [&](size_t bytes) -> void* {
        void* p = ws + off;
        off = (off + bytes + 255) & ~(size_t)255;
        return p;
    };
    uint32* ftb  = (uint32*)alloc((size_t)N * 96 * 4);   // merged bf16 rows: [xt(48 u32) | hN(48 u32)]
    uint32* hb   = (uint32*)alloc((size_t)N * 48 * 4);   // h bf16 rows
    uint32* hN0b = (uint32*)alloc((size_t)N * 48 * 4);   // AGNN(h) bf16 rows
    float* inv2  = (float*)alloc((size_t)N * 2 * 4);     // (inv_xt, inv_hN) pairs
    int* csr_src = (int*)alloc((size_t)Et * 4);
    int* deg     = (int*)alloc((size_t)N * 4);
    int* rs      = (int*)alloc((size_t)(N + 1) * 4);
    int* cur     = (int*)alloc((size_t)N * 4);
    int* bsum    = (int*)alloc(64 * 4);
    float* inv_h = (float*)alloc((size_t)N * 4);

    int nb = (N + 1023) / 1024;
    int gblk = (N + 63) / 64;

    hipMemsetAsync(deg, 0, (size_t)N * 4, stream);
    k_hist<<<(Et + 255) / 256, 256, 0, stream>>>(ei, E, N, deg);
    k_scanA<<<nb, 256, 0, stream>>>(deg, rs, bsum, N);
    k_scanB<<<1, 64, 0, stream>>>(bsum, nb);
    k_scanC<<<(N + 255) / 256, 256, 0, stream>>>(rs, cur, bsum, N, Et);
    k_scatter<<<(Et + 255) / 256, 256, 0, stream>>>(ei, E, N, cur, csr_src);

    k_gemm_in_mfma<<<gblk, 256, 0, stream>>>(x, W_in, b_in, ftb, inv2, N);
    k_cvt_h<<<(N + 3) / 4, 256, 0, stream>>>(h, hb, inv_h, N);
    k_fused_h<<<(N + 3) / 4, 256, 0, stream>>>(hb, inv_h, rs, csr_src, betas, hN0b, N);

    k_gemm_gate_mfma<<<gblk, 256, 0, stream>>>(hb, hN0b, h, Wb1, Wb2, bb1, bb2, ftb, inv2, N);

    float* hout = (float*)d_out;
    float* cout_ = (float*)d_out + NH;
    k_fused_gates<<<(N + 3) / 4, 256, 0, stream>>>(ftb, inv2, rs, csr_src, betas, c, hout, cout_, N);
}

// Round 17
// 264.443 us; speedup vs baseline: 1.1330x; 1.0066x over previous
//
#include <hip/hip_runtime.h>
#include <hip/hip_bf16.h>

#define H 96
#define DIN 256

typedef unsigned int uint32;
typedef __attribute__((ext_vector_type(8))) short bf16x8;
typedef __attribute__((ext_vector_type(4))) float f32x4;
typedef __attribute__((ext_vector_type(2))) float f32x2;

__device__ __forceinline__ float bflo(uint32 u) { return __uint_as_float(u << 16); }
__device__ __forceinline__ float bfhi(uint32 u) { return __uint_as_float(u & 0xffff0000u); }
__device__ __forceinline__ uint32 packbf(float a, float b) {
    __hip_bfloat16 x = __float2bfloat16(a), y = __float2bfloat16(b);
    unsigned short lo = *reinterpret_cast<unsigned short*>(&x);
    unsigned short hi = *reinterpret_cast<unsigned short*>(&y);
    return (uint32)lo | ((uint32)hi << 16);
}
__device__ __forceinline__ float bfround(float a) {
    return __bfloat162float(__float2bfloat16(a));
}
// fast tanh: exact at saturation (exp overflow -> 1, underflow -> -1)
__device__ __forceinline__ float tanh_fast(float x) {
    float e = __expf(2.f * x);
    return 1.f - 2.f / (e + 1.f);
}
__device__ __forceinline__ f32x2 unpk(uint32 u) {
    return (f32x2){__uint_as_float(u << 16), __uint_as_float(u & 0xffff0000u)};
}

// ---------- CSR build ----------
__global__ void k_hist(const int* __restrict__ ei, int E, int N, int* __restrict__ deg) {
    int e = blockIdx.x * blockDim.x + threadIdx.x;
    int Et = E + N;
    if (e >= Et) return;
    int dst = (e < E) ? ei[E + e] : (e - E);
    atomicAdd(&deg[dst], 1);
}

__global__ __launch_bounds__(256) void k_scanA(const int* __restrict__ deg, int* __restrict__ rs,
                                               int* __restrict__ bsum, int n) {
    __shared__ int sh[256];
    int t = threadIdx.x;
    int base = blockIdx.x * 1024 + t * 4;
    int v[4];
    int s = 0;
#pragma unroll
    for (int j = 0; j < 4; j++) { v[j] = (base + j < n) ? deg[base + j] : 0; s += v[j]; }
    sh[t] = s;
    __syncthreads();
    for (int off = 1; off < 256; off <<= 1) {
        int tmp = (t >= off) ? sh[t - off] : 0;
        __syncthreads();
        sh[t] += tmp;
        __syncthreads();
    }
    int excl = sh[t] - s;
#pragma unroll
    for (int j = 0; j < 4; j++) {
        if (base + j < n) rs[base + j] = excl;
        excl += v[j];
    }
    if (t == 255) bsum[blockIdx.x] = sh[255];
}

__global__ void k_scanB(int* __restrict__ bsum, int nb) {
    int l = threadIdx.x;
    int orig = (l < nb) ? bsum[l] : 0;
    int v = orig;
#pragma unroll
    for (int off = 1; off < 64; off <<= 1) {
        int u = __shfl_up(v, off, 64);
        if (l >= off) v += u;
    }
    if (l < nb) bsum[l] = v - orig;
}

__global__ void k_scanC(int* __restrict__ rs, int* __restrict__ cur, const int* __restrict__ bsum,
                        int n, int total) {
    int i = blockIdx.x * blockDim.x + threadIdx.x;
    if (i < n) {
        int r = rs[i] + bsum[i >> 10];
        rs[i] = r;
        cur[i] = r;
    }
    if (i == 0) rs[n] = total;
}

__global__ void k_scatter(const int* __restrict__ ei, int E, int N,
                          int* __restrict__ cur, int* __restrict__ csr_src) {
    int e = blockIdx.x * blockDim.x + threadIdx.x;
    int Et = E + N;
    if (e >= Et) return;
    int src, dst;
    if (e < E) { src = ei[e]; dst = ei[E + e]; }
    else       { src = e - E; dst = e - E; }
    int pos = atomicAdd(&cur[dst], 1);
    csr_src[pos] = src;
}

// ---------- MFMA GEMM: xt half of ftb + inv2.x ----------
__global__ __launch_bounds__(256) void k_gemm_in_mfma(const float* __restrict__ x, const float* __restrict__ W,
                                                      const float* __restrict__ b, uint32* __restrict__ ftb,
                                                      float* __restrict__ inv2, int N) {
    __shared__ uint32 As[64 * 68];
    __shared__ uint32 Ws[96 * 68];
    int tid = threadIdx.x;
    int lane = tid & 63;
    int w = tid >> 6;
    int row0 = blockIdx.x * 64;
    int n = lane & 15, g = lane >> 4;

    f32x4 acc[6];
#pragma unroll
    for (int t = 0; t < 6; t++) acc[t] = (f32x4){0.f, 0.f, 0.f, 0.f};

    for (int kc = 0; kc < DIN; kc += 128) {
        for (int i = tid; i < 64 * 32; i += 256) {
            int r = i >> 5, seg = i & 31;
            int grow = row0 + r;
            float4 v = (grow < N) ? *(const float4*)(x + (size_t)grow * DIN + kc + seg * 4)
                                  : make_float4(0.f, 0.f, 0.f, 0.f);
            As[r * 68 + seg * 2]     = packbf(v.x, v.y);
            As[r * 68 + seg * 2 + 1] = packbf(v.z, v.w);
        }
        for (int i = tid; i < 96 * 32; i += 256) {
            int r = i >> 5, seg = i & 31;
            float4 v = *(const float4*)(W + (size_t)r * DIN + kc + seg * 4);
            Ws[r * 68 + seg * 2]     = packbf(v.x, v.y);
            Ws[r * 68 + seg * 2 + 1] = packbf(v.z, v.w);
        }
        __syncthreads();
#pragma unroll
        for (int s = 0; s < 4; s++) {
            int kb = s * 16 + g * 4;
            bf16x8 a = *(const bf16x8*)&As[(16 * w + n) * 68 + kb];
#pragma unroll
            for (int t = 0; t < 6; t++) {
                bf16x8 bb = *(const bf16x8*)&Ws[(16 * t + n) * 68 + kb];
                acc[t] = __builtin_amdgcn_mfma_f32_16x16x32_bf16(a, bb, acc[t], 0, 0, 0);
            }
        }
        __syncthreads();
    }
    float ss[4] = {0.f, 0.f, 0.f, 0.f};
#pragma unroll
    for (int t = 0; t < 6; t++) {
        int col = 16 * t + n;
        float bv = b[col];
#pragma unroll
        for (int r = 0; r < 4; r++) {
            int grow = row0 + 16 * w + g * 4 + r;
            float v = acc[t][r] + bv;
            float vb = bfround(v);
            ss[r] += vb * vb;
            float p = __shfl_xor(v, 1, 64);
            if ((n & 1) == 0 && grow < N)
                ftb[(size_t)grow * 96 + 8 * t + (n >> 1)] = packbf(v, p);
        }
    }
#pragma unroll
    for (int r = 0; r < 4; r++) {
#pragma unroll
        for (int off = 1; off < 16; off <<= 1) ss[r] += __shfl_xor(ss[r], off, 64);
        int grow = row0 + 16 * w + g * 4 + r;
        if (n == 0 && grow < N) inv2[2 * grow] = 1.f / fmaxf(sqrtf(ss[r]), 1e-12f);
    }
}

// ---------- MFMA GEMM: h_N = h + tanh([h|A]@[Wb1|Wb2]^T + b) -> hN half of ftb + inv2.y ----------
__global__ __launch_bounds__(256) void k_gemm_gate_mfma(const uint32* __restrict__ hb, const uint32* __restrict__ hN0b,
                                                        const float* __restrict__ h,
                                                        const float* __restrict__ W1, const float* __restrict__ W2,
                                                        const float* __restrict__ b1, const float* __restrict__ b2,
                                                        uint32* __restrict__ ftb, float* __restrict__ inv2, int N) {
    __shared__ uint32 As[64 * 52];
    __shared__ uint32 Ws[96 * 52];
    int tid = threadIdx.x;
    int lane = tid & 63;
    int w = tid >> 6;
    int row0 = blockIdx.x * 64;
    int n = lane & 15, g = lane >> 4;

    f32x4 acc[6];
#pragma unroll
    for (int t = 0; t < 6; t++) acc[t] = (f32x4){0.f, 0.f, 0.f, 0.f};

    for (int chunk = 0; chunk < 2; chunk++) {
        {
            const uint32* src = chunk ? hN0b : hb;
            int r = tid >> 2, j = tid & 3;
            int grow = row0 + r;
            if (grow < N) {
#pragma unroll
                for (int m = 0; m < 3; m++) {
                    uint4 u = *(const uint4*)(src + (size_t)grow * 48 + j * 12 + m * 4);
                    *(uint4*)&As[r * 52 + j * 12 + m * 4] = u;
                }
            } else {
#pragma unroll
                for (int m = 0; m < 12; m++) As[r * 52 + j * 12 + m] = 0u;
            }
        }
        {
            const float* Wsrc = chunk ? W2 : W1;
            for (int i = tid; i < 96 * 24; i += 256) {
                int r = i / 24, seg = i % 24;
                float4 v = *(const float4*)(Wsrc + (size_t)r * H + seg * 4);
                Ws[r * 52 + seg * 2]     = packbf(v.x, v.y);
                Ws[r * 52 + seg * 2 + 1] = packbf(v.z, v.w);
            }
        }
        __syncthreads();
#pragma unroll
        for (int s = 0; s < 3; s++) {
            int kb = s * 16 + g * 4;
            bf16x8 a = *(const bf16x8*)&As[(16 * w + n) * 52 + kb];
#pragma unroll
            for (int t = 0; t < 6; t++) {
                bf16x8 bb = *(const bf16x8*)&Ws[(16 * t + n) * 52 + kb];
                acc[t] = __builtin_amdgcn_mfma_f32_16x16x32_bf16(a, bb, acc[t], 0, 0, 0);
            }
        }
        __syncthreads();
    }
    float ss[4] = {0.f, 0.f, 0.f, 0.f};
#pragma unroll
    for (int t = 0; t < 6; t++) {
        int col = 16 * t + n;
        float bsum = b1[col] + b2[col];
#pragma unroll
        for (int r = 0; r < 4; r++) {
            int grow = row0 + 16 * w + g * 4 + r;
            float hval = (grow < N) ? h[(size_t)grow * H + col] : 0.f;
            float v = hval + tanh_fast(acc[t][r] + bsum);
            float vb = bfround(v);
            ss[r] += vb * vb;
            float p = __shfl_xor(v, 1, 64);
            if ((n & 1) == 0 && grow < N)
                ftb[(size_t)grow * 96 + 48 + 8 * t + (n >> 1)] = packbf(v, p);
        }
    }
#pragma unroll
    for (int r = 0; r < 4; r++) {
#pragma unroll
        for (int off = 1; off < 16; off <<= 1) ss[r] += __shfl_xor(ss[r], off, 64);
        int grow = row0 + 16 * w + g * 4 + r;
        if (n == 0 && grow < N) inv2[2 * grow + 1] = 1.f / fmaxf(sqrtf(ss[r]), 1e-12f);
    }
}

// ---------- h (f32) -> bf16 table + inverse norm ----------
__global__ __launch_bounds__(256) void k_cvt_h(const float* __restrict__ h, uint32* __restrict__ hb,
                                               float* __restrict__ inv, int N) {
    int wid = (blockIdx.x * blockDim.x + threadIdx.x) >> 6;
    int lane = threadIdx.x & 63;
    if (wid >= N) return;
    const float2* row = (const float2*)(h + (size_t)wid * H);
    float ss = 0.f;
    if (lane < 48) {
        float2 v = row[lane];
        uint32 p = packbf(v.x, v.y);
        hb[(size_t)wid * 48 + lane] = p;
        float a = bflo(p), b = bfhi(p);
        ss = a * a + b * b;
    }
#pragma unroll
    for (int off = 32; off; off >>= 1) ss += __shfl_xor(ss, off, 64);
    if (lane == 0) inv[wid] = 1.f / fmaxf(sqrtf(ss), 1e-12f);
}

// ---------- fused AGNN on h: 8 lanes/edge x 8 edges/iter, ping-pong pipeline ----------
__global__ __launch_bounds__(256, 8) void k_fused_h(const uint32* __restrict__ hb, const float* __restrict__ invn,
                                                    const int* __restrict__ rs, const int* __restrict__ csr_src,
                                                    const float* __restrict__ betas, uint32* __restrict__ outb, int N) {
    int wid = (blockIdx.x * blockDim.x + threadIdx.x) >> 6;
    int lane = threadIdx.x & 63;
    if (wid >= N) return;
    int d8 = lane & 7;
    int e8 = lane >> 3;
    float beta = betas[1];
    float shift = fabsf(beta);
    const uint32* dbase = hb + (size_t)wid * 48 + 6 * d8;
    float invd = invn[wid];
    uint2 dw0 = *(const uint2*)dbase, dw1 = *(const uint2*)(dbase + 2), dw2 = *(const uint2*)(dbase + 4);
    f32x2 dn2[6];
    dn2[0] = unpk(dw0.x) * invd; dn2[1] = unpk(dw0.y) * invd;
    dn2[2] = unpk(dw1.x) * invd; dn2[3] = unpk(dw1.y) * invd;
    dn2[4] = unpk(dw2.x) * invd; dn2[5] = unpk(dw2.y) * invd;
    int s0 = rs[wid], s1 = rs[wid + 1];
    int nIter = (s1 - s0 + 7) >> 3;
    int idx0 = s0 + e8;

    float den = 0.f;
    f32x2 acc2[6];
#pragma unroll
    for (int j = 0; j < 6; j++) acc2[j] = (f32x2){0.f, 0.f};

    auto compute = [&](uint2 p0, uint2 p1, uint2 p2, float invS, bool vS) {
        f32x2 v2[6];
        v2[0] = unpk(p0.x); v2[1] = unpk(p0.y);
        v2[2] = unpk(p1.x); v2[3] = unpk(p1.y);
        v2[4] = unpk(p2.x); v2[5] = unpk(p2.y);
        f32x2 d2 = v2[0] * dn2[0];
#pragma unroll
        for (int j = 1; j < 6; j++) d2 += v2[j] * dn2[j];
        float d = d2.x + d2.y;
        d += __shfl_xor(d, 1, 64);
        d += __shfl_xor(d, 2, 64);
        d += __shfl_xor(d, 4, 64);
        float w = __expf(beta * (d * invS) - shift);
        if (!vS) w = 0.f;
        den += w;
#pragma unroll
        for (int j = 0; j < 6; j++) acc2[j] += w * v2[j];
    };
    auto fetch = [&](int it_, uint2& p0, uint2& p1, uint2& p2, float& invS, bool& vS) {
        int idx = idx0 + 8 * it_;
        vS = idx < s1;
        int sn = csr_src[vS ? idx : s0];
        const uint32* rp = hb + (size_t)sn * 48 + 6 * d8;
        p0 = *(const uint2*)rp; p1 = *(const uint2*)(rp + 2); p2 = *(const uint2*)(rp + 4);
        invS = invn[sn];
    };

    uint2 A0, A1, A2, B0, B1, B2;
    float iA, iB; bool vA, vB;
    fetch(0, A0, A1, A2, iA, vA);
    int it = 0;
    for (; it + 2 <= nIter; it += 2) {
        fetch(it + 1, B0, B1, B2, iB, vB);
        compute(A0, A1, A2, iA, vA);
        fetch(it + 2, A0, A1, A2, iA, vA);
        compute(B0, B1, B2, iB, vB);
    }
    if (it < nIter) compute(A0, A1, A2, iA, vA);

    den += __shfl_xor(den, 8, 64);
    den += __shfl_xor(den, 16, 64);
    den += __shfl_xor(den, 32, 64);
#pragma unroll
    for (int j = 0; j < 6; j++) {
        acc2[j].x += __shfl_xor(acc2[j].x, 8, 64);
        acc2[j].y += __shfl_xor(acc2[j].y, 8, 64);
        acc2[j].x += __shfl_xor(acc2[j].x, 16, 64);
        acc2[j].y += __shfl_xor(acc2[j].y, 16, 64);
        acc2[j].x += __shfl_xor(acc2[j].x, 32, 64);
        acc2[j].y += __shfl_xor(acc2[j].y, 32, 64);
    }
    if (e8 == 0) {
        float r = 1.f / den;
        uint32* op = outb + (size_t)wid * 48 + 6 * d8;
        uint2 o0, o1, o2;
        o0.x = packbf(acc2[0].x * r, acc2[0].y * r);  o0.y = packbf(acc2[1].x * r, acc2[1].y * r);
        o1.x = packbf(acc2[2].x * r, acc2[2].y * r);  o1.y = packbf(acc2[3].x * r, acc2[3].y * r);
        o2.x = packbf(acc2[4].x * r, acc2[4].y * r);  o2.y = packbf(acc2[5].x * r, acc2[5].y * r);
        *(uint2*)op = o0; *(uint2*)(op + 2) = o1; *(uint2*)(op + 4) = o2;
    }
}

// ---------- fused gate kernel: role-split, ping-pong pipeline, pre-scaled exchange ----------
__global__ __launch_bounds__(256, 8) void k_fused_gates(const uint32* __restrict__ ftb, const float* __restrict__ inv2,
                                                        const int* __restrict__ rs, const int* __restrict__ csr_src,
                                                        const float* __restrict__ betas, const float* __restrict__ cold,
                                                        float* __restrict__ hout, float* __restrict__ cout_, int N) {
    int wid = (blockIdx.x * blockDim.x + threadIdx.x) >> 6;
    int lane = threadIdx.x & 63;
    if (wid >= N) return;
    float bx0 = betas[2], bh0 = betas[3];
    float bx1 = betas[4], bh1 = betas[5];
    float bx2 = betas[6], bh2 = betas[7];
    float bx3 = betas[8], bh3 = betas[9];
    bool uni = (bx0 == bx1) && (bx0 == bx2) && (bx0 == bx3) &&
               (bh0 == bh1) && (bh0 == bh2) && (bh0 == bh3);
    int s0 = rs[wid], s1 = rs[wid + 1];
    size_t rowbase = (size_t)wid * H;

    if (uni) {
        int l16 = lane & 15, q = lane >> 4;
        int sub = l16 >> 3;      // 0 = xt, 1 = hN
        int d8  = l16 & 7;       // dims [12*d8, 12*d8+12) of its feature
        float bsel = sub ? bh0 : bx0;
        float ssel = fabsf(bsel);
        const uint32* dbase = ftb + (size_t)wid * 96 + sub * 48 + 6 * d8;
        float invd = inv2[2 * wid + sub];
        uint2 dw0 = *(const uint2*)dbase, dw1 = *(const uint2*)(dbase + 2), dw2 = *(const uint2*)(dbase + 4);
        f32x2 dn2[6];
        dn2[0] = unpk(dw0.x) * invd; dn2[1] = unpk(dw0.y) * invd;
        dn2[2] = unpk(dw1.x) * invd; dn2[3] = unpk(dw1.y) * invd;
        dn2[4] = unpk(dw2.x) * invd; dn2[5] = unpk(dw2.y) * invd;
        int nIter = (s1 - s0 + 3) >> 2;
        int idx0 = s0 + q;

        float den = 0.f;
        f32x2 acc2[6];
#pragma unroll
        for (int j = 0; j < 6; j++) acc2[j] = (f32x2){0.f, 0.f};

        auto compute = [&](uint2 p0, uint2 p1, uint2 p2, float isS, bool vS) {
            f32x2 v2[6];
            v2[0] = unpk(p0.x); v2[1] = unpk(p0.y);
            v2[2] = unpk(p1.x); v2[3] = unpk(p1.y);
            v2[4] = unpk(p2.x); v2[5] = unpk(p2.y);
            f32x2 d2 = v2[0] * dn2[0];
#pragma unroll
            for (int j = 1; j < 6; j++) d2 += v2[j] * dn2[j];
            float d = d2.x + d2.y;
            d += __shfl_xor(d, 1, 64);
            d += __shfl_xor(d, 2, 64);
            d += __shfl_xor(d, 4, 64);
            float w = __expf(bsel * (d * isS) - ssel);
            if (!vS) w = 0.f;
            den += w;
#pragma unroll
            for (int j = 0; j < 6; j++) acc2[j] += w * v2[j];
        };
        auto fetch = [&](int it_, uint2& p0, uint2& p1, uint2& p2, float& isS, bool& vS) {
            int idx = idx0 + 4 * it_;
            vS = idx < s1;
            int sn = csr_src[vS ? idx : s0];
            const uint32* rp = ftb + (size_t)sn * 96 + sub * 48 + 6 * d8;
            p0 = *(const uint2*)rp; p1 = *(const uint2*)(rp + 2); p2 = *(const uint2*)(rp + 4);
            isS = inv2[2 * sn + sub];
        };

        uint2 A0, A1, A2, B0, B1, B2;
        float iA, iB; bool vA, vB;
        fetch(0, A0, A1, A2, iA, vA);
        int it = 0;
        for (; it + 2 <= nIter; it += 2) {
            fetch(it + 1, B0, B1, B2, iB, vB);
            compute(A0, A1, A2, iA, vA);
            fetch(it + 2, A0, A1, A2, iA, vA);
            compute(B0, B1, B2, iB, vB);
        }
        if (it < nIter) compute(A0, A1, A2, iA, vA);

        den += __shfl_xor(den, 16, 64);
        den += __shfl_xor(den, 32, 64);
#pragma unroll
        for (int j = 0; j < 6; j++) {
            acc2[j].x += __shfl_xor(acc2[j].x, 16, 64);
            acc2[j].y += __shfl_xor(acc2[j].y, 16, 64);
            acc2[j].x += __shfl_xor(acc2[j].x, 32, 64);
            acc2[j].y += __shfl_xor(acc2[j].y, 32, 64);
        }
        // pre-scale by own 1/den, then one cross-feature exchange-add
        float rown = 1.f / den;
        f32x2 a2[6];
#pragma unroll
        for (int j = 0; j < 6; j++) {
            f32x2 own = acc2[j] * rown;
            own.x += __shfl_xor(own.x, 8, 64);
            own.y += __shfl_xor(own.y, 8, 64);
            a2[j] = own;   // = accX*rX + accH*rH on both sub lanes
        }
        // 4-way parallel epilogue: sub==0 lanes; lane q handles dims 12*d8 + 3q + {0,1,2}
        if (sub == 0) {
            float aA0 = q == 0 ? a2[0].x : q == 1 ? a2[1].y : q == 2 ? a2[3].x : a2[4].y;
            float aA1 = q == 0 ? a2[0].y : q == 1 ? a2[2].x : q == 2 ? a2[3].y : a2[5].x;
            float aA2 = q == 0 ? a2[1].x : q == 1 ? a2[2].y : q == 2 ? a2[4].x : a2[5].y;
            size_t ob = rowbase + 12 * d8 + 3 * q;
            float aA[3] = {aA0, aA1, aA2};
            float cvs[3] = {cold[ob], cold[ob + 1], cold[ob + 2]};
            float ho[3], co[3];
#pragma unroll
            for (int t = 0; t < 3; t++) {
                float a   = aA[t];
                float sig = 1.f / (1.f + __expf(-a));   // f = i = o
                float ct  = tanh_fast(a);
                float cn  = sig * cvs[t] + sig * ct;
                ho[t] = sig * tanh_fast(cn);
                co[t] = cn;
            }
            hout[ob]     = ho[0]; hout[ob + 1]  = ho[1]; hout[ob + 2]  = ho[2];
            cout_[ob]    = co[0]; cout_[ob + 1] = co[1]; cout_[ob + 2] = co[2];
        }
    } else {
        // general 4-gate path (correctness fallback; arbitrary betas)
        int fi = lane & 15;
        int q  = lane >> 4;
        float ixd = inv2[2 * wid], ihd = inv2[2 * wid + 1];
        const uint32* xdp = ftb + (size_t)wid * 96 + 3 * fi;
        const uint32* hdp = ftb + (size_t)wid * 96 + 48 + 3 * fi;
        uint32 xu0 = xdp[0], xu1 = xdp[1], xu2 = xdp[2];
        uint32 hu0 = hdp[0], hu1 = hdp[1], hu2 = hdp[2];
        float xn[6] = {bflo(xu0) * ixd, bfhi(xu0) * ixd, bflo(xu1) * ixd,
                       bfhi(xu1) * ixd, bflo(xu2) * ixd, bfhi(xu2) * ixd};
        float hn[6] = {bflo(hu0) * ihd, bfhi(hu0) * ihd, bflo(hu1) * ihd,
                       bfhi(hu1) * ihd, bflo(hu2) * ihd, bfhi(hu2) * ihd};
        float sx[4] = {fabsf(bx0), fabsf(bx1), fabsf(bx2), fabsf(bx3)};
        float sh_[4] = {fabsf(bh0), fabsf(bh1), fabsf(bh2), fabsf(bh3)};
        float bxv[4] = {bx0, bx1, bx2, bx3};
        float bhv[4] = {bh0, bh1, bh2, bh3};
        float denX[4] = {0, 0, 0, 0}, denH[4] = {0, 0, 0, 0};
        float aX[4][6], aH[4][6];
#pragma unroll
        for (int g = 0; g < 4; g++)
#pragma unroll
            for (int j = 0; j < 6; j++) { aX[g][j] = 0.f; aH[g][j] = 0.f; }
        for (int s = s0; s < s1; s += 4) {
            int idx = s + q;
            bool valid = idx < s1;
            int sidx = valid ? idx : s0;
            int sn = csr_src[sidx];
            float isx = inv2[2 * sn], ish = inv2[2 * sn + 1];
            const uint32* xrp = ftb + (size_t)sn * 96 + 3 * fi;
            const uint32* hrp = ftb + (size_t)sn * 96 + 48 + 3 * fi;
            uint32 a0 = xrp[0], a1 = xrp[1], a2 = xrp[2];
            uint32 b0 = hrp[0], b1 = hrp[1], b2 = hrp[2];
            float xv[6] = {bflo(a0), bfhi(a0), bflo(a1), bfhi(a1), bflo(a2), bfhi(a2)};
            float hv[6] = {bflo(b0), bfhi(b0), bflo(b1), bfhi(b1), bflo(b2), bfhi(b2)};
            float dx = 0.f, dh = 0.f;
#pragma unroll
            for (int j = 0; j < 6; j++) { dx += xv[j] * xn[j]; dh += hv[j] * hn[j]; }
#pragma unroll
            for (int off = 8; off; off >>= 1) {
                dx += __shfl_xor(dx, off, 64);
                dh += __shfl_xor(dh, off, 64);
            }
            float cx = dx * isx, ch = dh * ish;
#pragma unroll
            for (int g = 0; g < 4; g++) {
                float wx = __expf(bxv[g] * cx - sx[g]);
                float wh = __expf(bhv[g] * ch - sh_[g]);
                if (!valid) { wx = 0.f; wh = 0.f; }
                denX[g] += wx; denH[g] += wh;
#pragma unroll
                for (int j = 0; j < 6; j++) { aX[g][j] += wx * xv[j]; aH[g][j] += wh * hv[j]; }
            }
        }
#pragma unroll
        for (int g = 0; g < 4; g++) {
            denX[g] += __shfl_xor(denX[g], 16, 64); denX[g] += __shfl_xor(denX[g], 32, 64);
            denH[g] += __shfl_xor(denH[g], 16, 64); denH[g] += __shfl_xor(denH[g], 32, 64);
#pragma unroll
            for (int j = 0; j < 6; j++) {
                aX[g][j] += __shfl_xor(aX[g][j], 16, 64); aX[g][j] += __shfl_xor(aX[g][j], 32, 64);
                aH[g][j] += __shfl_xor(aH[g][j], 16, 64); aH[g][j] += __shfl_xor(aH[g][j], 32, 64);
            }
        }
        if (q == 0) {
#pragma unroll
            for (int j = 0; j < 6; j++) {
                int d = 6 * fi + j;
                float a0 = aX[0][j] / denX[0] + aH[0][j] / denH[0];
                float a1 = aX[1][j] / denX[1] + aH[1][j] / denH[1];
                float a2 = aX[2][j] / denX[2] + aH[2][j] / denH[2];
                float a3 = aX[3][j] / denX[3] + aH[3][j] / denH[3];
                float f  = 1.f / (1.f + __expf(-a0));
                float i_ = 1.f / (1.f + __expf(-a1));
                float ct = tanh_fast(a2);
                float o  = 1.f / (1.f + __expf(-a3));
                float cv = cold[rowbase + d];
                float cn = f * cv + i_ * ct;
                hout[rowbase + d]  = o * tanh_fast(cn);
                cout_[rowbase + d] = cn;
            }
        }
    }
}

extern "C" void kernel_launch(void* const* d_in, const int* in_sizes, int n_in,
                              void* d_out, int out_size, void* d_ws, size_t ws_size,
                              hipStream_t stream) {
    const float* x        = (const float*)d_in[0];
    const int*   ei       = (const int*)d_in[1];
    const float* h        = (const float*)d_in[2];
    const float* c        = (const float*)d_in[3];
    const float* W_in     = (const float*)d_in[4];
    const float* b_in     = (const float*)d_in[5];
    const float* Wb1      = (const float*)d_in[10];
    const float* bb1      = (const float*)d_in[11];
    const float* Wb2      = (const float*)d_in[12];
    const float* bb2      = (const float*)d_in[13];
    const float* betas    = (const float*)d_in[14];

    int N  = in_sizes[0] / DIN;
    int E  = in_sizes[1] / 2;
    int Et = E + N;
    int NH = N * H;

    char* ws = (char*)d_ws;
    size_t off = 0;
    auto alloc = [&](size_t bytes) -> void* {
        void* p = ws + off;
        off = (off + bytes + 255) & ~(size_t)255;
        return p;
    };
    uint32* ftb  = (uint32*)alloc((size_t)N * 96 * 4);   // merged bf16 rows: [xt(48 u32) | hN(48 u32)]
    uint32* hb   = (uint32*)alloc((size_t)N * 48 * 4);   // h bf16 rows
    uint32* hN0b = (uint32*)alloc((size_t)N * 48 * 4);   // AGNN(h) bf16 rows
    float* inv2  = (float*)alloc((size_t)N * 2 * 4);     // (inv_xt, inv_hN) pairs
    int* csr_src = (int*)alloc((size_t)Et * 4);
    int* deg     = (int*)alloc((size_t)N * 4);
    int* rs      = (int*)alloc((size_t)(N + 1) * 4);
    int* cur     = (int*)alloc((size_t)N * 4);
    int* bsum    = (int*)alloc(64 * 4);
    float* inv_h = (float*)alloc((size_t)N * 4);

    int nb = (N + 1023) / 1024;
    int gblk = (N + 63) / 64;

    hipMemsetAsync(deg, 0, (size_t)N * 4, stream);
    k_hist<<<(Et + 255) / 256, 256, 0, stream>>>(ei, E, N, deg);
    k_scanA<<<nb, 256, 0, stream>>>(deg, rs, bsum, N);
    k_scanB<<<1, 64, 0, stream>>>(bsum, nb);
    k_scanC<<<(N + 255) / 256, 256, 0, stream>>>(rs, cur, bsum, N, Et);
    k_scatter<<<(Et + 255) / 256, 256, 0, stream>>>(ei, E, N, cur, csr_src);

    k_gemm_in_mfma<<<gblk, 256, 0, stream>>>(x, W_in, b_in, ftb, inv2, N);
    k_cvt_h<<<(N + 3) / 4, 256, 0, stream>>>(h, hb, inv_h, N);
    k_fused_h<<<(N + 3) / 4, 256, 0, stream>>>(hb, inv_h, rs, csr_src, betas, hN0b, N);

    k_gemm_gate_mfma<<<gblk, 256, 0, stream>>>(hb, hN0b, h, Wb1, Wb2, bb1, bb2, ftb, inv2, N);

    float* hout = (float*)d_out;
    float* cout_ = (float*)d_out + NH;
    k_fused_gates<<<(N + 3) / 4, 256, 0, stream>>>(ftb, inv2, rs, csr_src, betas, c, hout, cout_, N);
}

// Round 18
// 254.630 us; speedup vs baseline: 1.1767x; 1.0385x over previous
//
#include <hip/hip_runtime.h>
#include <hip/hip_bf16.h>

#define H 96
#define DIN 256

typedef unsigned int uint32;
typedef __attribute__((ext_vector_type(8))) short bf16x8;
typedef __attribute__((ext_vector_type(4))) float f32x4;
typedef __attribute__((ext_vector_type(2))) float f32x2;

__device__ __forceinline__ float bflo(uint32 u) { return __uint_as_float(u << 16); }
__device__ __forceinline__ float bfhi(uint32 u) { return __uint_as_float(u & 0xffff0000u); }
__device__ __forceinline__ uint32 packbf(float a, float b) {
    __hip_bfloat16 x = __float2bfloat16(a), y = __float2bfloat16(b);
    unsigned short lo = *reinterpret_cast<unsigned short*>(&x);
    unsigned short hi = *reinterpret_cast<unsigned short*>(&y);
    return (uint32)lo | ((uint32)hi << 16);
}
__device__ __forceinline__ float bfround(float a) {
    return __bfloat162float(__float2bfloat16(a));
}
// fast tanh: exact at saturation (exp overflow -> 1, underflow -> -1)
__device__ __forceinline__ float tanh_fast(float x) {
    float e = __expf(2.f * x);
    return 1.f - 2.f / (e + 1.f);
}
__device__ __forceinline__ f32x2 unpk(uint32 u) {
    return (f32x2){__uint_as_float(u << 16), __uint_as_float(u & 0xffff0000u)};
}

// ---------- phase 1: MFMA GEMM (xt -> ftb + inv2.x) blocks [0,gblk); hist blocks [gblk, ...) ----------
__global__ __launch_bounds__(256) void k_phase1(const float* __restrict__ x, const float* __restrict__ W,
                                                const float* __restrict__ b, uint32* __restrict__ ftb,
                                                float* __restrict__ inv2, int N,
                                                const int* __restrict__ ei, int E, int* __restrict__ deg, int gblk_) {
    __shared__ uint32 As[64 * 68];
    __shared__ uint32 Ws[96 * 68];
    if (blockIdx.x >= gblk_) {
        // histogram part
        int e = (blockIdx.x - gblk_) * 256 + threadIdx.x;
        int Et = E + N;
        if (e < Et) {
            int dst = (e < E) ? ei[E + e] : (e - E);
            atomicAdd(&deg[dst], 1);
        }
        return;
    }
    int tid = threadIdx.x;
    int lane = tid & 63;
    int w = tid >> 6;
    int row0 = blockIdx.x * 64;
    int n = lane & 15, g = lane >> 4;

    f32x4 acc[6];
#pragma unroll
    for (int t = 0; t < 6; t++) acc[t] = (f32x4){0.f, 0.f, 0.f, 0.f};

    for (int kc = 0; kc < DIN; kc += 128) {
        for (int i = tid; i < 64 * 32; i += 256) {
            int r = i >> 5, seg = i & 31;
            int grow = row0 + r;
            float4 v = (grow < N) ? *(const float4*)(x + (size_t)grow * DIN + kc + seg * 4)
                                  : make_float4(0.f, 0.f, 0.f, 0.f);
            As[r * 68 + seg * 2]     = packbf(v.x, v.y);
            As[r * 68 + seg * 2 + 1] = packbf(v.z, v.w);
        }
        for (int i = tid; i < 96 * 32; i += 256) {
            int r = i >> 5, seg = i & 31;
            float4 v = *(const float4*)(W + (size_t)r * DIN + kc + seg * 4);
            Ws[r * 68 + seg * 2]     = packbf(v.x, v.y);
            Ws[r * 68 + seg * 2 + 1] = packbf(v.z, v.w);
        }
        __syncthreads();
#pragma unroll
        for (int s = 0; s < 4; s++) {
            int kb = s * 16 + g * 4;
            bf16x8 a = *(const bf16x8*)&As[(16 * w + n) * 68 + kb];
#pragma unroll
            for (int t = 0; t < 6; t++) {
                bf16x8 bb = *(const bf16x8*)&Ws[(16 * t + n) * 68 + kb];
                acc[t] = __builtin_amdgcn_mfma_f32_16x16x32_bf16(a, bb, acc[t], 0, 0, 0);
            }
        }
        __syncthreads();
    }
    float ss[4] = {0.f, 0.f, 0.f, 0.f};
#pragma unroll
    for (int t = 0; t < 6; t++) {
        int col = 16 * t + n;
        float bv = b[col];
#pragma unroll
        for (int r = 0; r < 4; r++) {
            int grow = row0 + 16 * w + g * 4 + r;
            float v = acc[t][r] + bv;
            float vb = bfround(v);
            ss[r] += vb * vb;
            float p = __shfl_xor(v, 1, 64);
            if ((n & 1) == 0 && grow < N)
                ftb[(size_t)grow * 96 + 8 * t + (n >> 1)] = packbf(v, p);
        }
    }
#pragma unroll
    for (int r = 0; r < 4; r++) {
#pragma unroll
        for (int off = 1; off < 16; off <<= 1) ss[r] += __shfl_xor(ss[r], off, 64);
        int grow = row0 + 16 * w + g * 4 + r;
        if (n == 0 && grow < N) inv2[2 * grow] = 1.f / fmaxf(sqrtf(ss[r]), 1e-12f);
    }
}

// ---------- phase 2: scanA blocks [0,nb); cvt_h blocks [nb, ...) ----------
__global__ __launch_bounds__(256) void k_phase2(const int* __restrict__ deg, int* __restrict__ rs,
                                                int* __restrict__ bsum, int n,
                                                const float* __restrict__ h, uint32* __restrict__ hb,
                                                float* __restrict__ inv, int N, int nb_) {
    __shared__ int sh[256];
    int t = threadIdx.x;
    if (blockIdx.x >= nb_) {
        // cvt_h part
        int wid = (blockIdx.x - nb_) * 4 + (t >> 6);
        int lane = t & 63;
        if (wid >= N) return;
        const float2* row = (const float2*)(h + (size_t)wid * H);
        float ss = 0.f;
        if (lane < 48) {
            float2 v = row[lane];
            uint32 p = packbf(v.x, v.y);
            hb[(size_t)wid * 48 + lane] = p;
            float a = bflo(p), b = bfhi(p);
            ss = a * a + b * b;
        }
#pragma unroll
        for (int off = 32; off; off >>= 1) ss += __shfl_xor(ss, off, 64);
        if (lane == 0) inv[wid] = 1.f / fmaxf(sqrtf(ss), 1e-12f);
        return;
    }
    // scanA part
    int base = blockIdx.x * 1024 + t * 4;
    int v[4];
    int s = 0;
#pragma unroll
    for (int j = 0; j < 4; j++) { v[j] = (base + j < n) ? deg[base + j] : 0; s += v[j]; }
    sh[t] = s;
    __syncthreads();
    for (int off = 1; off < 256; off <<= 1) {
        int tmp = (t >= off) ? sh[t - off] : 0;
        __syncthreads();
        sh[t] += tmp;
        __syncthreads();
    }
    int excl = sh[t] - s;
#pragma unroll
    for (int j = 0; j < 4; j++) {
        if (base + j < n) rs[base + j] = excl;
        excl += v[j];
    }
    if (t == 255) bsum[blockIdx.x] = sh[255];
}

__global__ void k_scanB(int* __restrict__ bsum, int nb) {
    int l = threadIdx.x;
    int orig = (l < nb) ? bsum[l] : 0;
    int v = orig;
#pragma unroll
    for (int off = 1; off < 64; off <<= 1) {
        int u = __shfl_up(v, off, 64);
        if (l >= off) v += u;
    }
    if (l < nb) bsum[l] = v - orig;
}

__global__ void k_scanC(int* __restrict__ rs, int* __restrict__ cur, const int* __restrict__ bsum,
                        int n, int total) {
    int i = blockIdx.x * blockDim.x + threadIdx.x;
    if (i < n) {
        int r = rs[i] + bsum[i >> 10];
        rs[i] = r;
        cur[i] = r;
    }
    if (i == 0) rs[n] = total;
}

__global__ void k_scatter(const int* __restrict__ ei, int E, int N,
                          int* __restrict__ cur, int* __restrict__ csr_src) {
    int e = blockIdx.x * blockDim.x + threadIdx.x;
    int Et = E + N;
    if (e >= Et) return;
    int src, dst;
    if (e < E) { src = ei[e]; dst = ei[E + e]; }
    else       { src = e - E; dst = e - E; }
    int pos = atomicAdd(&cur[dst], 1);
    csr_src[pos] = src;
}

// ---------- MFMA GEMM: h_N = h + tanh([h|A]@[Wb1|Wb2]^T + b) -> hN half of ftb + inv2.y ----------
__global__ __launch_bounds__(256) void k_gemm_gate_mfma(const uint32* __restrict__ hb, const uint32* __restrict__ hN0b,
                                                        const float* __restrict__ h,
                                                        const float* __restrict__ W1, const float* __restrict__ W2,
                                                        const float* __restrict__ b1, const float* __restrict__ b2,
                                                        uint32* __restrict__ ftb, float* __restrict__ inv2, int N) {
    __shared__ uint32 As[64 * 52];
    __shared__ uint32 Ws[96 * 52];
    int tid = threadIdx.x;
    int lane = tid & 63;
    int w = tid >> 6;
    int row0 = blockIdx.x * 64;
    int n = lane & 15, g = lane >> 4;

    f32x4 acc[6];
#pragma unroll
    for (int t = 0; t < 6; t++) acc[t] = (f32x4){0.f, 0.f, 0.f, 0.f};

    for (int chunk = 0; chunk < 2; chunk++) {
        {
            const uint32* src = chunk ? hN0b : hb;
            int r = tid >> 2, j = tid & 3;
            int grow = row0 + r;
            if (grow < N) {
#pragma unroll
                for (int m = 0; m < 3; m++) {
                    uint4 u = *(const uint4*)(src + (size_t)grow * 48 + j * 12 + m * 4);
                    *(uint4*)&As[r * 52 + j * 12 + m * 4] = u;
                }
            } else {
#pragma unroll
                for (int m = 0; m < 12; m++) As[r * 52 + j * 12 + m] = 0u;
            }
        }
        {
            const float* Wsrc = chunk ? W2 : W1;
            for (int i = tid; i < 96 * 24; i += 256) {
                int r = i / 24, seg = i % 24;
                float4 v = *(const float4*)(Wsrc + (size_t)r * H + seg * 4);
                Ws[r * 52 + seg * 2]     = packbf(v.x, v.y);
                Ws[r * 52 + seg * 2 + 1] = packbf(v.z, v.w);
            }
        }
        __syncthreads();
#pragma unroll
        for (int s = 0; s < 3; s++) {
            int kb = s * 16 + g * 4;
            bf16x8 a = *(const bf16x8*)&As[(16 * w + n) * 52 + kb];
#pragma unroll
            for (int t = 0; t < 6; t++) {
                bf16x8 bb = *(const bf16x8*)&Ws[(16 * t + n) * 52 + kb];
                acc[t] = __builtin_amdgcn_mfma_f32_16x16x32_bf16(a, bb, acc[t], 0, 0, 0);
            }
        }
        __syncthreads();
    }
    float ss[4] = {0.f, 0.f, 0.f, 0.f};
#pragma unroll
    for (int t = 0; t < 6; t++) {
        int col = 16 * t + n;
        float bsum = b1[col] + b2[col];
#pragma unroll
        for (int r = 0; r < 4; r++) {
            int grow = row0 + 16 * w + g * 4 + r;
            float hval = (grow < N) ? h[(size_t)grow * H + col] : 0.f;
            float v = hval + tanh_fast(acc[t][r] + bsum);
            float vb = bfround(v);
            ss[r] += vb * vb;
            float p = __shfl_xor(v, 1, 64);
            if ((n & 1) == 0 && grow < N)
                ftb[(size_t)grow * 96 + 48 + 8 * t + (n >> 1)] = packbf(v, p);
        }
    }
#pragma unroll
    for (int r = 0; r < 4; r++) {
#pragma unroll
        for (int off = 1; off < 16; off <<= 1) ss[r] += __shfl_xor(ss[r], off, 64);
        int grow = row0 + 16 * w + g * 4 + r;
        if (n == 0 && grow < N) inv2[2 * grow + 1] = 1.f / fmaxf(sqrtf(ss[r]), 1e-12f);
    }
}

// ---------- fused AGNN on h: 8 lanes/edge x 8 edges/iter, ping-pong pipeline ----------
__global__ __launch_bounds__(256, 8) void k_fused_h(const uint32* __restrict__ hb, const float* __restrict__ invn,
                                                    const int* __restrict__ rs, const int* __restrict__ csr_src,
                                                    const float* __restrict__ betas, uint32* __restrict__ outb, int N) {
    int wid = (blockIdx.x * blockDim.x + threadIdx.x) >> 6;
    int lane = threadIdx.x & 63;
    if (wid >= N) return;
    int d8 = lane & 7;
    int e8 = lane >> 3;
    float beta = betas[1];
    float shift = fabsf(beta);
    const uint32* dbase = hb + (size_t)wid * 48 + 6 * d8;
    float invd = invn[wid];
    uint2 dw0 = *(const uint2*)dbase, dw1 = *(const uint2*)(dbase + 2), dw2 = *(const uint2*)(dbase + 4);
    f32x2 dn2[6];
    dn2[0] = unpk(dw0.x) * invd; dn2[1] = unpk(dw0.y) * invd;
    dn2[2] = unpk(dw1.x) * invd; dn2[3] = unpk(dw1.y) * invd;
    dn2[4] = unpk(dw2.x) * invd; dn2[5] = unpk(dw2.y) * invd;
    int s0 = rs[wid], s1 = rs[wid + 1];
    int nIter = (s1 - s0 + 7) >> 3;
    int idx0 = s0 + e8;

    float den = 0.f;
    f32x2 acc2[6];
#pragma unroll
    for (int j = 0; j < 6; j++) acc2[j] = (f32x2){0.f, 0.f};

    auto compute = [&](uint2 p0, uint2 p1, uint2 p2, float invS, bool vS) {
        f32x2 v2[6];
        v2[0] = unpk(p0.x); v2[1] = unpk(p0.y);
        v2[2] = unpk(p1.x); v2[3] = unpk(p1.y);
        v2[4] = unpk(p2.x); v2[5] = unpk(p2.y);
        f32x2 d2 = v2[0] * dn2[0];
#pragma unroll
        for (int j = 1; j < 6; j++) d2 += v2[j] * dn2[j];
        float d = d2.x + d2.y;
        d += __shfl_xor(d, 1, 64);
        d += __shfl_xor(d, 2, 64);
        d += __shfl_xor(d, 4, 64);
        float w = __expf(beta * (d * invS) - shift);
        if (!vS) w = 0.f;
        den += w;
#pragma unroll
        for (int j = 0; j < 6; j++) acc2[j] += w * v2[j];
    };
    auto fetch = [&](int it_, uint2& p0, uint2& p1, uint2& p2, float& invS, bool& vS) {
        int idx = idx0 + 8 * it_;
        vS = idx < s1;
        int sn = csr_src[vS ? idx : s0];
        const uint32* rp = hb + (size_t)sn * 48 + 6 * d8;
        p0 = *(const uint2*)rp; p1 = *(const uint2*)(rp + 2); p2 = *(const uint2*)(rp + 4);
        invS = invn[sn];
    };

    uint2 A0, A1, A2, B0, B1, B2;
    float iA, iB; bool vA, vB;
    fetch(0, A0, A1, A2, iA, vA);
    int it = 0;
    for (; it + 2 <= nIter; it += 2) {
        fetch(it + 1, B0, B1, B2, iB, vB);
        compute(A0, A1, A2, iA, vA);
        fetch(it + 2, A0, A1, A2, iA, vA);
        compute(B0, B1, B2, iB, vB);
    }
    if (it < nIter) compute(A0, A1, A2, iA, vA);

    den += __shfl_xor(den, 8, 64);
    den += __shfl_xor(den, 16, 64);
    den += __shfl_xor(den, 32, 64);
#pragma unroll
    for (int j = 0; j < 6; j++) {
        acc2[j].x += __shfl_xor(acc2[j].x, 8, 64);
        acc2[j].y += __shfl_xor(acc2[j].y, 8, 64);
        acc2[j].x += __shfl_xor(acc2[j].x, 16, 64);
        acc2[j].y += __shfl_xor(acc2[j].y, 16, 64);
        acc2[j].x += __shfl_xor(acc2[j].x, 32, 64);
        acc2[j].y += __shfl_xor(acc2[j].y, 32, 64);
    }
    if (e8 == 0) {
        float r = 1.f / den;
        uint32* op = outb + (size_t)wid * 48 + 6 * d8;
        uint2 o0, o1, o2;
        o0.x = packbf(acc2[0].x * r, acc2[0].y * r);  o0.y = packbf(acc2[1].x * r, acc2[1].y * r);
        o1.x = packbf(acc2[2].x * r, acc2[2].y * r);  o1.y = packbf(acc2[3].x * r, acc2[3].y * r);
        o2.x = packbf(acc2[4].x * r, acc2[4].y * r);  o2.y = packbf(acc2[5].x * r, acc2[5].y * r);
        *(uint2*)op = o0; *(uint2*)(op + 2) = o1; *(uint2*)(op + 4) = o2;
    }
}

// ---------- fused gate kernel: role-split, ping-pong pipeline, pre-scaled exchange ----------
__global__ __launch_bounds__(256, 8) void k_fused_gates(const uint32* __restrict__ ftb, const float* __restrict__ inv2,
                                                        const int* __restrict__ rs, const int* __restrict__ csr_src,
                                                        const float* __restrict__ betas, const float* __restrict__ cold,
                                                        float* __restrict__ hout, float* __restrict__ cout_, int N) {
    int wid = (blockIdx.x * blockDim.x + threadIdx.x) >> 6;
    int lane = threadIdx.x & 63;
    if (wid >= N) return;
    float bx0 = betas[2], bh0 = betas[3];
    float bx1 = betas[4], bh1 = betas[5];
    float bx2 = betas[6], bh2 = betas[7];
    float bx3 = betas[8], bh3 = betas[9];
    bool uni = (bx0 == bx1) && (bx0 == bx2) && (bx0 == bx3) &&
               (bh0 == bh1) && (bh0 == bh2) && (bh0 == bh3);
    int s0 = rs[wid], s1 = rs[wid + 1];
    size_t rowbase = (size_t)wid * H;

    if (uni) {
        int l16 = lane & 15, q = lane >> 4;
        int sub = l16 >> 3;      // 0 = xt, 1 = hN
        int d8  = l16 & 7;       // dims [12*d8, 12*d8+12) of its feature
        float bsel = sub ? bh0 : bx0;
        float ssel = fabsf(bsel);
        const uint32* dbase = ftb + (size_t)wid * 96 + sub * 48 + 6 * d8;
        float invd = inv2[2 * wid + sub];
        uint2 dw0 = *(const uint2*)dbase, dw1 = *(const uint2*)(dbase + 2), dw2 = *(const uint2*)(dbase + 4);
        f32x2 dn2[6];
        dn2[0] = unpk(dw0.x) * invd; dn2[1] = unpk(dw0.y) * invd;
        dn2[2] = unpk(dw1.x) * invd; dn2[3] = unpk(dw1.y) * invd;
        dn2[4] = unpk(dw2.x) * invd; dn2[5] = unpk(dw2.y) * invd;
        int nIter = (s1 - s0 + 3) >> 2;
        int idx0 = s0 + q;

        float den = 0.f;
        f32x2 acc2[6];
#pragma unroll
        for (int j = 0; j < 6; j++) acc2[j] = (f32x2){0.f, 0.f};

        auto compute = [&](uint2 p0, uint2 p1, uint2 p2, float isS, bool vS) {
            f32x2 v2[6];
            v2[0] = unpk(p0.x); v2[1] = unpk(p0.y);
            v2[2] = unpk(p1.x); v2[3] = unpk(p1.y);
            v2[4] = unpk(p2.x); v2[5] = unpk(p2.y);
            f32x2 d2 = v2[0] * dn2[0];
#pragma unroll
            for (int j = 1; j < 6; j++) d2 += v2[j] * dn2[j];
            float d = d2.x + d2.y;
            d += __shfl_xor(d, 1, 64);
            d += __shfl_xor(d, 2, 64);
            d += __shfl_xor(d, 4, 64);
            float w = __expf(bsel * (d * isS) - ssel);
            if (!vS) w = 0.f;
            den += w;
#pragma unroll
            for (int j = 0; j < 6; j++) acc2[j] += w * v2[j];
        };
        auto fetch = [&](int it_, uint2& p0, uint2& p1, uint2& p2, float& isS, bool& vS) {
            int idx = idx0 + 4 * it_;
            vS = idx < s1;
            int sn = csr_src[vS ? idx : s0];
            const uint32* rp = ftb + (size_t)sn * 96 + sub * 48 + 6 * d8;
            p0 = *(const uint2*)rp; p1 = *(const uint2*)(rp + 2); p2 = *(const uint2*)(rp + 4);
            isS = inv2[2 * sn + sub];
        };

        uint2 A0, A1, A2, B0, B1, B2;
        float iA, iB; bool vA, vB;
        fetch(0, A0, A1, A2, iA, vA);
        int it = 0;
        for (; it + 2 <= nIter; it += 2) {
            fetch(it + 1, B0, B1, B2, iB, vB);
            compute(A0, A1, A2, iA, vA);
            fetch(it + 2, A0, A1, A2, iA, vA);
            compute(B0, B1, B2, iB, vB);
        }
        if (it < nIter) compute(A0, A1, A2, iA, vA);

        den += __shfl_xor(den, 16, 64);
        den += __shfl_xor(den, 32, 64);
#pragma unroll
        for (int j = 0; j < 6; j++) {
            acc2[j].x += __shfl_xor(acc2[j].x, 16, 64);
            acc2[j].y += __shfl_xor(acc2[j].y, 16, 64);
            acc2[j].x += __shfl_xor(acc2[j].x, 32, 64);
            acc2[j].y += __shfl_xor(acc2[j].y, 32, 64);
        }
        // pre-scale by own 1/den, then one cross-feature exchange-add
        float rown = 1.f / den;
        f32x2 a2[6];
#pragma unroll
        for (int j = 0; j < 6; j++) {
            f32x2 own = acc2[j] * rown;
            own.x += __shfl_xor(own.x, 8, 64);
            own.y += __shfl_xor(own.y, 8, 64);
            a2[j] = own;   // = accX*rX + accH*rH on both sub lanes
        }
        // 4-way parallel epilogue: sub==0 lanes; lane q handles dims 12*d8 + 3q + {0,1,2}
        if (sub == 0) {
            float aA0 = q == 0 ? a2[0].x : q == 1 ? a2[1].y : q == 2 ? a2[3].x : a2[4].y;
            float aA1 = q == 0 ? a2[0].y : q == 1 ? a2[2].x : q == 2 ? a2[3].y : a2[5].x;
            float aA2 = q == 0 ? a2[1].x : q == 1 ? a2[2].y : q == 2 ? a2[4].x : a2[5].y;
            size_t ob = rowbase + 12 * d8 + 3 * q;
            float aA[3] = {aA0, aA1, aA2};
            float cvs[3] = {cold[ob], cold[ob + 1], cold[ob + 2]};
            float ho[3], co[3];
#pragma unroll
            for (int t = 0; t < 3; t++) {
                float a   = aA[t];
                float sig = 1.f / (1.f + __expf(-a));   // f = i = o
                float ct  = tanh_fast(a);
                float cn  = sig * cvs[t] + sig * ct;
                ho[t] = sig * tanh_fast(cn);
                co[t] = cn;
            }
            hout[ob]     = ho[0]; hout[ob + 1]  = ho[1]; hout[ob + 2]  = ho[2];
            cout_[ob]    = co[0]; cout_[ob + 1] = co[1]; cout_[ob + 2] = co[2];
        }
    } else {
        // general 4-gate path (correctness fallback; arbitrary betas)
        int fi = lane & 15;
        int q  = lane >> 4;
        float ixd = inv2[2 * wid], ihd = inv2[2 * wid + 1];
        const uint32* xdp = ftb + (size_t)wid * 96 + 3 * fi;
        const uint32* hdp = ftb + (size_t)wid * 96 + 48 + 3 * fi;
        uint32 xu0 = xdp[0], xu1 = xdp[1], xu2 = xdp[2];
        uint32 hu0 = hdp[0], hu1 = hdp[1], hu2 = hdp[2];
        float xn[6] = {bflo(xu0) * ixd, bfhi(xu0) * ixd, bflo(xu1) * ixd,
                       bfhi(xu1) * ixd, bflo(xu2) * ixd, bfhi(xu2) * ixd};
        float hn[6] = {bflo(hu0) * ihd, bfhi(hu0) * ihd, bflo(hu1) * ihd,
                       bfhi(hu1) * ihd, bflo(hu2) * ihd, bfhi(hu2) * ihd};
        float sx[4] = {fabsf(bx0), fabsf(bx1), fabsf(bx2), fabsf(bx3)};
        float sh_[4] = {fabsf(bh0), fabsf(bh1), fabsf(bh2), fabsf(bh3)};
        float bxv[4] = {bx0, bx1, bx2, bx3};
        float bhv[4] = {bh0, bh1, bh2, bh3};
        float denX[4] = {0, 0, 0, 0}, denH[4] = {0, 0, 0, 0};
        float aX[4][6], aH[4][6];
#pragma unroll
        for (int g = 0; g < 4; g++)
#pragma unroll
            for (int j = 0; j < 6; j++) { aX[g][j] = 0.f; aH[g][j] = 0.f; }
        for (int s = s0; s < s1; s += 4) {
            int idx = s + q;
            bool valid = idx < s1;
            int sidx = valid ? idx : s0;
            int sn = csr_src[sidx];
            float isx = inv2[2 * sn], ish = inv2[2 * sn + 1];
            const uint32* xrp = ftb + (size_t)sn * 96 + 3 * fi;
            const uint32* hrp = ftb + (size_t)sn * 96 + 48 + 3 * fi;
            uint32 a0 = xrp[0], a1 = xrp[1], a2 = xrp[2];
            uint32 b0 = hrp[0], b1 = hrp[1], b2 = hrp[2];
            float xv[6] = {bflo(a0), bfhi(a0), bflo(a1), bfhi(a1), bflo(a2), bfhi(a2)};
            float hv[6] = {bflo(b0), bfhi(b0), bflo(b1), bfhi(b1), bflo(b2), bfhi(b2)};
            float dx = 0.f, dh = 0.f;
#pragma unroll
            for (int j = 0; j < 6; j++) { dx += xv[j] * xn[j]; dh += hv[j] * hn[j]; }
#pragma unroll
            for (int off = 8; off; off >>= 1) {
                dx += __shfl_xor(dx, off, 64);
                dh += __shfl_xor(dh, off, 64);
            }
            float cx = dx * isx, ch = dh * ish;
#pragma unroll
            for (int g = 0; g < 4; g++) {
                float wx = __expf(bxv[g] * cx - sx[g]);
                float wh = __expf(bhv[g] * ch - sh_[g]);
                if (!valid) { wx = 0.f; wh = 0.f; }
                denX[g] += wx; denH[g] += wh;
#pragma unroll
                for (int j = 0; j < 6; j++) { aX[g][j] += wx * xv[j]; aH[g][j] += wh * hv[j]; }
            }
        }
#pragma unroll
        for (int g = 0; g < 4; g++) {
            denX[g] += __shfl_xor(denX[g], 16, 64); denX[g] += __shfl_xor(denX[g], 32, 64);
            denH[g] += __shfl_xor(denH[g], 16, 64); denH[g] += __shfl_xor(denH[g], 32, 64);
#pragma unroll
            for (int j = 0; j < 6; j++) {
                aX[g][j] += __shfl_xor(aX[g][j], 16, 64); aX[g][j] += __shfl_xor(aX[g][j], 32, 64);
                aH[g][j] += __shfl_xor(aH[g][j], 16, 64); aH[g][j] += __shfl_xor(aH[g][j], 32, 64);
            }
        }
        if (q == 0) {
#pragma unroll
            for (int j = 0; j < 6; j++) {
                int d = 6 * fi + j;
                float a0 = aX[0][j] / denX[0] + aH[0][j] / denH[0];
                float a1 = aX[1][j] / denX[1] + aH[1][j] / denH[1];
                float a2 = aX[2][j] / denX[2] + aH[2][j] / denH[2];
                float a3 = aX[3][j] / denX[3] + aH[3][j] / denH[3];
                float f  = 1.f / (1.f + __expf(-a0));
                float i_ = 1.f / (1.f + __expf(-a1));
                float ct = tanh_fast(a2);
                float o  = 1.f / (1.f + __expf(-a3));
                float cv = cold[rowbase + d];
                float cn = f * cv + i_ * ct;
                hout[rowbase + d]  = o * tanh_fast(cn);
                cout_[rowbase + d] = cn;
            }
        }
    }
}

extern "C" void kernel_launch(void* const* d_in, const int* in_sizes, int n_in,
                              void* d_out, int out_size, void* d_ws, size_t ws_size,
                              hipStream_t stream) {
    const float* x        = (const float*)d_in[0];
    const int*   ei       = (const int*)d_in[1];
    const float* h        = (const float*)d_in[2];
    const float* c        = (const float*)d_in[3];
    const float* W_in     = (const float*)d_in[4];
    const float* b_in     = (const float*)d_in[5];
    const float* Wb1      = (const float*)d_in[10];
    const float* bb1      = (const float*)d_in[11];
    const float* Wb2      = (const float*)d_in[12];
    const float* bb2      = (const float*)d_in[13];
    const float* betas    = (const float*)d_in[14];

    int N  = in_sizes[0] / DIN;
    int E  = in_sizes[1] / 2;
    int Et = E + N;
    int NH = N * H;

    char* ws = (char*)d_ws;
    size_t off = 0;
    auto alloc = [&](size_t bytes) -> void* {
        void* p = ws + off;
        off = (off + bytes + 255) & ~(size_t)255;
        return p;
    };
    uint32* ftb  = (uint32*)alloc((size_t)N * 96 * 4);   // merged bf16 rows: [xt(48 u32) | hN(48 u32)]
    uint32* hb   = (uint32*)alloc((size_t)N * 48 * 4);   // h bf16 rows
    uint32* hN0b = (uint32*)alloc((size_t)N * 48 * 4);   // AGNN(h) bf16 rows
    float* inv2  = (float*)alloc((size_t)N * 2 * 4);     // (inv_xt, inv_hN) pairs
    int* csr_src = (int*)alloc((size_t)Et * 4);
    int* deg     = (int*)alloc((size_t)N * 4);
    int* rs      = (int*)alloc((size_t)(N + 1) * 4);
    int* cur     = (int*)alloc((size_t)N * 4);
    int* bsum    = (int*)alloc(64 * 4);
    float* inv_h = (float*)alloc((size_t)N * 4);

    int nb = (N + 1023) / 1024;
    int gblk = (N + 63) / 64;
    int histblk = (Et + 255) / 256;
    int cvtblk = (N + 3) / 4;

    hipMemsetAsync(deg, 0, (size_t)N * 4, stream);
    // phase 1: xt GEMM (blocks [0,gblk)) || degree histogram (blocks [gblk, gblk+histblk))
    k_phase1<<<gblk + histblk, 256, 0, stream>>>(x, W_in, b_in, ftb, inv2, N, ei, E, deg, gblk);
    // phase 2: scanA (blocks [0,nb)) || h->bf16 convert (blocks [nb, nb+cvtblk))
    k_phase2<<<nb + cvtblk, 256, 0, stream>>>(deg, rs, bsum, N, h, hb, inv_h, N, nb);
    k_scanB<<<1, 64, 0, stream>>>(bsum, nb);
    k_scanC<<<(N + 255) / 256, 256, 0, stream>>>(rs, cur, bsum, N, Et);
    k_scatter<<<(Et + 255) / 256, 256, 0, stream>>>(ei, E, N, cur, csr_src);

    k_fused_h<<<(N + 3) / 4, 256, 0, stream>>>(hb, inv_h, rs, csr_src, betas, hN0b, N);
    k_gemm_gate_mfma<<<gblk, 256, 0, stream>>>(hb, hN0b, h, Wb1, Wb2, bb1, bb2, ftb, inv2, N);

    float* hout = (float*)d_out;
    float* cout_ = (float*)d_out + NH;
    k_fused_gates<<<(N + 3) / 4, 256, 0, stream>>>(ftb, inv2, rs, csr_src, betas, c, hout, cout_, N);
}

// Round 19
// 242.563 us; speedup vs baseline: 1.2352x; 1.0497x over previous
//
#include <hip/hip_runtime.h>
#include <hip/hip_bf16.h>

#define H 96
#define DIN 256

typedef unsigned int uint32;
typedef __attribute__((ext_vector_type(8))) short bf16x8;
typedef __attribute__((ext_vector_type(4))) float f32x4;
typedef __attribute__((ext_vector_type(2))) float f32x2;

__device__ __forceinline__ float bflo(uint32 u) { return __uint_as_float(u << 16); }
__device__ __forceinline__ float bfhi(uint32 u) { return __uint_as_float(u & 0xffff0000u); }
__device__ __forceinline__ uint32 packbf(float a, float b) {
    __hip_bfloat16 x = __float2bfloat16(a), y = __float2bfloat16(b);
    unsigned short lo = *reinterpret_cast<unsigned short*>(&x);
    unsigned short hi = *reinterpret_cast<unsigned short*>(&y);
    return (uint32)lo | ((uint32)hi << 16);
}
__device__ __forceinline__ float bfround(float a) {
    return __bfloat162float(__float2bfloat16(a));
}
// fast tanh: exact at saturation (exp overflow -> 1, underflow -> -1)
__device__ __forceinline__ float tanh_fast(float x) {
    float e = __expf(2.f * x);
    return 1.f - 2.f / (e + 1.f);
}
__device__ __forceinline__ f32x2 unpk(uint32 u) {
    return (f32x2){__uint_as_float(u << 16), __uint_as_float(u & 0xffff0000u)};
}

// ---------- phase 1: MFMA GEMM (xt -> ftb + inv2.x) blocks [0,gblk); hist blocks [gblk, ...) ----------
// K-chunk = 64 so LDS = 23 KB -> ~7 blocks/CU for BOTH the GEMM and histogram parts.
__global__ __launch_bounds__(256) void k_phase1(const float* __restrict__ x, const float* __restrict__ W,
                                                const float* __restrict__ b, uint32* __restrict__ ftb,
                                                float* __restrict__ inv2, int N,
                                                const int* __restrict__ ei, int E, int* __restrict__ deg, int gblk_) {
    __shared__ uint32 As[64 * 36];   // 64 rows x 64 bf16 (+8 pad)
    __shared__ uint32 Ws[96 * 36];
    if (blockIdx.x >= gblk_) {
        int e = (blockIdx.x - gblk_) * 256 + threadIdx.x;
        int Et = E + N;
        if (e < Et) {
            int dst = (e < E) ? ei[E + e] : (e - E);
            atomicAdd(&deg[dst], 1);
        }
        return;
    }
    int tid = threadIdx.x;
    int lane = tid & 63;
    int w = tid >> 6;
    int row0 = blockIdx.x * 64;
    int n = lane & 15, g = lane >> 4;

    f32x4 acc[6];
#pragma unroll
    for (int t = 0; t < 6; t++) acc[t] = (f32x4){0.f, 0.f, 0.f, 0.f};

    for (int kc = 0; kc < DIN; kc += 64) {
        for (int i = tid; i < 64 * 16; i += 256) {
            int r = i >> 4, seg = i & 15;
            int grow = row0 + r;
            float4 v = (grow < N) ? *(const float4*)(x + (size_t)grow * DIN + kc + seg * 4)
                                  : make_float4(0.f, 0.f, 0.f, 0.f);
            As[r * 36 + seg * 2]     = packbf(v.x, v.y);
            As[r * 36 + seg * 2 + 1] = packbf(v.z, v.w);
        }
        for (int i = tid; i < 96 * 16; i += 256) {
            int r = i >> 4, seg = i & 15;
            float4 v = *(const float4*)(W + (size_t)r * DIN + kc + seg * 4);
            Ws[r * 36 + seg * 2]     = packbf(v.x, v.y);
            Ws[r * 36 + seg * 2 + 1] = packbf(v.z, v.w);
        }
        __syncthreads();
#pragma unroll
        for (int s = 0; s < 2; s++) {
            int kb = s * 16 + g * 4;
            bf16x8 a = *(const bf16x8*)&As[(16 * w + n) * 36 + kb];
#pragma unroll
            for (int t = 0; t < 6; t++) {
                bf16x8 bb = *(const bf16x8*)&Ws[(16 * t + n) * 36 + kb];
                acc[t] = __builtin_amdgcn_mfma_f32_16x16x32_bf16(a, bb, acc[t], 0, 0, 0);
            }
        }
        __syncthreads();
    }
    float ss[4] = {0.f, 0.f, 0.f, 0.f};
#pragma unroll
    for (int t = 0; t < 6; t++) {
        int col = 16 * t + n;
        float bv = b[col];
#pragma unroll
        for (int r = 0; r < 4; r++) {
            int grow = row0 + 16 * w + g * 4 + r;
            float v = acc[t][r] + bv;
            float vb = bfround(v);
            ss[r] += vb * vb;
            float p = __shfl_xor(v, 1, 64);
            if ((n & 1) == 0 && grow < N)
                ftb[(size_t)grow * 96 + 8 * t + (n >> 1)] = packbf(v, p);
        }
    }
#pragma unroll
    for (int r = 0; r < 4; r++) {
#pragma unroll
        for (int off = 1; off < 16; off <<= 1) ss[r] += __shfl_xor(ss[r], off, 64);
        int grow = row0 + 16 * w + g * 4 + r;
        if (n == 0 && grow < N) inv2[2 * grow] = 1.f / fmaxf(sqrtf(ss[r]), 1e-12f);
    }
}

// ---------- phase 2: scanA blocks [0,nb); cvt_h blocks [nb, ...) ----------
__global__ __launch_bounds__(256) void k_phase2(const int* __restrict__ deg, int* __restrict__ rs,
                                                int* __restrict__ bsum, int n,
                                                const float* __restrict__ h, uint32* __restrict__ hb,
                                                float* __restrict__ inv, int N, int nb_) {
    __shared__ int sh[256];
    int t = threadIdx.x;
    if (blockIdx.x >= nb_) {
        int wid = (blockIdx.x - nb_) * 4 + (t >> 6);
        int lane = t & 63;
        if (wid >= N) return;
        const float2* row = (const float2*)(h + (size_t)wid * H);
        float ss = 0.f;
        if (lane < 48) {
            float2 v = row[lane];
            uint32 p = packbf(v.x, v.y);
            hb[(size_t)wid * 48 + lane] = p;
            float a = bflo(p), b = bfhi(p);
            ss = a * a + b * b;
        }
#pragma unroll
        for (int off = 32; off; off >>= 1) ss += __shfl_xor(ss, off, 64);
        if (lane == 0) inv[wid] = 1.f / fmaxf(sqrtf(ss), 1e-12f);
        return;
    }
    int base = blockIdx.x * 1024 + t * 4;
    int v[4];
    int s = 0;
#pragma unroll
    for (int j = 0; j < 4; j++) { v[j] = (base + j < n) ? deg[base + j] : 0; s += v[j]; }
    sh[t] = s;
    __syncthreads();
    for (int off = 1; off < 256; off <<= 1) {
        int tmp = (t >= off) ? sh[t - off] : 0;
        __syncthreads();
        sh[t] += tmp;
        __syncthreads();
    }
    int excl = sh[t] - s;
#pragma unroll
    for (int j = 0; j < 4; j++) {
        if (base + j < n) rs[base + j] = excl;
        excl += v[j];
    }
    if (t == 255) bsum[blockIdx.x] = sh[255];
}

__global__ void k_scanB(int* __restrict__ bsum, int nb) {
    int l = threadIdx.x;
    int orig = (l < nb) ? bsum[l] : 0;
    int v = orig;
#pragma unroll
    for (int off = 1; off < 64; off <<= 1) {
        int u = __shfl_up(v, off, 64);
        if (l >= off) v += u;
    }
    if (l < nb) bsum[l] = v - orig;
}

__global__ void k_scanC(int* __restrict__ rs, int* __restrict__ cur, const int* __restrict__ bsum,
                        int n, int total) {
    int i = blockIdx.x * blockDim.x + threadIdx.x;
    if (i < n) {
        int r = rs[i] + bsum[i >> 10];
        rs[i] = r;
        cur[i] = r;
    }
    if (i == 0) rs[n] = total;
}

__global__ void k_scatter(const int* __restrict__ ei, int E, int N,
                          int* __restrict__ cur, int* __restrict__ csr_src) {
    int e = blockIdx.x * blockDim.x + threadIdx.x;
    int Et = E + N;
    if (e >= Et) return;
    int src, dst;
    if (e < E) { src = ei[e]; dst = ei[E + e]; }
    else       { src = e - E; dst = e - E; }
    int pos = atomicAdd(&cur[dst], 1);
    csr_src[pos] = src;
}

// ---------- MFMA GEMM: h_N = h + tanh([h|A]@[Wb1|Wb2]^T + b) -> hN half of ftb + inv2.y ----------
__global__ __launch_bounds__(256) void k_gemm_gate_mfma(const uint32* __restrict__ hb, const uint32* __restrict__ hN0b,
                                                        const float* __restrict__ h,
                                                        const float* __restrict__ W1, const float* __restrict__ W2,
                                                        const float* __restrict__ b1, const float* __restrict__ b2,
                                                        uint32* __restrict__ ftb, float* __restrict__ inv2, int N) {
    __shared__ uint32 As[64 * 52];
    __shared__ uint32 Ws[96 * 52];
    int tid = threadIdx.x;
    int lane = tid & 63;
    int w = tid >> 6;
    int row0 = blockIdx.x * 64;
    int n = lane & 15, g = lane >> 4;

    f32x4 acc[6];
#pragma unroll
    for (int t = 0; t < 6; t++) acc[t] = (f32x4){0.f, 0.f, 0.f, 0.f};

    for (int chunk = 0; chunk < 2; chunk++) {
        {
            const uint32* src = chunk ? hN0b : hb;
            int r = tid >> 2, j = tid & 3;
            int grow = row0 + r;
            if (grow < N) {
#pragma unroll
                for (int m = 0; m < 3; m++) {
                    uint4 u = *(const uint4*)(src + (size_t)grow * 48 + j * 12 + m * 4);
                    *(uint4*)&As[r * 52 + j * 12 + m * 4] = u;
                }
            } else {
#pragma unroll
                for (int m = 0; m < 12; m++) As[r * 52 + j * 12 + m] = 0u;
            }
        }
        {
            const float* Wsrc = chunk ? W2 : W1;
            for (int i = tid; i < 96 * 24; i += 256) {
                int r = i / 24, seg = i % 24;
                float4 v = *(const float4*)(Wsrc + (size_t)r * H + seg * 4);
                Ws[r * 52 + seg * 2]     = packbf(v.x, v.y);
                Ws[r * 52 + seg * 2 + 1] = packbf(v.z, v.w);
            }
        }
        __syncthreads();
#pragma unroll
        for (int s = 0; s < 3; s++) {
            int kb = s * 16 + g * 4;
            bf16x8 a = *(const bf16x8*)&As[(16 * w + n) * 52 + kb];
#pragma unroll
            for (int t = 0; t < 6; t++) {
                bf16x8 bb = *(const bf16x8*)&Ws[(16 * t + n) * 52 + kb];
                acc[t] = __builtin_amdgcn_mfma_f32_16x16x32_bf16(a, bb, acc[t], 0, 0, 0);
            }
        }
        __syncthreads();
    }
    float ss[4] = {0.f, 0.f, 0.f, 0.f};
#pragma unroll
    for (int t = 0; t < 6; t++) {
        int col = 16 * t + n;
        float bsum = b1[col] + b2[col];
#pragma unroll
        for (int r = 0; r < 4; r++) {
            int grow = row0 + 16 * w + g * 4 + r;
            float hval = (grow < N) ? h[(size_t)grow * H + col] : 0.f;
            float v = hval + tanh_fast(acc[t][r] + bsum);
            float vb = bfround(v);
            ss[r] += vb * vb;
            float p = __shfl_xor(v, 1, 64);
            if ((n & 1) == 0 && grow < N)
                ftb[(size_t)grow * 96 + 48 + 8 * t + (n >> 1)] = packbf(v, p);
        }
    }
#pragma unroll
    for (int r = 0; r < 4; r++) {
#pragma unroll
        for (int off = 1; off < 16; off <<= 1) ss[r] += __shfl_xor(ss[r], off, 64);
        int grow = row0 + 16 * w + g * 4 + r;
        if (n == 0 && grow < N) inv2[2 * grow + 1] = 1.f / fmaxf(sqrtf(ss[r]), 1e-12f);
    }
}

// ---------- fused AGNN on h: 8 lanes/edge x 8 edges/iter, ping-pong pipeline ----------
__global__ __launch_bounds__(256, 8) void k_fused_h(const uint32* __restrict__ hb, const float* __restrict__ invn,
                                                    const int* __restrict__ rs, const int* __restrict__ csr_src,
                                                    const float* __restrict__ betas, uint32* __restrict__ outb, int N) {
    int wid = (blockIdx.x * blockDim.x + threadIdx.x) >> 6;
    int lane = threadIdx.x & 63;
    if (wid >= N) return;
    int d8 = lane & 7;
    int e8 = lane >> 3;
    float beta = betas[1];
    float shift = fabsf(beta);
    const uint32* dbase = hb + (size_t)wid * 48 + 6 * d8;
    float invd = invn[wid];
    uint2 dw0 = *(const uint2*)dbase, dw1 = *(const uint2*)(dbase + 2), dw2 = *(const uint2*)(dbase + 4);
    f32x2 dn2[6];
    dn2[0] = unpk(dw0.x) * invd; dn2[1] = unpk(dw0.y) * invd;
    dn2[2] = unpk(dw1.x) * invd; dn2[3] = unpk(dw1.y) * invd;
    dn2[4] = unpk(dw2.x) * invd; dn2[5] = unpk(dw2.y) * invd;
    int s0 = rs[wid], s1 = rs[wid + 1];
    int nIter = (s1 - s0 + 7) >> 3;
    int idx0 = s0 + e8;

    float den = 0.f;
    f32x2 acc2[6];
#pragma unroll
    for (int j = 0; j < 6; j++) acc2[j] = (f32x2){0.f, 0.f};

    auto compute = [&](uint2 p0, uint2 p1, uint2 p2, float invS, bool vS) {
        f32x2 v2[6];
        v2[0] = unpk(p0.x); v2[1] = unpk(p0.y);
        v2[2] = unpk(p1.x); v2[3] = unpk(p1.y);
        v2[4] = unpk(p2.x); v2[5] = unpk(p2.y);
        f32x2 d2 = v2[0] * dn2[0];
#pragma unroll
        for (int j = 1; j < 6; j++) d2 += v2[j] * dn2[j];
        float d = d2.x + d2.y;
        d += __shfl_xor(d, 1, 64);
        d += __shfl_xor(d, 2, 64);
        d += __shfl_xor(d, 4, 64);
        float w = __expf(beta * (d * invS) - shift);
        if (!vS) w = 0.f;
        den += w;
#pragma unroll
        for (int j = 0; j < 6; j++) acc2[j] += w * v2[j];
    };
    auto fetch = [&](int it_, uint2& p0, uint2& p1, uint2& p2, float& invS, bool& vS) {
        int idx = idx0 + 8 * it_;
        vS = idx < s1;
        int sn = csr_src[vS ? idx : s0];
        const uint32* rp = hb + (size_t)sn * 48 + 6 * d8;
        p0 = *(const uint2*)rp; p1 = *(const uint2*)(rp + 2); p2 = *(const uint2*)(rp + 4);
        invS = invn[sn];
    };

    uint2 A0, A1, A2, B0, B1, B2;
    float iA, iB; bool vA, vB;
    fetch(0, A0, A1, A2, iA, vA);
    int it = 0;
    for (; it + 2 <= nIter; it += 2) {
        fetch(it + 1, B0, B1, B2, iB, vB);
        compute(A0, A1, A2, iA, vA);
        fetch(it + 2, A0, A1, A2, iA, vA);
        compute(B0, B1, B2, iB, vB);
    }
    if (it < nIter) compute(A0, A1, A2, iA, vA);

    den += __shfl_xor(den, 8, 64);
    den += __shfl_xor(den, 16, 64);
    den += __shfl_xor(den, 32, 64);
#pragma unroll
    for (int j = 0; j < 6; j++) {
        acc2[j].x += __shfl_xor(acc2[j].x, 8, 64);
        acc2[j].y += __shfl_xor(acc2[j].y, 8, 64);
        acc2[j].x += __shfl_xor(acc2[j].x, 16, 64);
        acc2[j].y += __shfl_xor(acc2[j].y, 16, 64);
        acc2[j].x += __shfl_xor(acc2[j].x, 32, 64);
        acc2[j].y += __shfl_xor(acc2[j].y, 32, 64);
    }
    if (e8 == 0) {
        float r = 1.f / den;
        uint32* op = outb + (size_t)wid * 48 + 6 * d8;
        uint2 o0, o1, o2;
        o0.x = packbf(acc2[0].x * r, acc2[0].y * r);  o0.y = packbf(acc2[1].x * r, acc2[1].y * r);
        o1.x = packbf(acc2[2].x * r, acc2[2].y * r);  o1.y = packbf(acc2[3].x * r, acc2[3].y * r);
        o2.x = packbf(acc2[4].x * r, acc2[4].y * r);  o2.y = packbf(acc2[5].x * r, acc2[5].y * r);
        *(uint2*)op = o0; *(uint2*)(op + 2) = o1; *(uint2*)(op + 4) = o2;
    }
}

// ---------- fused gate kernel: role-split, ping-pong pipeline, pre-scaled exchange ----------
__global__ __launch_bounds__(256, 8) void k_fused_gates(const uint32* __restrict__ ftb, const float* __restrict__ inv2,
                                                        const int* __restrict__ rs, const int* __restrict__ csr_src,
                                                        const float* __restrict__ betas, const float* __restrict__ cold,
                                                        float* __restrict__ hout, float* __restrict__ cout_, int N) {
    int wid = (blockIdx.x * blockDim.x + threadIdx.x) >> 6;
    int lane = threadIdx.x & 63;
    if (wid >= N) return;
    float bx0 = betas[2], bh0 = betas[3];
    float bx1 = betas[4], bh1 = betas[5];
    float bx2 = betas[6], bh2 = betas[7];
    float bx3 = betas[8], bh3 = betas[9];
    bool uni = (bx0 == bx1) && (bx0 == bx2) && (bx0 == bx3) &&
               (bh0 == bh1) && (bh0 == bh2) && (bh0 == bh3);
    int s0 = rs[wid], s1 = rs[wid + 1];
    size_t rowbase = (size_t)wid * H;

    if (uni) {
        int l16 = lane & 15, q = lane >> 4;
        int sub = l16 >> 3;      // 0 = xt, 1 = hN
        int d8  = l16 & 7;       // dims [12*d8, 12*d8+12) of its feature
        float bsel = sub ? bh0 : bx0;
        float ssel = fabsf(bsel);
        const uint32* dbase = ftb + (size_t)wid * 96 + sub * 48 + 6 * d8;
        float invd = inv2[2 * wid + sub];
        uint2 dw0 = *(const uint2*)dbase, dw1 = *(const uint2*)(dbase + 2), dw2 = *(const uint2*)(dbase + 4);
        f32x2 dn2[6];
        dn2[0] = unpk(dw0.x) * invd; dn2[1] = unpk(dw0.y) * invd;
        dn2[2] = unpk(dw1.x) * invd; dn2[3] = unpk(dw1.y) * invd;
        dn2[4] = unpk(dw2.x) * invd; dn2[5] = unpk(dw2.y) * invd;
        int nIter = (s1 - s0 + 3) >> 2;
        int idx0 = s0 + q;

        float den = 0.f;
        f32x2 acc2[6];
#pragma unroll
        for (int j = 0; j < 6; j++) acc2[j] = (f32x2){0.f, 0.f};

        auto compute = [&](uint2 p0, uint2 p1, uint2 p2, float isS, bool vS) {
            f32x2 v2[6];
            v2[0] = unpk(p0.x); v2[1] = unpk(p0.y);
            v2[2] = unpk(p1.x); v2[3] = unpk(p1.y);
            v2[4] = unpk(p2.x); v2[5] = unpk(p2.y);
            f32x2 d2 = v2[0] * dn2[0];
#pragma unroll
            for (int j = 1; j < 6; j++) d2 += v2[j] * dn2[j];
            float d = d2.x + d2.y;
            d += __shfl_xor(d, 1, 64);
            d += __shfl_xor(d, 2, 64);
            d += __shfl_xor(d, 4, 64);
            float w = __expf(bsel * (d * isS) - ssel);
            if (!vS) w = 0.f;
            den += w;
#pragma unroll
            for (int j = 0; j < 6; j++) acc2[j] += w * v2[j];
        };
        auto fetch = [&](int it_, uint2& p0, uint2& p1, uint2& p2, float& isS, bool& vS) {
            int idx = idx0 + 4 * it_;
            vS = idx < s1;
            int sn = csr_src[vS ? idx : s0];
            const uint32* rp = ftb + (size_t)sn * 96 + sub * 48 + 6 * d8;
            p0 = *(const uint2*)rp; p1 = *(const uint2*)(rp + 2); p2 = *(const uint2*)(rp + 4);
            isS = inv2[2 * sn + sub];
        };

        uint2 A0, A1, A2, B0, B1, B2;
        float iA, iB; bool vA, vB;
        fetch(0, A0, A1, A2, iA, vA);
        int it = 0;
        for (; it + 2 <= nIter; it += 2) {
            fetch(it + 1, B0, B1, B2, iB, vB);
            compute(A0, A1, A2, iA, vA);
            fetch(it + 2, A0, A1, A2, iA, vA);
            compute(B0, B1, B2, iB, vB);
        }
        if (it < nIter) compute(A0, A1, A2, iA, vA);

        den += __shfl_xor(den, 16, 64);
        den += __shfl_xor(den, 32, 64);
#pragma unroll
        for (int j = 0; j < 6; j++) {
            acc2[j].x += __shfl_xor(acc2[j].x, 16, 64);
            acc2[j].y += __shfl_xor(acc2[j].y, 16, 64);
            acc2[j].x += __shfl_xor(acc2[j].x, 32, 64);
            acc2[j].y += __shfl_xor(acc2[j].y, 32, 64);
        }
        // pre-scale by own 1/den, then one cross-feature exchange-add
        float rown = 1.f / den;
        f32x2 a2[6];
#pragma unroll
        for (int j = 0; j < 6; j++) {
            f32x2 own = acc2[j] * rown;
            own.x += __shfl_xor(own.x, 8, 64);
            own.y += __shfl_xor(own.y, 8, 64);
            a2[j] = own;   // = accX*rX + accH*rH on both sub lanes
        }
        // 4-way parallel epilogue: sub==0 lanes; lane q handles dims 12*d8 + 3q + {0,1,2}
        if (sub == 0) {
            float aA0 = q == 0 ? a2[0].x : q == 1 ? a2[1].y : q == 2 ? a2[3].x : a2[4].y;
            float aA1 = q == 0 ? a2[0].y : q == 1 ? a2[2].x : q == 2 ? a2[3].y : a2[5].x;
            float aA2 = q == 0 ? a2[1].x : q == 1 ? a2[2].y : q == 2 ? a2[4].x : a2[5].y;
            size_t ob = rowbase + 12 * d8 + 3 * q;
            float aA[3] = {aA0, aA1, aA2};
            float cvs[3] = {cold[ob], cold[ob + 1], cold[ob + 2]};
            float ho[3], co[3];
#pragma unroll
            for (int t = 0; t < 3; t++) {
                float a   = aA[t];
                float sig = 1.f / (1.f + __expf(-a));   // f = i = o
                float ct  = tanh_fast(a);
                float cn  = sig * cvs[t] + sig * ct;
                ho[t] = sig * tanh_fast(cn);
                co[t] = cn;
            }
            hout[ob]     = ho[0]; hout[ob + 1]  = ho[1]; hout[ob + 2]  = ho[2];
            cout_[ob]    = co[0]; cout_[ob + 1] = co[1]; cout_[ob + 2] = co[2];
        }
    } else {
        // general 4-gate path (correctness fallback; arbitrary betas)
        int fi = lane & 15;
        int q  = lane >> 4;
        float ixd = inv2[2 * wid], ihd = inv2[2 * wid + 1];
        const uint32* xdp = ftb + (size_t)wid * 96 + 3 * fi;
        const uint32* hdp = ftb + (size_t)wid * 96 + 48 + 3 * fi;
        uint32 xu0 = xdp[0], xu1 = xdp[1], xu2 = xdp[2];
        uint32 hu0 = hdp[0], hu1 = hdp[1], hu2 = hdp[2];
        float xn[6] = {bflo(xu0) * ixd, bfhi(xu0) * ixd, bflo(xu1) * ixd,
                       bfhi(xu1) * ixd, bflo(xu2) * ixd, bfhi(xu2) * ixd};
        float hn[6] = {bflo(hu0) * ihd, bfhi(hu0) * ihd, bflo(hu1) * ihd,
                       bfhi(hu1) * ihd, bflo(hu2) * ihd, bfhi(hu2) * ihd};
        float sx[4] = {fabsf(bx0), fabsf(bx1), fabsf(bx2), fabsf(bx3)};
        float sh_[4] = {fabsf(bh0), fabsf(bh1), fabsf(bh2), fabsf(bh3)};
        float bxv[4] = {bx0, bx1, bx2, bx3};
        float bhv[4] = {bh0, bh1, bh2, bh3};
        float denX[4] = {0, 0, 0, 0}, denH[4] = {0, 0, 0, 0};
        float aX[4][6], aH[4][6];
#pragma unroll
        for (int g = 0; g < 4; g++)
#pragma unroll
            for (int j = 0; j < 6; j++) { aX[g][j] = 0.f; aH[g][j] = 0.f; }
        for (int s = s0; s < s1; s += 4) {
            int idx = s + q;
            bool valid = idx < s1;
            int sidx = valid ? idx : s0;
            int sn = csr_src[sidx];
            float isx = inv2[2 * sn], ish = inv2[2 * sn + 1];
            const uint32* xrp = ftb + (size_t)sn * 96 + 3 * fi;
            const uint32* hrp = ftb + (size_t)sn * 96 + 48 + 3 * fi;
            uint32 a0 = xrp[0], a1 = xrp[1], a2 = xrp[2];
            uint32 b0 = hrp[0], b1 = hrp[1], b2 = hrp[2];
            float xv[6] = {bflo(a0), bfhi(a0), bflo(a1), bfhi(a1), bflo(a2), bfhi(a2)};
            float hv[6] = {bflo(b0), bfhi(b0), bflo(b1), bfhi(b1), bflo(b2), bfhi(b2)};
            float dx = 0.f, dh = 0.f;
#pragma unroll
            for (int j = 0; j < 6; j++) { dx += xv[j] * xn[j]; dh += hv[j] * hn[j]; }
#pragma unroll
            for (int off = 8; off; off >>= 1) {
                dx += __shfl_xor(dx, off, 64);
                dh += __shfl_xor(dh, off, 64);
            }
            float cx = dx * isx, ch = dh * ish;
#pragma unroll
            for (int g = 0; g < 4; g++) {
                float wx = __expf(bxv[g] * cx - sx[g]);
                float wh = __expf(bhv[g] * ch - sh_[g]);
                if (!valid) { wx = 0.f; wh = 0.f; }
                denX[g] += wx; denH[g] += wh;
#pragma unroll
                for (int j = 0; j < 6; j++) { aX[g][j] += wx * xv[j]; aH[g][j] += wh * hv[j]; }
            }
        }
#pragma unroll
        for (int g = 0; g < 4; g++) {
            denX[g] += __shfl_xor(denX[g], 16, 64); denX[g] += __shfl_xor(denX[g], 32, 64);
            denH[g] += __shfl_xor(denH[g], 16, 64); denH[g] += __shfl_xor(denH[g], 32, 64);
#pragma unroll
            for (int j = 0; j < 6; j++) {
                aX[g][j] += __shfl_xor(aX[g][j], 16, 64); aX[g][j] += __shfl_xor(aX[g][j], 32, 64);
                aH[g][j] += __shfl_xor(aH[g][j], 16, 64); aH[g][j] += __shfl_xor(aH[g][j], 32, 64);
            }
        }
        if (q == 0) {
#pragma unroll
            for (int j = 0; j < 6; j++) {
                int d = 6 * fi + j;
                float a0 = aX[0][j] / denX[0] + aH[0][j] / denH[0];
                float a1 = aX[1][j] / denX[1] + aH[1][j] / denH[1];
                float a2 = aX[2][j] / denX[2] + aH[2][j] / denH[2];
                float a3 = aX[3][j] / denX[3] + aH[3][j] / denH[3];
                float f  = 1.f / (1.f + __expf(-a0));
                float i_ = 1.f / (1.f + __expf(-a1));
                float ct = tanh_fast(a2);
                float o  = 1.f / (1.f + __expf(-a3));
                float cv = cold[rowbase + d];
                float cn = f * cv + i_ * ct;
                hout[rowbase + d]  = o * tanh_fast(cn);
                cout_[rowbase + d] = cn;
            }
        }
    }
}

extern "C" void kernel_launch(void* const* d_in, const int* in_sizes, int n_in,
                              void* d_out, int out_size, void* d_ws, size_t ws_size,
                              hipStream_t stream) {
    const float* x        = (const float*)d_in[0];
    const int*   ei       = (const int*)d_in[1];
    const float* h        = (const float*)d_in[2];
    const float* c        = (const float*)d_in[3];
    const float* W_in     = (const float*)d_in[4];
    const float* b_in     = (const float*)d_in[5];
    const float* Wb1      = (const float*)d_in[10];
    const float* bb1      = (const float*)d_in[11];
    const float* Wb2      = (const float*)d_in[12];
    const float* bb2      = (const float*)d_in[13];
    const float* betas    = (const float*)d_in[14];

    int N  = in_sizes[0] / DIN;
    int E  = in_sizes[1] / 2;
    int Et = E + N;
    int NH = N * H;

    char* ws = (char*)d_ws;
    size_t off = 0;
    auto alloc = [&](size_t bytes) -> void* {
        void* p = ws + off;
        off = (off + bytes + 255) & ~(size_t)255;
        return p;
    };
    uint32* ftb  = (uint32*)alloc((size_t)N * 96 * 4);   // merged bf16 rows: [xt(48 u32) | hN(48 u32)]
    uint32* hb   = (uint32*)alloc((size_t)N * 48 * 4);   // h bf16 rows
    uint32* hN0b = (uint32*)alloc((size_t)N * 48 * 4);   // AGNN(h) bf16 rows
    float* inv2  = (float*)alloc((size_t)N * 2 * 4);     // (inv_xt, inv_hN) pairs
    int* csr_src = (int*)alloc((size_t)Et * 4);
    int* deg     = (int*)alloc((size_t)N * 4);
    int* rs      = (int*)alloc((size_t)(N + 1) * 4);
    int* cur     = (int*)alloc((size_t)N * 4);
    int* bsum    = (int*)alloc(64 * 4);
    float* inv_h = (float*)alloc((size_t)N * 4);

    int nb = (N + 1023) / 1024;
    int gblk = (N + 63) / 64;
    int histblk = (Et + 255) / 256;
    int cvtblk = (N + 3) / 4;

    hipMemsetAsync(deg, 0, (size_t)N * 4, stream);
    // phase 1: xt GEMM (blocks [0,gblk)) || degree histogram (blocks [gblk, gblk+histblk))
    k_phase1<<<gblk + histblk, 256, 0, stream>>>(x, W_in, b_in, ftb, inv2, N, ei, E, deg, gblk);
    // phase 2: scanA (blocks [0,nb)) || h->bf16 convert (blocks [nb, nb+cvtblk))
    k_phase2<<<nb + cvtblk, 256, 0, stream>>>(deg, rs, bsum, N, h, hb, inv_h, N, nb);
    k_scanB<<<1, 64, 0, stream>>>(bsum, nb);
    k_scanC<<<(N + 255) / 256, 256, 0, stream>>>(rs, cur, bsum, N, Et);
    k_scatter<<<(Et + 255) / 256, 256, 0, stream>>>(ei, E, N, cur, csr_src);

    k_fused_h<<<(N + 3) / 4, 256, 0, stream>>>(hb, inv_h, rs, csr_src, betas, hN0b, N);
    k_gemm_gate_mfma<<<gblk, 256, 0, stream>>>(hb, hN0b, h, Wb1, Wb2, bb1, bb2, ftb, inv2, N);

    float* hout = (float*)d_out;
    float* cout_ = (float*)d_out + NH;
    k_fused_gates<<<(N + 3) / 4, 256, 0, stream>>>(ftb, inv2, rs, csr_src, betas, c, hout, cout_, N);
}

// Round 20
// 240.458 us; speedup vs baseline: 1.2460x; 1.0088x over previous
//
#include <hip/hip_runtime.h>
#include <hip/hip_bf16.h>

#define H 96
#define DIN 256

typedef unsigned int uint32;
typedef __attribute__((ext_vector_type(8))) short bf16x8;
typedef __attribute__((ext_vector_type(4))) float f32x4;
typedef __attribute__((ext_vector_type(2))) float f32x2;

__device__ __forceinline__ float bflo(uint32 u) { return __uint_as_float(u << 16); }
__device__ __forceinline__ float bfhi(uint32 u) { return __uint_as_float(u & 0xffff0000u); }
__device__ __forceinline__ uint32 packbf(float a, float b) {
    __hip_bfloat16 x = __float2bfloat16(a), y = __float2bfloat16(b);
    unsigned short lo = *reinterpret_cast<unsigned short*>(&x);
    unsigned short hi = *reinterpret_cast<unsigned short*>(&y);
    return (uint32)lo | ((uint32)hi << 16);
}
__device__ __forceinline__ float bfround(float a) {
    return __bfloat162float(__float2bfloat16(a));
}
// fast tanh: exact at saturation (exp overflow -> 1, underflow -> -1)
__device__ __forceinline__ float tanh_fast(float x) {
    float e = __expf(2.f * x);
    return 1.f - 2.f / (e + 1.f);
}
__device__ __forceinline__ f32x2 unpk(uint32 u) {
    return (f32x2){__uint_as_float(u << 16), __uint_as_float(u & 0xffff0000u)};
}

// ---------- phase 1: MFMA GEMM (xt -> ftb + inv2.x) blocks [0,gblk); hist blocks [gblk, ...) ----------
__global__ __launch_bounds__(256) void k_phase1(const float* __restrict__ x, const float* __restrict__ W,
                                                const float* __restrict__ b, uint32* __restrict__ ftb,
                                                float* __restrict__ inv2, int N,
                                                const int* __restrict__ ei, int E, int* __restrict__ deg, int gblk_) {
    __shared__ uint32 As[64 * 36];   // 64 rows x 64 bf16 (+8 pad)
    __shared__ uint32 Ws[96 * 36];
    if (blockIdx.x >= gblk_) {
        int e = (blockIdx.x - gblk_) * 256 + threadIdx.x;
        int Et = E + N;
        if (e < Et) {
            int dst = (e < E) ? ei[E + e] : (e - E);
            atomicAdd(&deg[dst], 1);
        }
        return;
    }
    int tid = threadIdx.x;
    int lane = tid & 63;
    int w = tid >> 6;
    int row0 = blockIdx.x * 64;
    int n = lane & 15, g = lane >> 4;

    f32x4 acc[6];
#pragma unroll
    for (int t = 0; t < 6; t++) acc[t] = (f32x4){0.f, 0.f, 0.f, 0.f};

    for (int kc = 0; kc < DIN; kc += 64) {
        for (int i = tid; i < 64 * 16; i += 256) {
            int r = i >> 4, seg = i & 15;
            int grow = row0 + r;
            float4 v = (grow < N) ? *(const float4*)(x + (size_t)grow * DIN + kc + seg * 4)
                                  : make_float4(0.f, 0.f, 0.f, 0.f);
            As[r * 36 + seg * 2]     = packbf(v.x, v.y);
            As[r * 36 + seg * 2 + 1] = packbf(v.z, v.w);
        }
        for (int i = tid; i < 96 * 16; i += 256) {
            int r = i >> 4, seg = i & 15;
            float4 v = *(const float4*)(W + (size_t)r * DIN + kc + seg * 4);
            Ws[r * 36 + seg * 2]     = packbf(v.x, v.y);
            Ws[r * 36 + seg * 2 + 1] = packbf(v.z, v.w);
        }
        __syncthreads();
#pragma unroll
        for (int s = 0; s < 2; s++) {
            int kb = s * 16 + g * 4;
            bf16x8 a = *(const bf16x8*)&As[(16 * w + n) * 36 + kb];
#pragma unroll
            for (int t = 0; t < 6; t++) {
                bf16x8 bb = *(const bf16x8*)&Ws[(16 * t + n) * 36 + kb];
                acc[t] = __builtin_amdgcn_mfma_f32_16x16x32_bf16(a, bb, acc[t], 0, 0, 0);
            }
        }
        __syncthreads();
    }
    float ss[4] = {0.f, 0.f, 0.f, 0.f};
#pragma unroll
    for (int t = 0; t < 6; t++) {
        int col = 16 * t + n;
        float bv = b[col];
#pragma unroll
        for (int r = 0; r < 4; r++) {
            int grow = row0 + 16 * w + g * 4 + r;
            float v = acc[t][r] + bv;
            float vb = bfround(v);
            ss[r] += vb * vb;
            float p = __shfl_xor(v, 1, 64);
            if ((n & 1) == 0 && grow < N)
                ftb[(size_t)grow * 96 + 8 * t + (n >> 1)] = packbf(v, p);
        }
    }
#pragma unroll
    for (int r = 0; r < 4; r++) {
#pragma unroll
        for (int off = 1; off < 16; off <<= 1) ss[r] += __shfl_xor(ss[r], off, 64);
        int grow = row0 + 16 * w + g * 4 + r;
        if (n == 0 && grow < N) inv2[2 * grow] = 1.f / fmaxf(sqrtf(ss[r]), 1e-12f);
    }
}

// ---------- phase 2: scanA blocks [0,nb); cvt_h blocks [nb, ...) ----------
// scanA stores RAW per-block sums in bsum (prefix computed in k_scanC).
__global__ __launch_bounds__(256) void k_phase2(const int* __restrict__ deg, int* __restrict__ rs,
                                                int* __restrict__ bsum, int n,
                                                const float* __restrict__ h, uint32* __restrict__ hb,
                                                float* __restrict__ inv, int N, int nb_) {
    __shared__ int sh[256];
    int t = threadIdx.x;
    if (blockIdx.x >= nb_) {
        int wid = (blockIdx.x - nb_) * 4 + (t >> 6);
        int lane = t & 63;
        if (wid >= N) return;
        const float2* row = (const float2*)(h + (size_t)wid * H);
        float ss = 0.f;
        if (lane < 48) {
            float2 v = row[lane];
            uint32 p = packbf(v.x, v.y);
            hb[(size_t)wid * 48 + lane] = p;
            float a = bflo(p), b = bfhi(p);
            ss = a * a + b * b;
        }
#pragma unroll
        for (int off = 32; off; off >>= 1) ss += __shfl_xor(ss, off, 64);
        if (lane == 0) inv[wid] = 1.f / fmaxf(sqrtf(ss), 1e-12f);
        return;
    }
    int base = blockIdx.x * 1024 + t * 4;
    int v[4];
    int s = 0;
#pragma unroll
    for (int j = 0; j < 4; j++) { v[j] = (base + j < n) ? deg[base + j] : 0; s += v[j]; }
    sh[t] = s;
    __syncthreads();
    for (int off = 1; off < 256; off <<= 1) {
        int tmp = (t >= off) ? sh[t - off] : 0;
        __syncthreads();
        sh[t] += tmp;
        __syncthreads();
    }
    int excl = sh[t] - s;
#pragma unroll
    for (int j = 0; j < 4; j++) {
        if (base + j < n) rs[base + j] = excl;
        excl += v[j];
    }
    if (t == 255) bsum[blockIdx.x] = sh[255];   // RAW block total
}

// scanC with inline prefix of bsum (nb <= 64 raw block sums)
__global__ void k_scanC(int* __restrict__ rs, int* __restrict__ cur, const int* __restrict__ bsum,
                        int n, int total, int nb_) {
    int i = blockIdx.x * blockDim.x + threadIdx.x;
    if (i < n) {
        int bkt = i >> 10;
        int add = 0;
        for (int j = 0; j < bkt; j++) add += bsum[j];
        int r = rs[i] + add;
        rs[i] = r;
        cur[i] = r;
    }
    if (i == 0) rs[n] = total;
}

__global__ void k_scatter(const int* __restrict__ ei, int E, int N,
                          int* __restrict__ cur, int* __restrict__ csr_src) {
    int e = blockIdx.x * blockDim.x + threadIdx.x;
    int Et = E + N;
    if (e >= Et) return;
    int src, dst;
    if (e < E) { src = ei[e]; dst = ei[E + e]; }
    else       { src = e - E; dst = e - E; }
    int pos = atomicAdd(&cur[dst], 1);
    csr_src[pos] = src;
}

// ---------- MFMA GEMM: h_N = h + tanh([h|A]@[Wb1|Wb2]^T + b) -> hN half of ftb + inv2.y ----------
__global__ __launch_bounds__(256) void k_gemm_gate_mfma(const uint32* __restrict__ hb, const uint32* __restrict__ hN0b,
                                                        const float* __restrict__ h,
                                                        const float* __restrict__ W1, const float* __restrict__ W2,
                                                        const float* __restrict__ b1, const float* __restrict__ b2,
                                                        uint32* __restrict__ ftb, float* __restrict__ inv2, int N) {
    __shared__ uint32 As[64 * 52];
    __shared__ uint32 Ws[96 * 52];
    int tid = threadIdx.x;
    int lane = tid & 63;
    int w = tid >> 6;
    int row0 = blockIdx.x * 64;
    int n = lane & 15, g = lane >> 4;

    f32x4 acc[6];
#pragma unroll
    for (int t = 0; t < 6; t++) acc[t] = (f32x4){0.f, 0.f, 0.f, 0.f};

    for (int chunk = 0; chunk < 2; chunk++) {
        {
            const uint32* src = chunk ? hN0b : hb;
            int r = tid >> 2, j = tid & 3;
            int grow = row0 + r;
            if (grow < N) {
#pragma unroll
                for (int m = 0; m < 3; m++) {
                    uint4 u = *(const uint4*)(src + (size_t)grow * 48 + j * 12 + m * 4);
                    *(uint4*)&As[r * 52 + j * 12 + m * 4] = u;
                }
            } else {
#pragma unroll
                for (int m = 0; m < 12; m++) As[r * 52 + j * 12 + m] = 0u;
            }
        }
        {
            const float* Wsrc = chunk ? W2 : W1;
            for (int i = tid; i < 96 * 24; i += 256) {
                int r = i / 24, seg = i % 24;
                float4 v = *(const float4*)(Wsrc + (size_t)r * H + seg * 4);
                Ws[r * 52 + seg * 2]     = packbf(v.x, v.y);
                Ws[r * 52 + seg * 2 + 1] = packbf(v.z, v.w);
            }
        }
        __syncthreads();
#pragma unroll
        for (int s = 0; s < 3; s++) {
            int kb = s * 16 + g * 4;
            bf16x8 a = *(const bf16x8*)&As[(16 * w + n) * 52 + kb];
#pragma unroll
            for (int t = 0; t < 6; t++) {
                bf16x8 bb = *(const bf16x8*)&Ws[(16 * t + n) * 52 + kb];
                acc[t] = __builtin_amdgcn_mfma_f32_16x16x32_bf16(a, bb, acc[t], 0, 0, 0);
            }
        }
        __syncthreads();
    }
    float ss[4] = {0.f, 0.f, 0.f, 0.f};
#pragma unroll
    for (int t = 0; t < 6; t++) {
        int col = 16 * t + n;
        float bsum = b1[col] + b2[col];
#pragma unroll
        for (int r = 0; r < 4; r++) {
            int grow = row0 + 16 * w + g * 4 + r;
            float hval = (grow < N) ? h[(size_t)grow * H + col] : 0.f;
            float v = hval + tanh_fast(acc[t][r] + bsum);
            float vb = bfround(v);
            ss[r] += vb * vb;
            float p = __shfl_xor(v, 1, 64);
            if ((n & 1) == 0 && grow < N)
                ftb[(size_t)grow * 96 + 48 + 8 * t + (n >> 1)] = packbf(v, p);
        }
    }
#pragma unroll
    for (int r = 0; r < 4; r++) {
#pragma unroll
        for (int off = 1; off < 16; off <<= 1) ss[r] += __shfl_xor(ss[r], off, 64);
        int grow = row0 + 16 * w + g * 4 + r;
        if (n == 0 && grow < N) inv2[2 * grow + 1] = 1.f / fmaxf(sqrtf(ss[r]), 1e-12f);
    }
}

// ---------- fused AGNN on h: 8 lanes/edge x 8 edges/iter, ping-pong pipeline ----------
__global__ __launch_bounds__(256, 8) void k_fused_h(const uint32* __restrict__ hb, const float* __restrict__ invn,
                                                    const int* __restrict__ rs, const int* __restrict__ csr_src,
                                                    const float* __restrict__ betas, uint32* __restrict__ outb, int N) {
    int wid = (blockIdx.x * blockDim.x + threadIdx.x) >> 6;
    int lane = threadIdx.x & 63;
    if (wid >= N) return;
    int d8 = lane & 7;
    int e8 = lane >> 3;
    float beta = betas[1];
    float shift = fabsf(beta);
    const uint32* dbase = hb + (size_t)wid * 48 + 6 * d8;
    float invd = invn[wid];
    uint2 dw0 = *(const uint2*)dbase, dw1 = *(const uint2*)(dbase + 2), dw2 = *(const uint2*)(dbase + 4);
    f32x2 dn2[6];
    dn2[0] = unpk(dw0.x) * invd; dn2[1] = unpk(dw0.y) * invd;
    dn2[2] = unpk(dw1.x) * invd; dn2[3] = unpk(dw1.y) * invd;
    dn2[4] = unpk(dw2.x) * invd; dn2[5] = unpk(dw2.y) * invd;
    int s0 = rs[wid], s1 = rs[wid + 1];
    int nIter = (s1 - s0 + 7) >> 3;
    int idx0 = s0 + e8;

    float den = 0.f;
    f32x2 acc2[6];
#pragma unroll
    for (int j = 0; j < 6; j++) acc2[j] = (f32x2){0.f, 0.f};

    auto compute = [&](uint2 p0, uint2 p1, uint2 p2, float invS, bool vS) {
        f32x2 v2[6];
        v2[0] = unpk(p0.x); v2[1] = unpk(p0.y);
        v2[2] = unpk(p1.x); v2[3] = unpk(p1.y);
        v2[4] = unpk(p2.x); v2[5] = unpk(p2.y);
        f32x2 d2 = v2[0] * dn2[0];
#pragma unroll
        for (int j = 1; j < 6; j++) d2 += v2[j] * dn2[j];
        float d = d2.x + d2.y;
        d += __shfl_xor(d, 1, 64);
        d += __shfl_xor(d, 2, 64);
        d += __shfl_xor(d, 4, 64);
        float w = __expf(beta * (d * invS) - shift);
        if (!vS) w = 0.f;
        den += w;
#pragma unroll
        for (int j = 0; j < 6; j++) acc2[j] += w * v2[j];
    };
    auto fetch = [&](int it_, uint2& p0, uint2& p1, uint2& p2, float& invS, bool& vS) {
        int idx = idx0 + 8 * it_;
        vS = idx < s1;
        int sn = csr_src[vS ? idx : s0];
        const uint32* rp = hb + (size_t)sn * 48 + 6 * d8;
        p0 = *(const uint2*)rp; p1 = *(const uint2*)(rp + 2); p2 = *(const uint2*)(rp + 4);
        invS = invn[sn];
    };

    uint2 A0, A1, A2, B0, B1, B2;
    float iA, iB; bool vA, vB;
    fetch(0, A0, A1, A2, iA, vA);
    int it = 0;
    for (; it + 2 <= nIter; it += 2) {
        fetch(it + 1, B0, B1, B2, iB, vB);
        compute(A0, A1, A2, iA, vA);
        fetch(it + 2, A0, A1, A2, iA, vA);
        compute(B0, B1, B2, iB, vB);
    }
    if (it < nIter) compute(A0, A1, A2, iA, vA);

    den += __shfl_xor(den, 8, 64);
    den += __shfl_xor(den, 16, 64);
    den += __shfl_xor(den, 32, 64);
#pragma unroll
    for (int j = 0; j < 6; j++) {
        acc2[j].x += __shfl_xor(acc2[j].x, 8, 64);
        acc2[j].y += __shfl_xor(acc2[j].y, 8, 64);
        acc2[j].x += __shfl_xor(acc2[j].x, 16, 64);
        acc2[j].y += __shfl_xor(acc2[j].y, 16, 64);
        acc2[j].x += __shfl_xor(acc2[j].x, 32, 64);
        acc2[j].y += __shfl_xor(acc2[j].y, 32, 64);
    }
    if (e8 == 0) {
        float r = 1.f / den;
        uint32* op = outb + (size_t)wid * 48 + 6 * d8;
        uint2 o0, o1, o2;
        o0.x = packbf(acc2[0].x * r, acc2[0].y * r);  o0.y = packbf(acc2[1].x * r, acc2[1].y * r);
        o1.x = packbf(acc2[2].x * r, acc2[2].y * r);  o1.y = packbf(acc2[3].x * r, acc2[3].y * r);
        o2.x = packbf(acc2[4].x * r, acc2[4].y * r);  o2.y = packbf(acc2[5].x * r, acc2[5].y * r);
        *(uint2*)op = o0; *(uint2*)(op + 2) = o1; *(uint2*)(op + 4) = o2;
    }
}

// ---------- fused gate kernel: role-split, ping-pong pipeline, pre-scaled exchange ----------
__global__ __launch_bounds__(256, 8) void k_fused_gates(const uint32* __restrict__ ftb, const float* __restrict__ inv2,
                                                        const int* __restrict__ rs, const int* __restrict__ csr_src,
                                                        const float* __restrict__ betas, const float* __restrict__ cold,
                                                        float* __restrict__ hout, float* __restrict__ cout_, int N) {
    int wid = (blockIdx.x * blockDim.x + threadIdx.x) >> 6;
    int lane = threadIdx.x & 63;
    if (wid >= N) return;
    float bx0 = betas[2], bh0 = betas[3];
    float bx1 = betas[4], bh1 = betas[5];
    float bx2 = betas[6], bh2 = betas[7];
    float bx3 = betas[8], bh3 = betas[9];
    bool uni = (bx0 == bx1) && (bx0 == bx2) && (bx0 == bx3) &&
               (bh0 == bh1) && (bh0 == bh2) && (bh0 == bh3);
    int s0 = rs[wid], s1 = rs[wid + 1];
    size_t rowbase = (size_t)wid * H;

    if (uni) {
        int l16 = lane & 15, q = lane >> 4;
        int sub = l16 >> 3;      // 0 = xt, 1 = hN
        int d8  = l16 & 7;       // dims [12*d8, 12*d8+12) of its feature
        float bsel = sub ? bh0 : bx0;
        float ssel = fabsf(bsel);
        const uint32* dbase = ftb + (size_t)wid * 96 + sub * 48 + 6 * d8;
        float invd = inv2[2 * wid + sub];
        uint2 dw0 = *(const uint2*)dbase, dw1 = *(const uint2*)(dbase + 2), dw2 = *(const uint2*)(dbase + 4);
        f32x2 dn2[6];
        dn2[0] = unpk(dw0.x) * invd; dn2[1] = unpk(dw0.y) * invd;
        dn2[2] = unpk(dw1.x) * invd; dn2[3] = unpk(dw1.y) * invd;
        dn2[4] = unpk(dw2.x) * invd; dn2[5] = unpk(dw2.y) * invd;
        int nIter = (s1 - s0 + 3) >> 2;
        int idx0 = s0 + q;

        float den = 0.f;
        f32x2 acc2[6];
#pragma unroll
        for (int j = 0; j < 6; j++) acc2[j] = (f32x2){0.f, 0.f};

        auto compute = [&](uint2 p0, uint2 p1, uint2 p2, float isS, bool vS) {
            f32x2 v2[6];
            v2[0] = unpk(p0.x); v2[1] = unpk(p0.y);
            v2[2] = unpk(p1.x); v2[3] = unpk(p1.y);
            v2[4] = unpk(p2.x); v2[5] = unpk(p2.y);
            f32x2 d2 = v2[0] * dn2[0];
#pragma unroll
            for (int j = 1; j < 6; j++) d2 += v2[j] * dn2[j];
            float d = d2.x + d2.y;
            d += __shfl_xor(d, 1, 64);
            d += __shfl_xor(d, 2, 64);
            d += __shfl_xor(d, 4, 64);
            float w = __expf(bsel * (d * isS) - ssel);
            if (!vS) w = 0.f;
            den += w;
#pragma unroll
            for (int j = 0; j < 6; j++) acc2[j] += w * v2[j];
        };
        auto fetch = [&](int it_, uint2& p0, uint2& p1, uint2& p2, float& isS, bool& vS) {
            int idx = idx0 + 4 * it_;
            vS = idx < s1;
            int sn = csr_src[vS ? idx : s0];
            const uint32* rp = ftb + (size_t)sn * 96 + sub * 48 + 6 * d8;
            p0 = *(const uint2*)rp; p1 = *(const uint2*)(rp + 2); p2 = *(const uint2*)(rp + 4);
            isS = inv2[2 * sn + sub];
        };

        uint2 A0, A1, A2, B0, B1, B2;
        float iA, iB; bool vA, vB;
        fetch(0, A0, A1, A2, iA, vA);
        int it = 0;
        for (; it + 2 <= nIter; it += 2) {
            fetch(it + 1, B0, B1, B2, iB, vB);
            compute(A0, A1, A2, iA, vA);
            fetch(it + 2, A0, A1, A2, iA, vA);
            compute(B0, B1, B2, iB, vB);
        }
        if (it < nIter) compute(A0, A1, A2, iA, vA);

        den += __shfl_xor(den, 16, 64);
        den += __shfl_xor(den, 32, 64);
#pragma unroll
        for (int j = 0; j < 6; j++) {
            acc2[j].x += __shfl_xor(acc2[j].x, 16, 64);
            acc2[j].y += __shfl_xor(acc2[j].y, 16, 64);
            acc2[j].x += __shfl_xor(acc2[j].x, 32, 64);
            acc2[j].y += __shfl_xor(acc2[j].y, 32, 64);
        }
        // pre-scale by own 1/den, then one cross-feature exchange-add
        float rown = 1.f / den;
        f32x2 a2[6];
#pragma unroll
        for (int j = 0; j < 6; j++) {
            f32x2 own = acc2[j] * rown;
            own.x += __shfl_xor(own.x, 8, 64);
            own.y += __shfl_xor(own.y, 8, 64);
            a2[j] = own;   // = accX*rX + accH*rH on both sub lanes
        }
        // 4-way parallel epilogue: sub==0 lanes; lane q handles dims 12*d8 + 3q + {0,1,2}
        if (sub == 0) {
            float aA0 = q == 0 ? a2[0].x : q == 1 ? a2[1].y : q == 2 ? a2[3].x : a2[4].y;
            float aA1 = q == 0 ? a2[0].y : q == 1 ? a2[2].x : q == 2 ? a2[3].y : a2[5].x;
            float aA2 = q == 0 ? a2[1].x : q == 1 ? a2[2].y : q == 2 ? a2[4].x : a2[5].y;
            size_t ob = rowbase + 12 * d8 + 3 * q;
            float aA[3] = {aA0, aA1, aA2};
            float cvs[3] = {cold[ob], cold[ob + 1], cold[ob + 2]};
            float ho[3], co[3];
#pragma unroll
            for (int t = 0; t < 3; t++) {
                float a   = aA[t];
                float sig = 1.f / (1.f + __expf(-a));   // f = i = o
                float ct  = tanh_fast(a);
                float cn  = sig * cvs[t] + sig * ct;
                ho[t] = sig * tanh_fast(cn);
                co[t] = cn;
            }
            hout[ob]     = ho[0]; hout[ob + 1]  = ho[1]; hout[ob + 2]  = ho[2];
            cout_[ob]    = co[0]; cout_[ob + 1] = co[1]; cout_[ob + 2] = co[2];
        }
    } else {
        // general 4-gate path (correctness fallback; arbitrary betas)
        int fi = lane & 15;
        int q  = lane >> 4;
        float ixd = inv2[2 * wid], ihd = inv2[2 * wid + 1];
        const uint32* xdp = ftb + (size_t)wid * 96 + 3 * fi;
        const uint32* hdp = ftb + (size_t)wid * 96 + 48 + 3 * fi;
        uint32 xu0 = xdp[0], xu1 = xdp[1], xu2 = xdp[2];
        uint32 hu0 = hdp[0], hu1 = hdp[1], hu2 = hdp[2];
        float xn[6] = {bflo(xu0) * ixd, bfhi(xu0) * ixd, bflo(xu1) * ixd,
                       bfhi(xu1) * ixd, bflo(xu2) * ixd, bfhi(xu2) * ixd};
        float hn[6] = {bflo(hu0) * ihd, bfhi(hu0) * ihd, bflo(hu1) * ihd,
                       bfhi(hu1) * ihd, bflo(hu2) * ihd, bfhi(hu2) * ihd};
        float sx[4] = {fabsf(bx0), fabsf(bx1), fabsf(bx2), fabsf(bx3)};
        float sh_[4] = {fabsf(bh0), fabsf(bh1), fabsf(bh2), fabsf(bh3)};
        float bxv[4] = {bx0, bx1, bx2, bx3};
        float bhv[4] = {bh0, bh1, bh2, bh3};
        float denX[4] = {0, 0, 0, 0}, denH[4] = {0, 0, 0, 0};
        float aX[4][6], aH[4][6];
#pragma unroll
        for (int g = 0; g < 4; g++)
#pragma unroll
            for (int j = 0; j < 6; j++) { aX[g][j] = 0.f; aH[g][j] = 0.f; }
        for (int s = s0; s < s1; s += 4) {
            int idx = s + q;
            bool valid = idx < s1;
            int sidx = valid ? idx : s0;
            int sn = csr_src[sidx];
            float isx = inv2[2 * sn], ish = inv2[2 * sn + 1];
            const uint32* xrp = ftb + (size_t)sn * 96 + 3 * fi;
            const uint32* hrp = ftb + (size_t)sn * 96 + 48 + 3 * fi;
            uint32 a0 = xrp[0], a1 = xrp[1], a2 = xrp[2];
            uint32 b0 = hrp[0], b1 = hrp[1], b2 = hrp[2];
            float xv[6] = {bflo(a0), bfhi(a0), bflo(a1), bfhi(a1), bflo(a2), bfhi(a2)};
            float hv[6] = {bflo(b0), bfhi(b0), bflo(b1), bfhi(b1), bflo(b2), bfhi(b2)};
            float dx = 0.f, dh = 0.f;
#pragma unroll
            for (int j = 0; j < 6; j++) { dx += xv[j] * xn[j]; dh += hv[j] * hn[j]; }
#pragma unroll
            for (int off = 8; off; off >>= 1) {
                dx += __shfl_xor(dx, off, 64);
                dh += __shfl_xor(dh, off, 64);
            }
            float cx = dx * isx, ch = dh * ish;
#pragma unroll
            for (int g = 0; g < 4; g++) {
                float wx = __expf(bxv[g] * cx - sx[g]);
                float wh = __expf(bhv[g] * ch - sh_[g]);
                if (!valid) { wx = 0.f; wh = 0.f; }
                denX[g] += wx; denH[g] += wh;
#pragma unroll
                for (int j = 0; j < 6; j++) { aX[g][j] += wx * xv[j]; aH[g][j] += wh * hv[j]; }
            }
        }
#pragma unroll
        for (int g = 0; g < 4; g++) {
            denX[g] += __shfl_xor(denX[g], 16, 64); denX[g] += __shfl_xor(denX[g], 32, 64);
            denH[g] += __shfl_xor(denH[g], 16, 64); denH[g] += __shfl_xor(denH[g], 32, 64);
#pragma unroll
            for (int j = 0; j < 6; j++) {
                aX[g][j] += __shfl_xor(aX[g][j], 16, 64); aX[g][j] += __shfl_xor(aX[g][j], 32, 64);
                aH[g][j] += __shfl_xor(aH[g][j], 16, 64); aH[g][j] += __shfl_xor(aH[g][j], 32, 64);
            }
        }
        if (q == 0) {
#pragma unroll
            for (int j = 0; j < 6; j++) {
                int d = 6 * fi + j;
                float a0 = aX[0][j] / denX[0] + aH[0][j] / denH[0];
                float a1 = aX[1][j] / denX[1] + aH[1][j] / denH[1];
                float a2 = aX[2][j] / denX[2] + aH[2][j] / denH[2];
                float a3 = aX[3][j] / denX[3] + aH[3][j] / denH[3];
                float f  = 1.f / (1.f + __expf(-a0));
                float i_ = 1.f / (1.f + __expf(-a1));
                float ct = tanh_fast(a2);
                float o  = 1.f / (1.f + __expf(-a3));
                float cv = cold[rowbase + d];
                float cn = f * cv + i_ * ct;
                hout[rowbase + d]  = o * tanh_fast(cn);
                cout_[rowbase + d] = cn;
            }
        }
    }
}

extern "C" void kernel_launch(void* const* d_in, const int* in_sizes, int n_in,
                              void* d_out, int out_size, void* d_ws, size_t ws_size,
                              hipStream_t stream) {
    const float* x        = (const float*)d_in[0];
    const int*   ei       = (const int*)d_in[1];
    const float* h        = (const float*)d_in[2];
    const float* c        = (const float*)d_in[3];
    const float* W_in     = (const float*)d_in[4];
    const float* b_in     = (const float*)d_in[5];
    const float* Wb1      = (const float*)d_in[10];
    const float* bb1      = (const float*)d_in[11];
    const float* Wb2      = (const float*)d_in[12];
    const float* bb2      = (const float*)d_in[13];
    const float* betas    = (const float*)d_in[14];

    int N  = in_sizes[0] / DIN;
    int E  = in_sizes[1] / 2;
    int Et = E + N;
    int NH = N * H;

    char* ws = (char*)d_ws;
    size_t off = 0;
    auto alloc = [&](size_t bytes) -> void* {
        void* p = ws + off;
        off = (off + bytes + 255) & ~(size_t)255;
        return p;
    };
    uint32* ftb  = (uint32*)alloc((size_t)N * 96 * 4);   // merged bf16 rows: [xt(48 u32) | hN(48 u32)]
    uint32* hb   = (uint32*)alloc((size_t)N * 48 * 4);   // h bf16 rows
    uint32* hN0b = (uint32*)alloc((size_t)N * 48 * 4);   // AGNN(h) bf16 rows
    float* inv2  = (float*)alloc((size_t)N * 2 * 4);     // (inv_xt, inv_hN) pairs
    int* csr_src = (int*)alloc((size_t)Et * 4);
    int* deg     = (int*)alloc((size_t)N * 4);
    int* rs      = (int*)alloc((size_t)(N + 1) * 4);
    int* cur     = (int*)alloc((size_t)N * 4);
    int* bsum    = (int*)alloc(64 * 4);
    float* inv_h = (float*)alloc((size_t)N * 4);

    int nb = (N + 1023) / 1024;
    int gblk = (N + 63) / 64;
    int histblk = (Et + 255) / 256;
    int cvtblk = (N + 3) / 4;

    hipMemsetAsync(deg, 0, (size_t)N * 4, stream);
    // phase 1: xt GEMM (blocks [0,gblk)) || degree histogram (blocks [gblk, gblk+histblk))
    k_phase1<<<gblk + histblk, 256, 0, stream>>>(x, W_in, b_in, ftb, inv2, N, ei, E, deg, gblk);
    // phase 2: scanA (blocks [0,nb)) || h->bf16 convert (blocks [nb, nb+cvtblk))
    k_phase2<<<nb + cvtblk, 256, 0, stream>>>(deg, rs, bsum, N, h, hb, inv_h, N, nb);
    k_scanC<<<(N + 255) / 256, 256, 0, stream>>>(rs, cur, bsum, N, Et, nb);
    k_scatter<<<(Et + 255) / 256, 256, 0, stream>>>(ei, E, N, cur, csr_src);

    k_fused_h<<<(N + 3) / 4, 256, 0, stream>>>(hb, inv_h, rs, csr_src, betas, hN0b, N);
    k_gemm_gate_mfma<<<gblk, 256, 0, stream>>>(hb, hN0b, h, Wb1, Wb2, bb1, bb2, ftb, inv2, N);

    float* hout = (float*)d_out;
    float* cout_ = (float*)d_out + NH;
    k_fused_gates<<<(N + 3) / 4, 256, 0, stream>>>(ftb, inv2, rs, csr_src, betas, c, hout, cout_, N);
}